// Round 12
// baseline (335.296 us; speedup 1.0000x reference)
//
#include <hip/hip_runtime.h>
#include <hip/hip_bf16.h>

typedef __bf16 bf16;
typedef __bf16 bf16x8 __attribute__((ext_vector_type(8)));
typedef float f32x4 __attribute__((ext_vector_type(4)));

// ---------------- async global->LDS (width 16) ----------------
__device__ __forceinline__ void gload_lds16(const bf16* g, bf16* l) {
    __builtin_amdgcn_global_load_lds(
        (const __attribute__((address_space(1))) void*)g,
        (__attribute__((address_space(3))) void*)l, 16, 0, 0);
}

// ---------------- GroupNorm stats: one block per (n,group) ----------------
__global__ __launch_bounds__(256) void k_gnstats(const float* __restrict__ x,
                                                 float2* __restrict__ stats) {
    const int g = blockIdx.x;            // 0..127
    const float4* p = (const float4*)(x + (long)g * 65536);
    float s = 0.f, ss = 0.f;
    #pragma unroll 8
    for (int i = 0; i < 64; ++i) {
        float4 v = p[threadIdx.x + i * 256];
        s  += v.x + v.y + v.z + v.w;
        ss += v.x * v.x + v.y * v.y + v.z * v.z + v.w * v.w;
    }
    #pragma unroll
    for (int off = 32; off >= 1; off >>= 1) {
        s  += __shfl_down(s, off);
        ss += __shfl_down(ss, off);
    }
    __shared__ float rs[4], rss[4];
    if ((threadIdx.x & 63) == 0) { rs[threadIdx.x >> 6] = s; rss[threadIdx.x >> 6] = ss; }
    __syncthreads();
    if (threadIdx.x == 0) {
        float S  = rs[0] + rs[1] + rs[2] + rs[3];
        float SS = rss[0] + rss[1] + rss[2] + rss[3];
        float mu = S * (1.f / 65536.f);
        float var = SS * (1.f / 65536.f) - mu * mu;
        stats[g] = make_float2(mu, rsqrtf(var + 1e-5f));
    }
}

// ---------------- normalize + transpose NCHW -> tokens [nt][512] bf16 ----------------
__global__ __launch_bounds__(256) void k_norm_t(const float* __restrict__ x,
                                                const float* __restrict__ w,
                                                const float* __restrict__ b,
                                                const float2* __restrict__ stats,
                                                bf16* __restrict__ t) {
    __shared__ float tile[64][65];
    const int bid = blockIdx.x;
    const int n = bid >> 9, rem = bid & 511;
    const int s0 = (rem >> 3) * 64, c0 = (rem & 7) * 64;
    const int tid = threadIdx.x;
    const int sl = tid & 63, cq = tid >> 6;
    #pragma unroll
    for (int i = 0; i < 16; ++i) {
        const int cl = cq * 16 + i;
        const int c = c0 + cl;
        const float2 st = stats[n * 32 + (c >> 4)];
        const float v = x[((long)(n * 512 + c)) * 4096 + s0 + sl];
        tile[cl][sl] = (v - st.x) * st.y * w[c] + b[c];
    }
    __syncthreads();
    #pragma unroll
    for (int i = 0; i < 16; ++i) {
        const int sl2 = cq * 16 + i;
        const int cl2 = tid & 63;
        t[((long)(n * 4096 + s0 + sl2)) * 512 + c0 + cl2] = (bf16)tile[cl2][sl2];
    }
}

// ---------------- weight conversion (fold log2e/sqrt(512) into q rows) ----------------
__global__ __launch_bounds__(256) void k_convw(const float* __restrict__ qw,
                                               const float* __restrict__ pw,
                                               bf16* __restrict__ qwb,
                                               bf16* __restrict__ pwb) {
    const int i = blockIdx.x * 256 + threadIdx.x;
    if (i < 786432) {
        float v = qw[i];
        if (i < 512 * 512) v *= 0.06376281516217733f;  // log2(e)/sqrt(512)
        qwb[i] = (bf16)v;
    } else {
        const int j = i - 786432;
        pwb[j] = (bf16)pw[j];
    }
}

// ---------------- transpose vbuf [16384][512] -> Vt[n][512][4096] ----------------
__global__ __launch_bounds__(256) void k_vt(const bf16* __restrict__ vbuf,
                                            bf16* __restrict__ Vt) {
    __shared__ bf16 tile[64][66];
    const int bid = blockIdx.x;
    const int n = bid >> 9, rem = bid & 511;
    const int s0 = (rem >> 3) * 64, d0 = (rem & 7) * 64;
    const int tid = threadIdx.x;
    #pragma unroll
    for (int i = 0; i < 16; ++i) {
        const int sl = (tid >> 6) * 16 + i;
        const int dl = tid & 63;
        tile[sl][dl] = vbuf[((long)(n * 4096 + s0 + sl)) * 512 + d0 + dl];
    }
    __syncthreads();
    #pragma unroll
    for (int i = 0; i < 16; ++i) {
        const int dl = (tid >> 6) * 16 + i;
        const int sl = tid & 63;
        Vt[((long)(n * 512 + d0 + dl)) * 4096 + s0 + sl] = tile[sl][dl];
    }
}

// =====================================================================
// 256x256 tile, BK=64, 8-wave, 8-phase GEMM with counted vmcnt (T3+T4+T5)
// LDS swizzle: granule ^= (row>>1)&3  (2-way banks = free)
// EPI 1: P = exp2(acc) bf16 store (scores in log2 domain).
// EPI 2: QKV split store -- q,k into C [row][1024]; v into vbuf [row][512].
// =====================================================================
#define PH(mh, kk, S_, WN)                                                         \
  {                                                                                \
    if ((mh) == 0) {                                                               \
      _Pragma("unroll")                                                            \
      for (int n = 0; n < 4; ++n) {                                                \
        int row = wn * 64 + n * 16 + lr;                                           \
        int cg = lg ^ ((row >> 1) & 3);                                            \
        bfr[n] = *(const bf16x8*)(BsT + (kk) * 8192 + row * 32 + cg * 8);          \
      }                                                                            \
    }                                                                              \
    _Pragma("unroll")                                                              \
    for (int i = 0; i < 4; ++i) {                                                  \
      int row = wm * 128 + ((mh) * 4 + i) * 16 + lr;                               \
      int cg = lg ^ ((row >> 1) & 3);                                              \
      af[i] = *(const bf16x8*)(AsT + (kk) * 8192 + row * 32 + cg * 8);             \
    }                                                                              \
    if ((S_) >= 0) issue_unit(S_);                                                 \
    __builtin_amdgcn_s_barrier();                                                  \
    asm volatile("" ::: "memory");                                                 \
    __builtin_amdgcn_s_setprio(1);                                                 \
    _Pragma("unroll")                                                              \
    for (int i = 0; i < 4; ++i)                                                    \
      _Pragma("unroll")                                                            \
      for (int n = 0; n < 4; ++n)                                                  \
        acc[(mh) * 4 + i][n] =                                                     \
            __builtin_amdgcn_mfma_f32_16x16x32_bf16(af[i], bfr[n],                 \
                                                    acc[(mh) * 4 + i][n], 0, 0, 0);\
    __builtin_amdgcn_s_setprio(0);                                                 \
    if constexpr ((WN) >= 0)                                                       \
      asm volatile("s_waitcnt vmcnt(%0)" ::"i"(WN) : "memory");                    \
    __builtin_amdgcn_s_barrier();                                                  \
    asm volatile("" ::: "memory");                                                 \
  }

template <int EPI>
__global__ __launch_bounds__(512, 2) void gemm256(
    const bf16* __restrict__ A, int lda, long aZ,
    const bf16* __restrict__ B, int ldb, long bZ,
    bf16* __restrict__ C, int ldc, long cZ, int K,
    bf16* __restrict__ vbuf) {
    __shared__ bf16 As[2 * 2 * 256 * 32];
    __shared__ bf16 Bs[2 * 2 * 256 * 32];
    const int t = threadIdx.x;
    const int wid = t >> 6, l = t & 63;
    const int wm = wid >> 2, wn = wid & 3;     // 2 x 4 waves
    const int lr = l & 15;
    const int lg = l >> 4;                     // fragment col-group 0..3
    const long z = blockIdx.z;

    const int gx = gridDim.x;
    int nwg = gx * gridDim.y;
    int flat = blockIdx.y * gx + blockIdx.x;
    if ((nwg & 7) == 0) { int qq = nwg >> 3; flat = (flat & 7) * qq + (flat >> 3); }
    const int bx = flat % gx, by = flat / gx;

    const bf16* Ab = A + z * aZ + (long)bx * 256 * lda;
    const bf16* Bb = B + z * bZ + (long)by * 256 * ldb;

    const int NT = K >> 6;
    const int NT4 = NT << 2;

    f32x4 acc[8][4];
    #pragma unroll
    for (int i = 0; i < 8; ++i)
        #pragma unroll
        for (int n = 0; n < 4; ++n) acc[i][n] = f32x4{0.f, 0.f, 0.f, 0.f};

    const int srow = t >> 2;       // 0..127
    const int scg0 = t & 3;

    auto issue_unit = [&](int s) {
        int ti = s >> 2, idx = s & 3;
        int kh = idx >> 1, isB = idx & 1;
        const bf16* g = isB ? Bb : Ab;
        int ld = isB ? ldb : lda;
        bf16* lp = (isB ? Bs : As) + ((ti & 1) * 2 + kh) * 8192;
        int k0 = ti * 64 + kh * 32;
        #pragma unroll
        for (int j = 0; j < 2; ++j) {
            int row = j * 128 + srow;
            int cg = scg0 ^ ((row >> 1) & 3);
            gload_lds16(g + (long)row * ld + k0 + cg * 8, lp + (j * 512 + t) * 8);
        }
    };

    #pragma unroll
    for (int s = 0; s < 6; ++s) issue_unit(s);
    asm volatile("s_waitcnt vmcnt(8)" ::: "memory");
    __builtin_amdgcn_s_barrier();
    asm volatile("" ::: "memory");

    bf16x8 bfr[4], af[4];

    for (int ti = 0; ti < NT - 2; ++ti) {
        const bf16* AsT = As + (ti & 1) * 16384;
        const bf16* BsT = Bs + (ti & 1) * 16384;
        const int sb = 4 * ti + 6;
        PH(0, 0, sb + 0, -1)
        PH(1, 0, sb + 1, 8)
        PH(0, 1, sb + 2, -1)
        PH(1, 1, sb + 3, 8)
    }
    {
        const bf16* AsT = As + ((NT - 2) & 1) * 16384;
        const bf16* BsT = Bs + ((NT - 2) & 1) * 16384;
        PH(0, 0, NT4 - 2, -1)
        PH(1, 0, NT4 - 1, 8)
        PH(0, 1, -1, -1)
        PH(1, 1, -1, 4)
    }
    {
        const bf16* AsT = As + ((NT - 1) & 1) * 16384;
        const bf16* BsT = Bs + ((NT - 1) & 1) * 16384;
        PH(0, 0, -1, -1)
        PH(1, 0, -1, 0)
        PH(0, 1, -1, -1)
        PH(1, 1, -1, -1)
    }

    const int row0 = bx * 256 + wm * 128;
    const int col0 = by * 256 + wn * 64;
    const int rq = lg * 4;

    if (EPI == 1) {
        bf16* Cz = C + z * cZ;
        #pragma unroll
        for (int i = 0; i < 8; ++i)
            #pragma unroll
            for (int n = 0; n < 4; ++n) {
                const int col = col0 + n * 16 + lr;
                #pragma unroll
                for (int r = 0; r < 4; ++r)
                    Cz[(long)(row0 + i * 16 + rq + r) * ldc + col] = (bf16)exp2f(acc[i][n][r]);
            }
    } else {
        // QKV: q,k -> C [row][1024]; v -> vbuf [row][512]  (both coalesced)
        #pragma unroll
        for (int i = 0; i < 8; ++i) {
            const int row = row0 + i * 16 + rq;
            #pragma unroll
            for (int n = 0; n < 4; ++n) {
                const int col = col0 + n * 16 + lr;
                if (col < 1024) {
                    #pragma unroll
                    for (int r = 0; r < 4; ++r)
                        C[(long)(row + r) * 1024 + col] = (bf16)acc[i][n][r];
                } else {
                    #pragma unroll
                    for (int r = 0; r < 4; ++r)
                        vbuf[(long)(row + r) * 512 + (col - 1024)] = (bf16)acc[i][n][r];
                }
            }
        }
    }
}

// =====================================================================
// PV GEMM v2: BK=32, LDS 72.25KB -> 2 blocks/CU (cross-block overlap).
// O[64 x 512] per block = P[64 x 4096] * V (via Vt[512][4096]) / rowsum.
// 128-tile loop; 5 uniform gload units/tile (1 P + 4 V; waves 4-7 issue
// benign duplicate P writes so every wave's vmcnt ledger is identical).
// Steady-state vmcnt(5); XCD remap groups each XCD's blocks on one z so
// Vt_z (4MB) fits that XCD's L2.
// =====================================================================
__global__ __launch_bounds__(512, 2) void k_pv(
    const bf16* __restrict__ P, const bf16* __restrict__ Vt,
    bf16* __restrict__ O, int ldo) {
    __shared__ bf16 Bs[2][512 * 32];   // 2 x 32 KB
    __shared__ bf16 As[2][64 * 32];    // 2 x 4 KB
    __shared__ float linv[64];
    const int t = threadIdx.x;
    const int w = t >> 6, l = t & 63, lr = l & 15, lg = l >> 4;
    const int cgr = lg ^ ((lr >> 1) & 3);

    // XCD remap: blocks on XCD x all share z = x>>1 (Vt_z L2-resident)
    int f = blockIdx.y * 64 + blockIdx.x;
    const int xcd = f & 7, idx = f >> 3;
    const long zz = xcd >> 1;
    const int bx = (xcd & 1) * 32 + idx;

    // V staging: 4 units x (512 thr x 16B); row vr+u*128, granule pre-swizzled
    const int vr = t >> 2;                       // 0..127
    const int vg = (t & 3) ^ ((vr >> 1) & 3);
    const bf16* Vgp = Vt + zz * ((long)512 * 4096) + (long)vr * 4096 + vg * 8;
    // P staging: wave w covers quarter q=w&3 (waves 4-7 duplicate: benign)
    const int q = w & 3;
    const int prl = l >> 2;                      // 0..15
    const int pg = (l & 3) ^ ((l >> 3) & 3);
    const bf16* Pgp = P + zz * ((long)4096 * 4096)
                        + (long)(bx * 64 + q * 16 + prl) * 4096 + pg * 8;

    bf16* Asl = &As[0][0];
    bf16* Bsl = &Bs[0][0];

    auto issue = [&](int ti, int buf) {
        gload_lds16(Pgp + ti * 32, Asl + buf * 2048 + q * 512 + l * 8);
        #pragma unroll
        for (int u = 0; u < 4; ++u)
            gload_lds16(Vgp + (long)u * 128 * 4096 + ti * 32,
                        Bsl + buf * 16384 + u * 4096 + t * 8);
    };

    f32x4 acc[4][4];
    #pragma unroll
    for (int i = 0; i < 4; ++i)
        #pragma unroll
        for (int n = 0; n < 4; ++n) acc[i][n] = f32x4{0.f, 0.f, 0.f, 0.f};

    float lsum = 0.f;

    issue(0, 0);
    issue(1, 1);

    for (int ti = 0; ti < 128; ++ti) {
        if (ti < 127) { asm volatile("s_waitcnt vmcnt(5)" ::: "memory"); }
        else          { asm volatile("s_waitcnt vmcnt(0)" ::: "memory"); }
        __builtin_amdgcn_s_barrier();
        asm volatile("" ::: "memory");

        const bf16* Asb = Asl + (ti & 1) * 2048;
        const bf16* Bsb = Bsl + (ti & 1) * 16384;

        // own-slot row-partial sums (waves 0-3 only; exact coverage)
        if (w < 4) {
            bf16x8 sv = *(const bf16x8*)(Asb + q * 512 + l * 8);
            #pragma unroll
            for (int j = 0; j < 8; ++j) lsum += (float)sv[j];
        }

        __builtin_amdgcn_s_setprio(1);
        bf16x8 af[4], bfv[4];
        #pragma unroll
        for (int mi = 0; mi < 4; ++mi)
            af[mi] = *(const bf16x8*)(Asb + (mi * 16 + lr) * 32 + cgr * 8);
        #pragma unroll
        for (int n = 0; n < 4; ++n)
            bfv[n] = *(const bf16x8*)(Bsb + (w * 64 + n * 16 + lr) * 32 + cgr * 8);
        #pragma unroll
        for (int mi = 0; mi < 4; ++mi)
            #pragma unroll
            for (int n = 0; n < 4; ++n)
                acc[mi][n] = __builtin_amdgcn_mfma_f32_16x16x32_bf16(af[mi], bfv[n], acc[mi][n], 0, 0, 0);
        __builtin_amdgcn_s_setprio(0);

        __builtin_amdgcn_s_barrier();
        asm volatile("" ::: "memory");
        if (ti < 126) issue(ti + 2, ti & 1);
    }

    // finalize row sums: 4 lanes per row (granules), xor-reduce, lane0 writes
    if (w < 4) {
        lsum += __shfl_xor(lsum, 1);
        lsum += __shfl_xor(lsum, 2);
        if ((l & 3) == 0) linv[q * 16 + prl] = 1.f / lsum;
    }
    asm volatile("s_waitcnt lgkmcnt(0)" ::: "memory");
    __builtin_amdgcn_s_barrier();
    asm volatile("" ::: "memory");

    bf16* Oz = O + zz * ((long)4096 * ldo);
    #pragma unroll
    for (int mi = 0; mi < 4; ++mi) {
        float4 lv = *(const float4*)&linv[mi * 16 + lg * 4];
        #pragma unroll
        for (int n = 0; n < 4; ++n) {
            const long base = (long)(bx * 64 + mi * 16 + lg * 4) * ldo + w * 64 + n * 16 + lr;
            Oz[base]           = (bf16)(acc[mi][n][0] * lv.x);
            Oz[base + ldo]     = (bf16)(acc[mi][n][1] * lv.y);
            Oz[base + 2 * ldo] = (bf16)(acc[mi][n][2] * lv.z);
            Oz[base + 3 * ldo] = (bf16)(acc[mi][n][3] * lv.w);
        }
    }
}

// =====================================================================
// 256x128 tile, BK=64, 8-wave (4M x 2N), 8-phase, counted vmcnt.
// proj epilogue: f32 + bias, coalesced store [row][512].
// =====================================================================
#define PH128(nh, kk, S_, WN)                                                      \
  {                                                                                \
    if ((nh) == 0) {                                                               \
      _Pragma("unroll")                                                            \
      for (int i = 0; i < 4; ++i) {                                                \
        int row = wm * 64 + i * 16 + lr;                                           \
        int cg = lg ^ ((row >> 1) & 3);                                            \
        af[i] = *(const bf16x8*)(AsT + (kk) * 8192 + row * 32 + cg * 8);           \
      }                                                                            \
    }                                                                              \
    _Pragma("unroll")                                                              \
    for (int j = 0; j < 2; ++j) {                                                  \
      int row = wn * 64 + ((nh) * 2 + j) * 16 + lr;                                \
      int cg = lg ^ ((row >> 1) & 3);                                              \
      bfr[j] = *(const bf16x8*)(BsT + (kk) * 4096 + row * 32 + cg * 8);            \
    }                                                                              \
    if ((S_) >= 0) issue_unit(S_);                                                 \
    __builtin_amdgcn_s_barrier();                                                  \
    asm volatile("" ::: "memory");                                                 \
    __builtin_amdgcn_s_setprio(1);                                                 \
    _Pragma("unroll")                                                              \
    for (int i = 0; i < 4; ++i)                                                    \
      _Pragma("unroll")                                                            \
      for (int j = 0; j < 2; ++j)                                                  \
        acc[i][(nh) * 2 + j] =                                                     \
            __builtin_amdgcn_mfma_f32_16x16x32_bf16(af[i], bfr[j],                 \
                                                    acc[i][(nh) * 2 + j], 0, 0, 0);\
    __builtin_amdgcn_s_setprio(0);                                                 \
    if constexpr ((WN) >= 0)                                                       \
      asm volatile("s_waitcnt vmcnt(%0)" ::"i"(WN) : "memory");                    \
    __builtin_amdgcn_s_barrier();                                                  \
    asm volatile("" ::: "memory");                                                 \
  }

__global__ __launch_bounds__(512, 2) void gemm_proj(
    const bf16* __restrict__ A, int lda,
    const bf16* __restrict__ B, int ldb,
    const float* __restrict__ bias,
    float* __restrict__ Cout) {
    __shared__ bf16 As[2 * 2 * 256 * 32];   // 64 KB
    __shared__ bf16 Bs[2 * 2 * 128 * 32];   // 32 KB
    const int t = threadIdx.x;
    const int wid = t >> 6, l = t & 63;
    const int wm = wid >> 1, wn = wid & 1;   // 4M x 2N waves, wave tile 64x64
    const int lr = l & 15;
    const int lg = l >> 4;

    const int gx = gridDim.x;
    int nwg = gx * gridDim.y;
    int flat = blockIdx.y * gx + blockIdx.x;
    if ((nwg & 7) == 0) { int qq = nwg >> 3; flat = (flat & 7) * qq + (flat >> 3); }
    const int bx = flat % gx, by = flat / gx;

    const bf16* Ab = A + (long)bx * 256 * lda;
    const bf16* Bb = B + (long)by * 128 * ldb;

    const int NT = 8;            // K = 512
    const int NT4 = 32;

    f32x4 acc[4][4];
    #pragma unroll
    for (int i = 0; i < 4; ++i)
        #pragma unroll
        for (int n = 0; n < 4; ++n) acc[i][n] = f32x4{0.f, 0.f, 0.f, 0.f};

    const int srow = t >> 2;       // 0..127
    const int scg0 = t & 3;

    auto issue_unit = [&](int s) {
        int ti = s >> 2, idx = s & 3;
        int kh = idx >> 1, isB = idx & 1;
        int k0 = ti * 64 + kh * 32;
        if (isB) {
            bf16* lp = Bs + ((ti & 1) * 2 + kh) * 4096;
            int cg = scg0 ^ ((srow >> 1) & 3);
            gload_lds16(Bb + (long)srow * ldb + k0 + cg * 8, lp + t * 8);
        } else {
            bf16* lp = As + ((ti & 1) * 2 + kh) * 8192;
            #pragma unroll
            for (int j = 0; j < 2; ++j) {
                int row = j * 128 + srow;
                int cg = scg0 ^ ((row >> 1) & 3);
                gload_lds16(Ab + (long)row * lda + k0 + cg * 8, lp + (j * 512 + t) * 8);
            }
        }
    };

    #pragma unroll
    for (int s = 0; s < 6; ++s) issue_unit(s);
    asm volatile("s_waitcnt vmcnt(6)" ::: "memory");
    __builtin_amdgcn_s_barrier();
    asm volatile("" ::: "memory");

    bf16x8 bfr[2], af[4];

    for (int ti = 0; ti < NT - 2; ++ti) {
        const bf16* AsT = As + (ti & 1) * 16384;
        const bf16* BsT = Bs + (ti & 1) * 8192;
        const int sb = 4 * ti + 6;
        PH128(0, 0, sb + 0, -1)
        PH128(1, 0, sb + 1, 6)
        PH128(0, 1, sb + 2, -1)
        PH128(1, 1, sb + 3, 6)
    }
    {
        const bf16* AsT = As + ((NT - 2) & 1) * 16384;
        const bf16* BsT = Bs + ((NT - 2) & 1) * 8192;
        PH128(0, 0, NT4 - 2, -1)
        PH128(1, 0, NT4 - 1, 6)
        PH128(0, 1, -1, -1)
        PH128(1, 1, -1, 3)
    }
    {
        const bf16* AsT = As + ((NT - 1) & 1) * 16384;
        const bf16* BsT = Bs + ((NT - 1) & 1) * 8192;
        PH128(0, 0, -1, -1)
        PH128(1, 0, -1, 0)
        PH128(0, 1, -1, -1)
        PH128(1, 1, -1, -1)
    }

    const int row0 = bx * 256 + wm * 64;
    const int col0 = by * 128 + wn * 64;
    const int rq = lg * 4;
    #pragma unroll
    for (int i = 0; i < 4; ++i)
        #pragma unroll
        for (int n = 0; n < 4; ++n) {
            const int col = col0 + n * 16 + lr;
            #pragma unroll
            for (int r = 0; r < 4; ++r)
                Cout[(long)(row0 + i * 16 + rq + r) * 512 + col] = acc[i][n][r] + bias[col];
        }
}

// ---------------- proj-out [nt][512] f32 -> NCHW + residual ----------------
__global__ __launch_bounds__(256) void k_final(const float* __restrict__ pb,
                                               const float* __restrict__ x,
                                               float* __restrict__ out) {
    __shared__ float tile[64][65];
    const int bid = blockIdx.x;
    const int n = bid >> 9, rem = bid & 511;
    const int s0 = (rem >> 3) * 64, c0 = (rem & 7) * 64;
    const int tid = threadIdx.x;
    #pragma unroll
    for (int i = 0; i < 16; ++i) {
        const int sl = (tid >> 6) * 16 + i;
        const int cl = tid & 63;
        tile[sl][cl] = pb[((long)(n * 4096 + s0 + sl)) * 512 + c0 + cl];
    }
    __syncthreads();
    #pragma unroll
    for (int i = 0; i < 16; ++i) {
        const int cl = (tid >> 6) * 16 + i;
        const int sl = tid & 63;
        const long oi = ((long)(n * 512 + c0 + cl)) * 4096 + s0 + sl;
        out[oi] = tile[sl][cl] + x[oi];
    }
}

extern "C" void kernel_launch(void* const* d_in, const int* in_sizes, int n_in,
                              void* d_out, int out_size, void* d_ws, size_t ws_size,
                              hipStream_t stream) {
    const float* x     = (const float*)d_in[0];
    const float* gnw   = (const float*)d_in[1];
    const float* gnb   = (const float*)d_in[2];
    const float* qkvw  = (const float*)d_in[3];
    const float* projw = (const float*)d_in[4];
    const float* projb = (const float*)d_in[5];

    char* ws = (char*)d_ws;
    size_t off = 0;
    auto alloc = [&](size_t bytes) {
        void* p = ws + off;
        off += (bytes + 255) & ~(size_t)255;
        return p;
    };
    // fixed: weights 2.1 MB + qk 33.55 MB + Vt 16.78 MB
    bf16*   qwb   = (bf16*)alloc((size_t)1536 * 512 * 2);
    bf16*   pwb   = (bf16*)alloc((size_t)512 * 512 * 2);
    float2* stats = (float2*)alloc((size_t)128 * 8);
    bf16*   qk    = (bf16*)alloc((size_t)16384 * 1024 * 2);  // q|k; q-half becomes O
    bf16*   Vt    = (bf16*)alloc((size_t)4 * 512 * 4096 * 2);
    // aliased region R (134.2 MB): tbuf+vbuf early -> Sbuf(4z) -> pjout f32
    char*   R     = (char*)alloc((size_t)4 * 4096 * 4096 * 2);
    bf16*   tbuf  = (bf16*)R;                                  // tokens [16384][512]
    bf16*   vbuf  = (bf16*)(R + (size_t)16384 * 512 * 2);      // v [16384][512]
    bf16*   Sbuf  = (bf16*)R;                                  // P, all 4 z
    float*  pjout = (float*)R;                                 // proj f32 [16384][512]

    k_gnstats<<<128, 256, 0, stream>>>(x, stats);
    k_norm_t<<<2048, 256, 0, stream>>>(x, gnw, gnb, stats, tbuf);
    k_convw<<<4096, 256, 0, stream>>>(qkvw, projw, qwb, pwb);

    // qkv: q,k -> qk [16384][1024]; v -> vbuf [16384][512]
    gemm256<2><<<dim3(64, 6, 1), 512, 0, stream>>>(
        tbuf, 512, 0, qwb, 512, 0, qk, 1024, 0, 512, vbuf);

    k_vt<<<2048, 256, 0, stream>>>(vbuf, Vt);

    const long QZ = (long)4096 * 1024;   // z-stride in qk
    const long SZ = (long)4096 * 4096;   // z-stride in Sbuf
    // P = exp2(q k^T) for ALL 4 batches in one dispatch (1024 blocks)
    gemm256<1><<<dim3(16, 16, 4), 512, 0, stream>>>(
        qk, 1024, QZ,
        qk + 512, 1024, QZ,
        Sbuf, 4096, SZ, 512, nullptr);
    // O = (P * V) / rowsum, all 4 batches, 256 blocks at 2 blocks/CU
    k_pv<<<dim3(64, 4), 512, 0, stream>>>(Sbuf, Vt, qk, 1024);

    // proj: [16384 x 512] f32 + bias (A = O in qk q-half, lda=1024)
    gemm_proj<<<dim3(64, 4), 512, 0, stream>>>(
        qk, 1024, pwb, 512, projb, pjout);

    // transpose back + residual
    k_final<<<2048, 256, 0, stream>>>(pjout, x, (float*)d_out);
}

// Round 13
// 321.062 us; speedup vs baseline: 1.0443x; 1.0443x over previous
//
#include <hip/hip_runtime.h>
#include <hip/hip_bf16.h>

typedef __bf16 bf16;
typedef __bf16 bf16x8 __attribute__((ext_vector_type(8)));
typedef float f32x4 __attribute__((ext_vector_type(4)));

// ---------------- async global->LDS (width 16) ----------------
__device__ __forceinline__ void gload_lds16(const bf16* g, bf16* l) {
    __builtin_amdgcn_global_load_lds(
        (const __attribute__((address_space(1))) void*)g,
        (__attribute__((address_space(3))) void*)l, 16, 0, 0);
}

// ---------------- GroupNorm stats: one block per (n,group) ----------------
__global__ __launch_bounds__(256) void k_gnstats(const float* __restrict__ x,
                                                 float2* __restrict__ stats) {
    const int g = blockIdx.x;            // 0..127
    const float4* p = (const float4*)(x + (long)g * 65536);
    float s = 0.f, ss = 0.f;
    #pragma unroll 8
    for (int i = 0; i < 64; ++i) {
        float4 v = p[threadIdx.x + i * 256];
        s  += v.x + v.y + v.z + v.w;
        ss += v.x * v.x + v.y * v.y + v.z * v.z + v.w * v.w;
    }
    #pragma unroll
    for (int off = 32; off >= 1; off >>= 1) {
        s  += __shfl_down(s, off);
        ss += __shfl_down(ss, off);
    }
    __shared__ float rs[4], rss[4];
    if ((threadIdx.x & 63) == 0) { rs[threadIdx.x >> 6] = s; rss[threadIdx.x >> 6] = ss; }
    __syncthreads();
    if (threadIdx.x == 0) {
        float S  = rs[0] + rs[1] + rs[2] + rs[3];
        float SS = rss[0] + rss[1] + rss[2] + rss[3];
        float mu = S * (1.f / 65536.f);
        float var = SS * (1.f / 65536.f) - mu * mu;
        stats[g] = make_float2(mu, rsqrtf(var + 1e-5f));
    }
}

// ---------------- normalize + transpose NCHW -> tokens [nt][512] bf16 ----------------
__global__ __launch_bounds__(256) void k_norm_t(const float* __restrict__ x,
                                                const float* __restrict__ w,
                                                const float* __restrict__ b,
                                                const float2* __restrict__ stats,
                                                bf16* __restrict__ t) {
    __shared__ float tile[64][65];
    const int bid = blockIdx.x;
    const int n = bid >> 9, rem = bid & 511;
    const int s0 = (rem >> 3) * 64, c0 = (rem & 7) * 64;
    const int tid = threadIdx.x;
    const int sl = tid & 63, cq = tid >> 6;
    #pragma unroll
    for (int i = 0; i < 16; ++i) {
        const int cl = cq * 16 + i;
        const int c = c0 + cl;
        const float2 st = stats[n * 32 + (c >> 4)];
        const float v = x[((long)(n * 512 + c)) * 4096 + s0 + sl];
        tile[cl][sl] = (v - st.x) * st.y * w[c] + b[c];
    }
    __syncthreads();
    #pragma unroll
    for (int i = 0; i < 16; ++i) {
        const int sl2 = cq * 16 + i;
        const int cl2 = tid & 63;
        t[((long)(n * 4096 + s0 + sl2)) * 512 + c0 + cl2] = (bf16)tile[cl2][sl2];
    }
}

// ---------------- weight conversion (fold log2e/sqrt(512) into q rows) ----------------
__global__ __launch_bounds__(256) void k_convw(const float* __restrict__ qw,
                                               const float* __restrict__ pw,
                                               bf16* __restrict__ qwb,
                                               bf16* __restrict__ pwb) {
    const int i = blockIdx.x * 256 + threadIdx.x;
    if (i < 786432) {
        float v = qw[i];
        if (i < 512 * 512) v *= 0.06376281516217733f;  // log2(e)/sqrt(512)
        qwb[i] = (bf16)v;
    } else {
        const int j = i - 786432;
        pwb[j] = (bf16)pw[j];
    }
}

// ---------------- transpose vbuf [16384][512] -> Vt[n][512][4096] ----------------
__global__ __launch_bounds__(256) void k_vt(const bf16* __restrict__ vbuf,
                                            bf16* __restrict__ Vt) {
    __shared__ bf16 tile[64][66];
    const int bid = blockIdx.x;
    const int n = bid >> 9, rem = bid & 511;
    const int s0 = (rem >> 3) * 64, d0 = (rem & 7) * 64;
    const int tid = threadIdx.x;
    #pragma unroll
    for (int i = 0; i < 16; ++i) {
        const int sl = (tid >> 6) * 16 + i;
        const int dl = tid & 63;
        tile[sl][dl] = vbuf[((long)(n * 4096 + s0 + sl)) * 512 + d0 + dl];
    }
    __syncthreads();
    #pragma unroll
    for (int i = 0; i < 16; ++i) {
        const int dl = (tid >> 6) * 16 + i;
        const int sl = tid & 63;
        Vt[((long)(n * 512 + d0 + dl)) * 4096 + s0 + sl] = tile[sl][dl];
    }
}

// =====================================================================
// Persistent 256x256-tile, BK=64, 8-wave, 8-phase GEMM (T3+T4+T5).
// Each block chains NTILES output tiles through ONE software pipeline
// (GT = NTILES*8 k-tiles). K fixed at 512. Swizzle granule ^= (row>>1)&3.
// EPI 1 (S): per-tile store P = exp2(acc) to C + j*dC (z-chaining).
// EPI 2 (QKV): per-tile split store, col-tiles chained (col0 += j*768);
//              cols<1024 -> C[row][1024] (q,k), cols>=1024 -> vbuf[row][512].
// Mid-stream stores transiently inflate vmcnt: counted waits become
// conservative (never unsafe).
// =====================================================================
#define PH(mh, kk, S_, WN)                                                         \
  {                                                                                \
    if ((mh) == 0) {                                                               \
      _Pragma("unroll")                                                            \
      for (int n = 0; n < 4; ++n) {                                                \
        int row = wn * 64 + n * 16 + lr;                                           \
        int cg = lg ^ ((row >> 1) & 3);                                            \
        bfr[n] = *(const bf16x8*)(BsT + (kk) * 8192 + row * 32 + cg * 8);          \
      }                                                                            \
    }                                                                              \
    _Pragma("unroll")                                                              \
    for (int i = 0; i < 4; ++i) {                                                  \
      int row = wm * 128 + ((mh) * 4 + i) * 16 + lr;                               \
      int cg = lg ^ ((row >> 1) & 3);                                              \
      af[i] = *(const bf16x8*)(AsT + (kk) * 8192 + row * 32 + cg * 8);             \
    }                                                                              \
    if ((S_) >= 0) issue_unit(S_);                                                 \
    __builtin_amdgcn_s_barrier();                                                  \
    asm volatile("" ::: "memory");                                                 \
    __builtin_amdgcn_s_setprio(1);                                                 \
    _Pragma("unroll")                                                              \
    for (int i = 0; i < 4; ++i)                                                    \
      _Pragma("unroll")                                                            \
      for (int n = 0; n < 4; ++n)                                                  \
        acc[(mh) * 4 + i][n] =                                                     \
            __builtin_amdgcn_mfma_f32_16x16x32_bf16(af[i], bfr[n],                 \
                                                    acc[(mh) * 4 + i][n], 0, 0, 0);\
    __builtin_amdgcn_s_setprio(0);                                                 \
    if constexpr ((WN) >= 0)                                                       \
      asm volatile("s_waitcnt vmcnt(%0)" ::"i"(WN) : "memory");                    \
    __builtin_amdgcn_s_barrier();                                                  \
    asm volatile("" ::: "memory");                                                 \
  }

template <int NTILES, int EPI>
__global__ __launch_bounds__(512, 2) void gemm256p(
    const bf16* __restrict__ A, int lda, long dA,
    const bf16* __restrict__ B, int ldb, long dB,
    bf16* __restrict__ C, int ldc, long dC,
    bf16* __restrict__ vbuf) {
    __shared__ bf16 As[2 * 2 * 256 * 32];
    __shared__ bf16 Bs[2 * 2 * 256 * 32];
    const int t = threadIdx.x;
    const int wid = t >> 6, l = t & 63;
    const int wm = wid >> 2, wn = wid & 3;     // 2 x 4 waves
    const int lr = l & 15;
    const int lg = l >> 4;                     // fragment col-group 0..3

    const int gx = gridDim.x;
    int nwg = gx * gridDim.y;
    int flat = blockIdx.y * gx + blockIdx.x;
    if ((nwg & 7) == 0) { int qq = nwg >> 3; flat = (flat & 7) * qq + (flat >> 3); }
    const int bx = flat % gx, by = flat / gx;

    const long bxoff = (long)bx * 256 * lda;
    const long byoff = (long)by * 256 * ldb;

    constexpr int GT = NTILES * 8;

    f32x4 acc[8][4];
    #pragma unroll
    for (int i = 0; i < 8; ++i)
        #pragma unroll
        for (int n = 0; n < 4; ++n) acc[i][n] = f32x4{0.f, 0.f, 0.f, 0.f};

    const int srow = t >> 2;       // 0..127
    const int scg0 = t & 3;

    // unit s: global k-tile tig=s>>2 (j = tig>>3, local til = tig&7);
    // idx: 0=A-kh0, 1=B-kh0, 2=A-kh1, 3=B-kh1 (2 loads each)
    auto issue_unit = [&](int s) {
        int tig = s >> 2, idx = s & 3;
        int j = tig >> 3, til = tig & 7;
        int kh = idx >> 1, isB = idx & 1;
        const bf16* g = isB ? (B + (long)j * dB + byoff) : (A + (long)j * dA + bxoff);
        int ld = isB ? ldb : lda;
        bf16* lp = (isB ? Bs : As) + ((tig & 1) * 2 + kh) * 8192;
        int k0 = til * 64 + kh * 32;
        #pragma unroll
        for (int jj = 0; jj < 2; ++jj) {
            int row = jj * 128 + srow;
            int cg = scg0 ^ ((row >> 1) & 3);
            gload_lds16(g + (long)row * ld + k0 + cg * 8, lp + (jj * 512 + t) * 8);
        }
    };

    auto store_tile = [&](int j) {
        const int row0 = bx * 256 + wm * 128;
        const int rq = lg * 4;
        if constexpr (EPI == 1) {
            bf16* Cz = C + (long)j * dC;
            const int col0 = by * 256 + wn * 64;
            #pragma unroll
            for (int i = 0; i < 8; ++i)
                #pragma unroll
                for (int n = 0; n < 4; ++n) {
                    const int col = col0 + n * 16 + lr;
                    #pragma unroll
                    for (int r = 0; r < 4; ++r)
                        Cz[(long)(row0 + i * 16 + rq + r) * ldc + col] = (bf16)exp2f(acc[i][n][r]);
                }
        } else {
            const int col0 = j * 768 + by * 256 + wn * 64;
            #pragma unroll
            for (int i = 0; i < 8; ++i) {
                const int row = row0 + i * 16 + rq;
                #pragma unroll
                for (int n = 0; n < 4; ++n) {
                    const int col = col0 + n * 16 + lr;
                    if (col < 1024) {
                        #pragma unroll
                        for (int r = 0; r < 4; ++r)
                            C[(long)(row + r) * 1024 + col] = (bf16)acc[i][n][r];
                    } else {
                        #pragma unroll
                        for (int r = 0; r < 4; ++r)
                            vbuf[(long)(row + r) * 512 + (col - 1024)] = (bf16)acc[i][n][r];
                    }
                }
            }
        }
        #pragma unroll
        for (int i = 0; i < 8; ++i)
            #pragma unroll
            for (int n = 0; n < 4; ++n) acc[i][n] = f32x4{0.f, 0.f, 0.f, 0.f};
    };

    #pragma unroll
    for (int s = 0; s < 6; ++s) issue_unit(s);
    asm volatile("s_waitcnt vmcnt(8)" ::: "memory");
    __builtin_amdgcn_s_barrier();
    asm volatile("" ::: "memory");

    bf16x8 bfr[4], af[4];

    #pragma unroll 1
    for (int gt = 0; gt < GT - 2; ++gt) {
        const bf16* AsT = As + (gt & 1) * 16384;
        const bf16* BsT = Bs + (gt & 1) * 16384;
        const int sb = 4 * gt + 6;
        PH(0, 0, sb + 0, -1)
        PH(1, 0, sb + 1, 8)
        PH(0, 1, sb + 2, -1)
        PH(1, 1, sb + 3, 8)
        if (NTILES > 1 && (gt & 7) == 7) store_tile(gt >> 3);
    }
    {   // gt = GT-2: last issues
        const bf16* AsT = As + ((GT - 2) & 1) * 16384;
        const bf16* BsT = Bs + ((GT - 2) & 1) * 16384;
        PH(0, 0, 4 * GT - 2, -1)
        PH(1, 0, 4 * GT - 1, 8)
        PH(0, 1, -1, -1)
        PH(1, 1, -1, 4)
    }
    {   // gt = GT-1: drain
        const bf16* AsT = As + ((GT - 1) & 1) * 16384;
        const bf16* BsT = Bs + ((GT - 1) & 1) * 16384;
        PH(0, 0, -1, -1)
        PH(1, 0, -1, 0)
        PH(0, 1, -1, -1)
        PH(1, 1, -1, -1)
    }
    store_tile(NTILES - 1);
}

// =====================================================================
// PV GEMM (round-11 verified): O[64 x 512] per block = P[64 x 4096] * V
// (via Vt[512][4096]), normalized by row sums from the staged P tiles
// (own-slot sums). 512 threads, 8 waves, BK=64, 2-tile-deep counted
// vmcnt. Grid (64,4) = 256 blocks = 1/CU, all batches in one dispatch.
// O stored with leading dim ldo (overwrites the dead q-half of qk).
// =====================================================================
__global__ __launch_bounds__(512, 1) void k_pv(
    const bf16* __restrict__ P, const bf16* __restrict__ Vt,
    bf16* __restrict__ O, int ldo) {
    __shared__ bf16 Bs[2][512 * 64];
    __shared__ bf16 As[2][64 * 64];
    __shared__ float linv[64];
    const int t = threadIdx.x;
    const int w = t >> 6, l = t & 63, lr = l & 15, lg = l >> 4;
    const int lr7 = lr & 7;
    const int sr = t >> 3, sc8 = t & 7, sr7 = sr & 7;
    const long zz = blockIdx.y;
    const int bx = blockIdx.x;

    const bf16* Pg = P + zz * ((long)4096 * 4096) + (long)(bx * 64 + sr) * 4096 + (sc8 ^ sr7) * 8;
    const bf16* Vg = Vt + zz * ((long)512 * 4096) + (long)sr * 4096 + (sc8 ^ sr7) * 8;

    auto issue = [&](int tile, int buf) {
        gload_lds16(Pg + tile * 64, As[buf] + t * 8);
        #pragma unroll
        for (int u = 0; u < 8; ++u)
            gload_lds16(Vg + (long)u * 64 * 4096 + tile * 64, Bs[buf] + u * 4096 + t * 8);
    };

    f32x4 acc[4][4];
    #pragma unroll
    for (int i = 0; i < 4; ++i)
        #pragma unroll
        for (int n = 0; n < 4; ++n) acc[i][n] = f32x4{0.f, 0.f, 0.f, 0.f};

    float lsum = 0.f;

    issue(0, 0);
    issue(1, 1);

    for (int ti = 0; ti < 64; ++ti) {
        if (ti < 63) { asm volatile("s_waitcnt vmcnt(9)" ::: "memory"); }
        else         { asm volatile("s_waitcnt vmcnt(0)" ::: "memory"); }
        __builtin_amdgcn_s_barrier();
        asm volatile("" ::: "memory");

        const bf16* Asb = As[ti & 1];
        const bf16* Bsb = Bs[ti & 1];

        // own-slot row-partial sum (row sr) -- P as quantized to bf16
        {
            bf16x8 sv = *(const bf16x8*)(Asb + t * 8);
            #pragma unroll
            for (int j = 0; j < 8; ++j) lsum += (float)sv[j];
        }

        __builtin_amdgcn_s_setprio(1);
        #pragma unroll
        for (int kk = 0; kk < 2; ++kk) {
            bf16x8 af[4], bfv[4];
            #pragma unroll
            for (int mi = 0; mi < 4; ++mi)
                af[mi] = *(const bf16x8*)(Asb + (mi * 16 + lr) * 64 + (((kk * 4 + lg) ^ lr7) * 8));
            #pragma unroll
            for (int n = 0; n < 4; ++n)
                bfv[n] = *(const bf16x8*)(Bsb + (w * 64 + n * 16 + lr) * 64 + (((kk * 4 + lg) ^ lr7) * 8));
            #pragma unroll
            for (int mi = 0; mi < 4; ++mi)
                #pragma unroll
                for (int n = 0; n < 4; ++n)
                    acc[mi][n] = __builtin_amdgcn_mfma_f32_16x16x32_bf16(af[mi], bfv[n], acc[mi][n], 0, 0, 0);
        }
        __builtin_amdgcn_s_setprio(0);

        __builtin_amdgcn_s_barrier();
        asm volatile("" ::: "memory");
        if (ti < 62) issue(ti + 2, ti & 1);
    }

    lsum += __shfl_xor(lsum, 1);
    lsum += __shfl_xor(lsum, 2);
    lsum += __shfl_xor(lsum, 4);
    if (sc8 == 0) linv[sr] = 1.f / lsum;
    asm volatile("s_waitcnt lgkmcnt(0)" ::: "memory");
    __builtin_amdgcn_s_barrier();
    asm volatile("" ::: "memory");

    bf16* Oz = O + zz * ((long)4096 * ldo);
    #pragma unroll
    for (int mi = 0; mi < 4; ++mi) {
        float4 lv = *(const float4*)&linv[mi * 16 + lg * 4];
        #pragma unroll
        for (int n = 0; n < 4; ++n) {
            const long base = (long)(bx * 64 + mi * 16 + lg * 4) * ldo + w * 64 + n * 16 + lr;
            Oz[base]           = (bf16)(acc[mi][n][0] * lv.x);
            Oz[base + ldo]     = (bf16)(acc[mi][n][1] * lv.y);
            Oz[base + 2 * ldo] = (bf16)(acc[mi][n][2] * lv.z);
            Oz[base + 3 * ldo] = (bf16)(acc[mi][n][3] * lv.w);
        }
    }
}

// =====================================================================
// 256x128 tile, BK=64, 8-wave (4M x 2N), 8-phase, counted vmcnt.
// proj epilogue: f32 + bias, coalesced store [row][512].
// =====================================================================
#define PH128(nh, kk, S_, WN)                                                      \
  {                                                                                \
    if ((nh) == 0) {                                                               \
      _Pragma("unroll")                                                            \
      for (int i = 0; i < 4; ++i) {                                                \
        int row = wm * 64 + i * 16 + lr;                                           \
        int cg = lg ^ ((row >> 1) & 3);                                            \
        af[i] = *(const bf16x8*)(AsT + (kk) * 8192 + row * 32 + cg * 8);           \
      }                                                                            \
    }                                                                              \
    _Pragma("unroll")                                                              \
    for (int j = 0; j < 2; ++j) {                                                  \
      int row = wn * 64 + ((nh) * 2 + j) * 16 + lr;                                \
      int cg = lg ^ ((row >> 1) & 3);                                              \
      bfr[j] = *(const bf16x8*)(BsT + (kk) * 4096 + row * 32 + cg * 8);            \
    }                                                                              \
    if ((S_) >= 0) issue_unit(S_);                                                 \
    __builtin_amdgcn_s_barrier();                                                  \
    asm volatile("" ::: "memory");                                                 \
    __builtin_amdgcn_s_setprio(1);                                                 \
    _Pragma("unroll")                                                              \
    for (int i = 0; i < 4; ++i)                                                    \
      _Pragma("unroll")                                                            \
      for (int j = 0; j < 2; ++j)                                                  \
        acc[i][(nh) * 2 + j] =                                                     \
            __builtin_amdgcn_mfma_f32_16x16x32_bf16(af[i], bfr[j],                 \
                                                    acc[i][(nh) * 2 + j], 0, 0, 0);\
    __builtin_amdgcn_s_setprio(0);                                                 \
    if constexpr ((WN) >= 0)                                                       \
      asm volatile("s_waitcnt vmcnt(%0)" ::"i"(WN) : "memory");                    \
    __builtin_amdgcn_s_barrier();                                                  \
    asm volatile("" ::: "memory");                                                 \
  }

__global__ __launch_bounds__(512, 2) void gemm_proj(
    const bf16* __restrict__ A, int lda,
    const bf16* __restrict__ B, int ldb,
    const float* __restrict__ bias,
    float* __restrict__ Cout) {
    __shared__ bf16 As[2 * 2 * 256 * 32];   // 64 KB
    __shared__ bf16 Bs[2 * 2 * 128 * 32];   // 32 KB
    const int t = threadIdx.x;
    const int wid = t >> 6, l = t & 63;
    const int wm = wid >> 1, wn = wid & 1;   // 4M x 2N waves, wave tile 64x64
    const int lr = l & 15;
    const int lg = l >> 4;

    const int gx = gridDim.x;
    int nwg = gx * gridDim.y;
    int flat = blockIdx.y * gx + blockIdx.x;
    if ((nwg & 7) == 0) { int qq = nwg >> 3; flat = (flat & 7) * qq + (flat >> 3); }
    const int bx = flat % gx, by = flat / gx;

    const bf16* Ab = A + (long)bx * 256 * lda;
    const bf16* Bb = B + (long)by * 128 * ldb;

    const int NT = 8;            // K = 512
    const int NT4 = 32;

    f32x4 acc[4][4];
    #pragma unroll
    for (int i = 0; i < 4; ++i)
        #pragma unroll
        for (int n = 0; n < 4; ++n) acc[i][n] = f32x4{0.f, 0.f, 0.f, 0.f};

    const int srow = t >> 2;       // 0..127
    const int scg0 = t & 3;

    auto issue_unit = [&](int s) {
        int ti = s >> 2, idx = s & 3;
        int kh = idx >> 1, isB = idx & 1;
        int k0 = ti * 64 + kh * 32;
        if (isB) {
            bf16* lp = Bs + ((ti & 1) * 2 + kh) * 4096;
            int cg = scg0 ^ ((srow >> 1) & 3);
            gload_lds16(Bb + (long)srow * ldb + k0 + cg * 8, lp + t * 8);
        } else {
            bf16* lp = As + ((ti & 1) * 2 + kh) * 8192;
            #pragma unroll
            for (int j = 0; j < 2; ++j) {
                int row = j * 128 + srow;
                int cg = scg0 ^ ((row >> 1) & 3);
                gload_lds16(Ab + (long)row * lda + k0 + cg * 8, lp + (j * 512 + t) * 8);
            }
        }
    };

    #pragma unroll
    for (int s = 0; s < 6; ++s) issue_unit(s);
    asm volatile("s_waitcnt vmcnt(6)" ::: "memory");
    __builtin_amdgcn_s_barrier();
    asm volatile("" ::: "memory");

    bf16x8 bfr[2], af[4];

    for (int ti = 0; ti < NT - 2; ++ti) {
        const bf16* AsT = As + (ti & 1) * 16384;
        const bf16* BsT = Bs + (ti & 1) * 8192;
        const int sb = 4 * ti + 6;
        PH128(0, 0, sb + 0, -1)
        PH128(1, 0, sb + 1, 6)
        PH128(0, 1, sb + 2, -1)
        PH128(1, 1, sb + 3, 6)
    }
    {
        const bf16* AsT = As + ((NT - 2) & 1) * 16384;
        const bf16* BsT = Bs + ((NT - 2) & 1) * 8192;
        PH128(0, 0, NT4 - 2, -1)
        PH128(1, 0, NT4 - 1, 6)
        PH128(0, 1, -1, -1)
        PH128(1, 1, -1, 3)
    }
    {
        const bf16* AsT = As + ((NT - 1) & 1) * 16384;
        const bf16* BsT = Bs + ((NT - 1) & 1) * 8192;
        PH128(0, 0, -1, -1)
        PH128(1, 0, -1, 0)
        PH128(0, 1, -1, -1)
        PH128(1, 1, -1, -1)
    }

    const int row0 = bx * 256 + wm * 64;
    const int col0 = by * 128 + wn * 64;
    const int rq = lg * 4;
    #pragma unroll
    for (int i = 0; i < 4; ++i)
        #pragma unroll
        for (int n = 0; n < 4; ++n) {
            const int col = col0 + n * 16 + lr;
            #pragma unroll
            for (int r = 0; r < 4; ++r)
                Cout[(long)(row0 + i * 16 + rq + r) * 512 + col] = acc[i][n][r] + bias[col];
        }
}

// ---------------- proj-out [nt][512] f32 -> NCHW + residual ----------------
__global__ __launch_bounds__(256) void k_final(const float* __restrict__ pb,
                                               const float* __restrict__ x,
                                               float* __restrict__ out) {
    __shared__ float tile[64][65];
    const int bid = blockIdx.x;
    const int n = bid >> 9, rem = bid & 511;
    const int s0 = (rem >> 3) * 64, c0 = (rem & 7) * 64;
    const int tid = threadIdx.x;
    #pragma unroll
    for (int i = 0; i < 16; ++i) {
        const int sl = (tid >> 6) * 16 + i;
        const int cl = tid & 63;
        tile[sl][cl] = pb[((long)(n * 4096 + s0 + sl)) * 512 + c0 + cl];
    }
    __syncthreads();
    #pragma unroll
    for (int i = 0; i < 16; ++i) {
        const int cl = (tid >> 6) * 16 + i;
        const int sl = tid & 63;
        const long oi = ((long)(n * 512 + c0 + cl)) * 4096 + s0 + sl;
        out[oi] = tile[sl][cl] + x[oi];
    }
}

extern "C" void kernel_launch(void* const* d_in, const int* in_sizes, int n_in,
                              void* d_out, int out_size, void* d_ws, size_t ws_size,
                              hipStream_t stream) {
    const float* x     = (const float*)d_in[0];
    const float* gnw   = (const float*)d_in[1];
    const float* gnb   = (const float*)d_in[2];
    const float* qkvw  = (const float*)d_in[3];
    const float* projw = (const float*)d_in[4];
    const float* projb = (const float*)d_in[5];

    char* ws = (char*)d_ws;
    size_t off = 0;
    auto alloc = [&](size_t bytes) {
        void* p = ws + off;
        off += (bytes + 255) & ~(size_t)255;
        return p;
    };
    // fixed: weights 2.1 MB + qk 33.55 MB + Vt 16.78 MB
    bf16*   qwb   = (bf16*)alloc((size_t)1536 * 512 * 2);
    bf16*   pwb   = (bf16*)alloc((size_t)512 * 512 * 2);
    float2* stats = (float2*)alloc((size_t)128 * 8);
    bf16*   qk    = (bf16*)alloc((size_t)16384 * 1024 * 2);  // q|k; q-half becomes O
    bf16*   Vt    = (bf16*)alloc((size_t)4 * 512 * 4096 * 2);
    // aliased region R (134.2 MB): tbuf+vbuf early -> Sbuf(4z) -> pjout f32
    char*   R     = (char*)alloc((size_t)4 * 4096 * 4096 * 2);
    bf16*   tbuf  = (bf16*)R;                                  // tokens [16384][512]
    bf16*   vbuf  = (bf16*)(R + (size_t)16384 * 512 * 2);      // v [16384][512]
    bf16*   Sbuf  = (bf16*)R;                                  // P, all 4 z
    float*  pjout = (float*)R;                                 // proj f32 [16384][512]

    k_gnstats<<<128, 256, 0, stream>>>(x, stats);
    k_norm_t<<<2048, 256, 0, stream>>>(x, gnw, gnb, stats, tbuf);
    k_convw<<<4096, 256, 0, stream>>>(qkvw, projw, qwb, pwb);

    // qkv: q,k -> qk [16384][1024]; v -> vbuf [16384][512]
    // Persistent: 2 col-tile-triples chained, grid (64,3) = 192 blocks
    gemm256p<2, 2><<<dim3(64, 3), 512, 0, stream>>>(
        tbuf, 512, 0, qwb, 512, (long)768 * 512, qk, 1024, 0, vbuf);

    k_vt<<<2048, 256, 0, stream>>>(vbuf, Vt);

    const long QZ = (long)4096 * 1024;   // z-stride in qk
    const long SZ = (long)4096 * 4096;   // z-stride in Sbuf
    // P = exp2(q k^T): persistent over all 4 z, grid (16,16) = 256 blocks (1/CU)
    gemm256p<4, 1><<<dim3(16, 16), 512, 0, stream>>>(
        qk, 1024, QZ,
        qk + 512, 1024, QZ,
        Sbuf, 4096, SZ, nullptr);
    // O = (P * V) / rowsum, all 4 batches, 256 blocks = 1/CU
    k_pv<<<dim3(64, 4), 512, 0, stream>>>(Sbuf, Vt, qk, 1024);

    // proj: [16384 x 512] f32 + bias (A = O in qk q-half, lda=1024)
    gemm_proj<<<dim3(64, 4), 512, 0, stream>>>(
        qk, 1024, pwb, 512, projb, pjout);

    // transpose back + residual
    k_final<<<2048, 256, 0, stream>>>(pjout, x, (float*)d_out);
}

// Round 14
// 311.793 us; speedup vs baseline: 1.0754x; 1.0297x over previous
//
#include <hip/hip_runtime.h>
#include <hip/hip_bf16.h>

typedef __bf16 bf16;
typedef __bf16 bf16x8 __attribute__((ext_vector_type(8)));
typedef float f32x4 __attribute__((ext_vector_type(4)));

// ---------------- async global->LDS (width 16) ----------------
__device__ __forceinline__ void gload_lds16(const bf16* g, bf16* l) {
    __builtin_amdgcn_global_load_lds(
        (const __attribute__((address_space(1))) void*)g,
        (__attribute__((address_space(3))) void*)l, 16, 0, 0);
}

// ---------------- GroupNorm stats: one block per (n,group) ----------------
__global__ __launch_bounds__(256) void k_gnstats(const float* __restrict__ x,
                                                 float2* __restrict__ stats) {
    const int g = blockIdx.x;            // 0..127
    const float4* p = (const float4*)(x + (long)g * 65536);
    float s = 0.f, ss = 0.f;
    #pragma unroll 8
    for (int i = 0; i < 64; ++i) {
        float4 v = p[threadIdx.x + i * 256];
        s  += v.x + v.y + v.z + v.w;
        ss += v.x * v.x + v.y * v.y + v.z * v.z + v.w * v.w;
    }
    #pragma unroll
    for (int off = 32; off >= 1; off >>= 1) {
        s  += __shfl_down(s, off);
        ss += __shfl_down(ss, off);
    }
    __shared__ float rs[4], rss[4];
    if ((threadIdx.x & 63) == 0) { rs[threadIdx.x >> 6] = s; rss[threadIdx.x >> 6] = ss; }
    __syncthreads();
    if (threadIdx.x == 0) {
        float S  = rs[0] + rs[1] + rs[2] + rs[3];
        float SS = rss[0] + rss[1] + rss[2] + rss[3];
        float mu = S * (1.f / 65536.f);
        float var = SS * (1.f / 65536.f) - mu * mu;
        stats[g] = make_float2(mu, rsqrtf(var + 1e-5f));
    }
}

// ---------------- normalize + transpose NCHW -> tokens [nt][512] bf16 ----------------
__global__ __launch_bounds__(256) void k_norm_t(const float* __restrict__ x,
                                                const float* __restrict__ w,
                                                const float* __restrict__ b,
                                                const float2* __restrict__ stats,
                                                bf16* __restrict__ t) {
    __shared__ float tile[64][65];
    const int bid = blockIdx.x;
    const int n = bid >> 9, rem = bid & 511;
    const int s0 = (rem >> 3) * 64, c0 = (rem & 7) * 64;
    const int tid = threadIdx.x;
    const int sl = tid & 63, cq = tid >> 6;
    #pragma unroll
    for (int i = 0; i < 16; ++i) {
        const int cl = cq * 16 + i;
        const int c = c0 + cl;
        const float2 st = stats[n * 32 + (c >> 4)];
        const float v = x[((long)(n * 512 + c)) * 4096 + s0 + sl];
        tile[cl][sl] = (v - st.x) * st.y * w[c] + b[c];
    }
    __syncthreads();
    #pragma unroll
    for (int i = 0; i < 16; ++i) {
        const int sl2 = cq * 16 + i;
        const int cl2 = tid & 63;
        t[((long)(n * 4096 + s0 + sl2)) * 512 + c0 + cl2] = (bf16)tile[cl2][sl2];
    }
}

// ---------------- weight conversion (fold log2e/sqrt(512) into q rows) ----------------
__global__ __launch_bounds__(256) void k_convw(const float* __restrict__ qw,
                                               const float* __restrict__ pw,
                                               bf16* __restrict__ qwb,
                                               bf16* __restrict__ pwb) {
    const int i = blockIdx.x * 256 + threadIdx.x;
    if (i < 786432) {
        float v = qw[i];
        if (i < 512 * 512) v *= 0.06376281516217733f;  // log2(e)/sqrt(512)
        qwb[i] = (bf16)v;
    } else {
        const int j = i - 786432;
        pwb[j] = (bf16)pw[j];
    }
}

// ---------------- transpose vbuf [16384][512] -> Vt[n][512][4096] ----------------
__global__ __launch_bounds__(256) void k_vt(const bf16* __restrict__ vbuf,
                                            bf16* __restrict__ Vt) {
    __shared__ bf16 tile[64][66];
    const int bid = blockIdx.x;
    const int n = bid >> 9, rem = bid & 511;
    const int s0 = (rem >> 3) * 64, d0 = (rem & 7) * 64;
    const int tid = threadIdx.x;
    #pragma unroll
    for (int i = 0; i < 16; ++i) {
        const int sl = (tid >> 6) * 16 + i;
        const int dl = tid & 63;
        tile[sl][dl] = vbuf[((long)(n * 4096 + s0 + sl)) * 512 + d0 + dl];
    }
    __syncthreads();
    #pragma unroll
    for (int i = 0; i < 16; ++i) {
        const int dl = (tid >> 6) * 16 + i;
        const int sl = tid & 63;
        Vt[((long)(n * 512 + d0 + dl)) * 4096 + s0 + sl] = tile[sl][dl];
    }
}

// =====================================================================
// 256x256 tile, BK=64, 8-wave, 8-phase GEMM with counted vmcnt (T3+T4+T5)
// LDS swizzle: granule ^= (row>>1)&3  (2-way banks = free)
// EPI 1: P = exp2(acc) bf16 store (scores in log2 domain).
// EPI 2: QKV split store -- q,k into C [row][1024]; v into vbuf [row][512].
// =====================================================================
#define PH(mh, kk, S_, WN)                                                         \
  {                                                                                \
    if ((mh) == 0) {                                                               \
      _Pragma("unroll")                                                            \
      for (int n = 0; n < 4; ++n) {                                                \
        int row = wn * 64 + n * 16 + lr;                                           \
        int cg = lg ^ ((row >> 1) & 3);                                            \
        bfr[n] = *(const bf16x8*)(BsT + (kk) * 8192 + row * 32 + cg * 8);          \
      }                                                                            \
    }                                                                              \
    _Pragma("unroll")                                                              \
    for (int i = 0; i < 4; ++i) {                                                  \
      int row = wm * 128 + ((mh) * 4 + i) * 16 + lr;                               \
      int cg = lg ^ ((row >> 1) & 3);                                              \
      af[i] = *(const bf16x8*)(AsT + (kk) * 8192 + row * 32 + cg * 8);             \
    }                                                                              \
    if ((S_) >= 0) issue_unit(S_);                                                 \
    __builtin_amdgcn_s_barrier();                                                  \
    asm volatile("" ::: "memory");                                                 \
    __builtin_amdgcn_s_setprio(1);                                                 \
    _Pragma("unroll")                                                              \
    for (int i = 0; i < 4; ++i)                                                    \
      _Pragma("unroll")                                                            \
      for (int n = 0; n < 4; ++n)                                                  \
        acc[(mh) * 4 + i][n] =                                                     \
            __builtin_amdgcn_mfma_f32_16x16x32_bf16(af[i], bfr[n],                 \
                                                    acc[(mh) * 4 + i][n], 0, 0, 0);\
    __builtin_amdgcn_s_setprio(0);                                                 \
    if constexpr ((WN) >= 0)                                                       \
      asm volatile("s_waitcnt vmcnt(%0)" ::"i"(WN) : "memory");                    \
    __builtin_amdgcn_s_barrier();                                                  \
    asm volatile("" ::: "memory");                                                 \
  }

template <int EPI>
__global__ __launch_bounds__(512, 2) void gemm256(
    const bf16* __restrict__ A, int lda, long aZ,
    const bf16* __restrict__ B, int ldb, long bZ,
    bf16* __restrict__ C, int ldc, long cZ, int K,
    bf16* __restrict__ vbuf) {
    __shared__ bf16 As[2 * 2 * 256 * 32];
    __shared__ bf16 Bs[2 * 2 * 256 * 32];
    const int t = threadIdx.x;
    const int wid = t >> 6, l = t & 63;
    const int wm = wid >> 2, wn = wid & 3;     // 2 x 4 waves
    const int lr = l & 15;
    const int lg = l >> 4;                     // fragment col-group 0..3
    const long z = blockIdx.z;

    const int gx = gridDim.x;
    int nwg = gx * gridDim.y;
    int flat = blockIdx.y * gx + blockIdx.x;
    if ((nwg & 7) == 0) { int qq = nwg >> 3; flat = (flat & 7) * qq + (flat >> 3); }
    const int bx = flat % gx, by = flat / gx;

    const bf16* Ab = A + z * aZ + (long)bx * 256 * lda;
    const bf16* Bb = B + z * bZ + (long)by * 256 * ldb;

    const int NT = K >> 6;
    const int NT4 = NT << 2;

    f32x4 acc[8][4];
    #pragma unroll
    for (int i = 0; i < 8; ++i)
        #pragma unroll
        for (int n = 0; n < 4; ++n) acc[i][n] = f32x4{0.f, 0.f, 0.f, 0.f};

    const int srow = t >> 2;       // 0..127
    const int scg0 = t & 3;

    auto issue_unit = [&](int s) {
        int ti = s >> 2, idx = s & 3;
        int kh = idx >> 1, isB = idx & 1;
        const bf16* g = isB ? Bb : Ab;
        int ld = isB ? ldb : lda;
        bf16* lp = (isB ? Bs : As) + ((ti & 1) * 2 + kh) * 8192;
        int k0 = ti * 64 + kh * 32;
        #pragma unroll
        for (int j = 0; j < 2; ++j) {
            int row = j * 128 + srow;
            int cg = scg0 ^ ((row >> 1) & 3);
            gload_lds16(g + (long)row * ld + k0 + cg * 8, lp + (j * 512 + t) * 8);
        }
    };

    #pragma unroll
    for (int s = 0; s < 6; ++s) issue_unit(s);
    asm volatile("s_waitcnt vmcnt(8)" ::: "memory");
    __builtin_amdgcn_s_barrier();
    asm volatile("" ::: "memory");

    bf16x8 bfr[4], af[4];

    for (int ti = 0; ti < NT - 2; ++ti) {
        const bf16* AsT = As + (ti & 1) * 16384;
        const bf16* BsT = Bs + (ti & 1) * 16384;
        const int sb = 4 * ti + 6;
        PH(0, 0, sb + 0, -1)
        PH(1, 0, sb + 1, 8)
        PH(0, 1, sb + 2, -1)
        PH(1, 1, sb + 3, 8)
    }
    {
        const bf16* AsT = As + ((NT - 2) & 1) * 16384;
        const bf16* BsT = Bs + ((NT - 2) & 1) * 16384;
        PH(0, 0, NT4 - 2, -1)
        PH(1, 0, NT4 - 1, 8)
        PH(0, 1, -1, -1)
        PH(1, 1, -1, 4)
    }
    {
        const bf16* AsT = As + ((NT - 1) & 1) * 16384;
        const bf16* BsT = Bs + ((NT - 1) & 1) * 16384;
        PH(0, 0, -1, -1)
        PH(1, 0, -1, 0)
        PH(0, 1, -1, -1)
        PH(1, 1, -1, -1)
    }

    const int row0 = bx * 256 + wm * 128;
    const int col0 = by * 256 + wn * 64;
    const int rq = lg * 4;

    if (EPI == 1) {
        bf16* Cz = C + z * cZ;
        #pragma unroll
        for (int i = 0; i < 8; ++i)
            #pragma unroll
            for (int n = 0; n < 4; ++n) {
                const int col = col0 + n * 16 + lr;
                #pragma unroll
                for (int r = 0; r < 4; ++r)
                    Cz[(long)(row0 + i * 16 + rq + r) * ldc + col] = (bf16)exp2f(acc[i][n][r]);
            }
    } else {
        // QKV: q,k -> C [row][1024]; v -> vbuf [row][512]  (both coalesced)
        #pragma unroll
        for (int i = 0; i < 8; ++i) {
            const int row = row0 + i * 16 + rq;
            #pragma unroll
            for (int n = 0; n < 4; ++n) {
                const int col = col0 + n * 16 + lr;
                if (col < 1024) {
                    #pragma unroll
                    for (int r = 0; r < 4; ++r)
                        C[(long)(row + r) * 1024 + col] = (bf16)acc[i][n][r];
                } else {
                    #pragma unroll
                    for (int r = 0; r < 4; ++r)
                        vbuf[(long)(row + r) * 512 + (col - 1024)] = (bf16)acc[i][n][r];
                }
            }
        }
    }
}

// =====================================================================
// PV GEMM (round-11 structure + XCD z-pin remap): O[64 x 512] per block
// = P[64 x 4096] * V (via Vt[512][4096]) / rowsum (own-slot sums).
// 512 threads, 8 waves, BK=64, 2-tile-deep counted vmcnt, 1 dispatch.
// XCD remap: blocks on XCD x share z = x>>1 so Vt_z (4MB) stays in that
// XCD's L2 (round-12 evidence: FETCH 131->82 MB). Bijective:
// f -> (xcd=f&7, idx=f>>3) -> (zz=xcd>>1, bx=(xcd&1)*32+idx).
// O stored with leading dim ldo (overwrites the dead q-half of qk).
// =====================================================================
__global__ __launch_bounds__(512, 1) void k_pv(
    const bf16* __restrict__ P, const bf16* __restrict__ Vt,
    bf16* __restrict__ O, int ldo) {
    __shared__ bf16 Bs[2][512 * 64];
    __shared__ bf16 As[2][64 * 64];
    __shared__ float linv[64];
    const int t = threadIdx.x;
    const int w = t >> 6, l = t & 63, lr = l & 15, lg = l >> 4;
    const int lr7 = lr & 7;
    const int sr = t >> 3, sc8 = t & 7, sr7 = sr & 7;

    // XCD z-pin remap (grid (64,4) = 256 blocks)
    const int f = blockIdx.y * 64 + blockIdx.x;
    const int xcd = f & 7, idx = f >> 3;
    const long zz = xcd >> 1;
    const int bx = (xcd & 1) * 32 + idx;

    const bf16* Pg = P + zz * ((long)4096 * 4096) + (long)(bx * 64 + sr) * 4096 + (sc8 ^ sr7) * 8;
    const bf16* Vg = Vt + zz * ((long)512 * 4096) + (long)sr * 4096 + (sc8 ^ sr7) * 8;

    auto issue = [&](int tile, int buf) {
        gload_lds16(Pg + tile * 64, As[buf] + t * 8);
        #pragma unroll
        for (int u = 0; u < 8; ++u)
            gload_lds16(Vg + (long)u * 64 * 4096 + tile * 64, Bs[buf] + u * 4096 + t * 8);
    };

    f32x4 acc[4][4];
    #pragma unroll
    for (int i = 0; i < 4; ++i)
        #pragma unroll
        for (int n = 0; n < 4; ++n) acc[i][n] = f32x4{0.f, 0.f, 0.f, 0.f};

    float lsum = 0.f;

    issue(0, 0);
    issue(1, 1);

    for (int ti = 0; ti < 64; ++ti) {
        if (ti < 63) { asm volatile("s_waitcnt vmcnt(9)" ::: "memory"); }
        else         { asm volatile("s_waitcnt vmcnt(0)" ::: "memory"); }
        __builtin_amdgcn_s_barrier();
        asm volatile("" ::: "memory");

        const bf16* Asb = As[ti & 1];
        const bf16* Bsb = Bs[ti & 1];

        // own-slot row-partial sum (row sr) -- P as quantized to bf16
        {
            bf16x8 sv = *(const bf16x8*)(Asb + t * 8);
            #pragma unroll
            for (int j = 0; j < 8; ++j) lsum += (float)sv[j];
        }

        __builtin_amdgcn_s_setprio(1);
        #pragma unroll
        for (int kk = 0; kk < 2; ++kk) {
            bf16x8 af[4], bfv[4];
            #pragma unroll
            for (int mi = 0; mi < 4; ++mi)
                af[mi] = *(const bf16x8*)(Asb + (mi * 16 + lr) * 64 + (((kk * 4 + lg) ^ lr7) * 8));
            #pragma unroll
            for (int n = 0; n < 4; ++n)
                bfv[n] = *(const bf16x8*)(Bsb + (w * 64 + n * 16 + lr) * 64 + (((kk * 4 + lg) ^ lr7) * 8));
            #pragma unroll
            for (int mi = 0; mi < 4; ++mi)
                #pragma unroll
                for (int n = 0; n < 4; ++n)
                    acc[mi][n] = __builtin_amdgcn_mfma_f32_16x16x32_bf16(af[mi], bfv[n], acc[mi][n], 0, 0, 0);
        }
        __builtin_amdgcn_s_setprio(0);

        __builtin_amdgcn_s_barrier();
        asm volatile("" ::: "memory");
        if (ti < 62) issue(ti + 2, ti & 1);
    }

    lsum += __shfl_xor(lsum, 1);
    lsum += __shfl_xor(lsum, 2);
    lsum += __shfl_xor(lsum, 4);
    if (sc8 == 0) linv[sr] = 1.f / lsum;
    asm volatile("s_waitcnt lgkmcnt(0)" ::: "memory");
    __builtin_amdgcn_s_barrier();
    asm volatile("" ::: "memory");

    bf16* Oz = O + zz * ((long)4096 * ldo);
    #pragma unroll
    for (int mi = 0; mi < 4; ++mi) {
        float4 lv = *(const float4*)&linv[mi * 16 + lg * 4];
        #pragma unroll
        for (int n = 0; n < 4; ++n) {
            const long base = (long)(bx * 64 + mi * 16 + lg * 4) * ldo + w * 64 + n * 16 + lr;
            Oz[base]           = (bf16)(acc[mi][n][0] * lv.x);
            Oz[base + ldo]     = (bf16)(acc[mi][n][1] * lv.y);
            Oz[base + 2 * ldo] = (bf16)(acc[mi][n][2] * lv.z);
            Oz[base + 3 * ldo] = (bf16)(acc[mi][n][3] * lv.w);
        }
    }
}

// =====================================================================
// 256x128 tile, BK=64, 8-wave (4M x 2N), 8-phase, counted vmcnt.
// proj epilogue: f32 + bias, coalesced store [row][512].
// =====================================================================
#define PH128(nh, kk, S_, WN)                                                      \
  {                                                                                \
    if ((nh) == 0) {                                                               \
      _Pragma("unroll")                                                            \
      for (int i = 0; i < 4; ++i) {                                                \
        int row = wm * 64 + i * 16 + lr;                                           \
        int cg = lg ^ ((row >> 1) & 3);                                            \
        af[i] = *(const bf16x8*)(AsT + (kk) * 8192 + row * 32 + cg * 8);           \
      }                                                                            \
    }                                                                              \
    _Pragma("unroll")                                                              \
    for (int j = 0; j < 2; ++j) {                                                  \
      int row = wn * 64 + ((nh) * 2 + j) * 16 + lr;                                \
      int cg = lg ^ ((row >> 1) & 3);                                              \
      bfr[j] = *(const bf16x8*)(BsT + (kk) * 4096 + row * 32 + cg * 8);            \
    }                                                                              \
    if ((S_) >= 0) issue_unit(S_);                                                 \
    __builtin_amdgcn_s_barrier();                                                  \
    asm volatile("" ::: "memory");                                                 \
    __builtin_amdgcn_s_setprio(1);                                                 \
    _Pragma("unroll")                                                              \
    for (int i = 0; i < 4; ++i)                                                    \
      _Pragma("unroll")                                                            \
      for (int j = 0; j < 2; ++j)                                                  \
        acc[i][(nh) * 2 + j] =                                                     \
            __builtin_amdgcn_mfma_f32_16x16x32_bf16(af[i], bfr[j],                 \
                                                    acc[i][(nh) * 2 + j], 0, 0, 0);\
    __builtin_amdgcn_s_setprio(0);                                                 \
    if constexpr ((WN) >= 0)                                                       \
      asm volatile("s_waitcnt vmcnt(%0)" ::"i"(WN) : "memory");                    \
    __builtin_amdgcn_s_barrier();                                                  \
    asm volatile("" ::: "memory");                                                 \
  }

__global__ __launch_bounds__(512, 2) void gemm_proj(
    const bf16* __restrict__ A, int lda,
    const bf16* __restrict__ B, int ldb,
    const float* __restrict__ bias,
    float* __restrict__ Cout) {
    __shared__ bf16 As[2 * 2 * 256 * 32];   // 64 KB
    __shared__ bf16 Bs[2 * 2 * 128 * 32];   // 32 KB
    const int t = threadIdx.x;
    const int wid = t >> 6, l = t & 63;
    const int wm = wid >> 1, wn = wid & 1;   // 4M x 2N waves, wave tile 64x64
    const int lr = l & 15;
    const int lg = l >> 4;

    const int gx = gridDim.x;
    int nwg = gx * gridDim.y;
    int flat = blockIdx.y * gx + blockIdx.x;
    if ((nwg & 7) == 0) { int qq = nwg >> 3; flat = (flat & 7) * qq + (flat >> 3); }
    const int bx = flat % gx, by = flat / gx;

    const bf16* Ab = A + (long)bx * 256 * lda;
    const bf16* Bb = B + (long)by * 128 * ldb;

    const int NT = 8;            // K = 512
    const int NT4 = 32;

    f32x4 acc[4][4];
    #pragma unroll
    for (int i = 0; i < 4; ++i)
        #pragma unroll
        for (int n = 0; n < 4; ++n) acc[i][n] = f32x4{0.f, 0.f, 0.f, 0.f};

    const int srow = t >> 2;       // 0..127
    const int scg0 = t & 3;

    auto issue_unit = [&](int s) {
        int ti = s >> 2, idx = s & 3;
        int kh = idx >> 1, isB = idx & 1;
        int k0 = ti * 64 + kh * 32;
        if (isB) {
            bf16* lp = Bs + ((ti & 1) * 2 + kh) * 4096;
            int cg = scg0 ^ ((srow >> 1) & 3);
            gload_lds16(Bb + (long)srow * ldb + k0 + cg * 8, lp + t * 8);
        } else {
            bf16* lp = As + ((ti & 1) * 2 + kh) * 8192;
            #pragma unroll
            for (int j = 0; j < 2; ++j) {
                int row = j * 128 + srow;
                int cg = scg0 ^ ((row >> 1) & 3);
                gload_lds16(Ab + (long)row * lda + k0 + cg * 8, lp + (j * 512 + t) * 8);
            }
        }
    };

    #pragma unroll
    for (int s = 0; s < 6; ++s) issue_unit(s);
    asm volatile("s_waitcnt vmcnt(6)" ::: "memory");
    __builtin_amdgcn_s_barrier();
    asm volatile("" ::: "memory");

    bf16x8 bfr[2], af[4];

    for (int ti = 0; ti < NT - 2; ++ti) {
        const bf16* AsT = As + (ti & 1) * 16384;
        const bf16* BsT = Bs + (ti & 1) * 8192;
        const int sb = 4 * ti + 6;
        PH128(0, 0, sb + 0, -1)
        PH128(1, 0, sb + 1, 6)
        PH128(0, 1, sb + 2, -1)
        PH128(1, 1, sb + 3, 6)
    }
    {
        const bf16* AsT = As + ((NT - 2) & 1) * 16384;
        const bf16* BsT = Bs + ((NT - 2) & 1) * 8192;
        PH128(0, 0, NT4 - 2, -1)
        PH128(1, 0, NT4 - 1, 6)
        PH128(0, 1, -1, -1)
        PH128(1, 1, -1, 3)
    }
    {
        const bf16* AsT = As + ((NT - 1) & 1) * 16384;
        const bf16* BsT = Bs + ((NT - 1) & 1) * 8192;
        PH128(0, 0, -1, -1)
        PH128(1, 0, -1, 0)
        PH128(0, 1, -1, -1)
        PH128(1, 1, -1, -1)
    }

    const int row0 = bx * 256 + wm * 64;
    const int col0 = by * 128 + wn * 64;
    const int rq = lg * 4;
    #pragma unroll
    for (int i = 0; i < 4; ++i)
        #pragma unroll
        for (int n = 0; n < 4; ++n) {
            const int col = col0 + n * 16 + lr;
            #pragma unroll
            for (int r = 0; r < 4; ++r)
                Cout[(long)(row0 + i * 16 + rq + r) * 512 + col] = acc[i][n][r] + bias[col];
        }
}

// ---------------- proj-out [nt][512] f32 -> NCHW + residual ----------------
__global__ __launch_bounds__(256) void k_final(const float* __restrict__ pb,
                                               const float* __restrict__ x,
                                               float* __restrict__ out) {
    __shared__ float tile[64][65];
    const int bid = blockIdx.x;
    const int n = bid >> 9, rem = bid & 511;
    const int s0 = (rem >> 3) * 64, c0 = (rem & 7) * 64;
    const int tid = threadIdx.x;
    #pragma unroll
    for (int i = 0; i < 16; ++i) {
        const int sl = (tid >> 6) * 16 + i;
        const int cl = tid & 63;
        tile[sl][cl] = pb[((long)(n * 4096 + s0 + sl)) * 512 + c0 + cl];
    }
    __syncthreads();
    #pragma unroll
    for (int i = 0; i < 16; ++i) {
        const int cl = (tid >> 6) * 16 + i;
        const int sl = tid & 63;
        const long oi = ((long)(n * 512 + c0 + cl)) * 4096 + s0 + sl;
        out[oi] = tile[sl][cl] + x[oi];
    }
}

extern "C" void kernel_launch(void* const* d_in, const int* in_sizes, int n_in,
                              void* d_out, int out_size, void* d_ws, size_t ws_size,
                              hipStream_t stream) {
    const float* x     = (const float*)d_in[0];
    const float* gnw   = (const float*)d_in[1];
    const float* gnb   = (const float*)d_in[2];
    const float* qkvw  = (const float*)d_in[3];
    const float* projw = (const float*)d_in[4];
    const float* projb = (const float*)d_in[5];

    char* ws = (char*)d_ws;
    size_t off = 0;
    auto alloc = [&](size_t bytes) {
        void* p = ws + off;
        off += (bytes + 255) & ~(size_t)255;
        return p;
    };
    // fixed: weights 2.1 MB + qk 33.55 MB + Vt 16.78 MB
    bf16*   qwb   = (bf16*)alloc((size_t)1536 * 512 * 2);
    bf16*   pwb   = (bf16*)alloc((size_t)512 * 512 * 2);
    float2* stats = (float2*)alloc((size_t)128 * 8);
    bf16*   qk    = (bf16*)alloc((size_t)16384 * 1024 * 2);  // q|k; q-half becomes O
    bf16*   Vt    = (bf16*)alloc((size_t)4 * 512 * 4096 * 2);
    // aliased region R (134.2 MB): tbuf+vbuf early -> Sbuf(4z) -> pjout f32
    char*   R     = (char*)alloc((size_t)4 * 4096 * 4096 * 2);
    bf16*   tbuf  = (bf16*)R;                                  // tokens [16384][512]
    bf16*   vbuf  = (bf16*)(R + (size_t)16384 * 512 * 2);      // v [16384][512]
    bf16*   Sbuf  = (bf16*)R;                                  // P, all 4 z
    float*  pjout = (float*)R;                                 // proj f32 [16384][512]

    k_gnstats<<<128, 256, 0, stream>>>(x, stats);
    k_norm_t<<<2048, 256, 0, stream>>>(x, gnw, gnb, stats, tbuf);
    k_convw<<<4096, 256, 0, stream>>>(qkvw, projw, qwb, pwb);

    // qkv: q,k -> qk [16384][1024]; v -> vbuf [16384][512]
    gemm256<2><<<dim3(64, 6, 1), 512, 0, stream>>>(
        tbuf, 512, 0, qwb, 512, 0, qk, 1024, 0, 512, vbuf);

    k_vt<<<2048, 256, 0, stream>>>(vbuf, Vt);

    const long QZ = (long)4096 * 1024;   // z-stride in qk
    const long SZ = (long)4096 * 4096;   // z-stride in Sbuf
    // P = exp2(q k^T) for ALL 4 batches in one dispatch (1024 blocks)
    gemm256<1><<<dim3(16, 16, 4), 512, 0, stream>>>(
        qk, 1024, QZ,
        qk + 512, 1024, QZ,
        Sbuf, 4096, SZ, 512, nullptr);
    // O = (P * V) / rowsum, all 4 batches, 256 blocks = 1/CU (XCD z-pinned)
    k_pv<<<dim3(64, 4), 512, 0, stream>>>(Sbuf, Vt, qk, 1024);

    // proj: [16384 x 512] f32 + bias (A = O in qk q-half, lda=1024)
    gemm_proj<<<dim3(64, 4), 512, 0, stream>>>(
        qk, 1024, pwb, 512, projb, pjout);

    // transpose back + residual
    k_final<<<2048, 256, 0, stream>>>(pjout, x, (float*)d_out);
}

// Round 15
// 304.506 us; speedup vs baseline: 1.1011x; 1.0239x over previous
//
#include <hip/hip_runtime.h>
#include <hip/hip_bf16.h>

typedef __bf16 bf16;
typedef __bf16 bf16x8 __attribute__((ext_vector_type(8)));
typedef float f32x4 __attribute__((ext_vector_type(4)));

// ---------------- async global->LDS (width 16) ----------------
__device__ __forceinline__ void gload_lds16(const bf16* g, bf16* l) {
    __builtin_amdgcn_global_load_lds(
        (const __attribute__((address_space(1))) void*)g,
        (__attribute__((address_space(3))) void*)l, 16, 0, 0);
}

// ---------------- GroupNorm stats: one block per (n,group) ----------------
__global__ __launch_bounds__(256) void k_gnstats(const float* __restrict__ x,
                                                 float2* __restrict__ stats) {
    const int g = blockIdx.x;            // 0..127
    const float4* p = (const float4*)(x + (long)g * 65536);
    float s = 0.f, ss = 0.f;
    #pragma unroll 8
    for (int i = 0; i < 64; ++i) {
        float4 v = p[threadIdx.x + i * 256];
        s  += v.x + v.y + v.z + v.w;
        ss += v.x * v.x + v.y * v.y + v.z * v.z + v.w * v.w;
    }
    #pragma unroll
    for (int off = 32; off >= 1; off >>= 1) {
        s  += __shfl_down(s, off);
        ss += __shfl_down(ss, off);
    }
    __shared__ float rs[4], rss[4];
    if ((threadIdx.x & 63) == 0) { rs[threadIdx.x >> 6] = s; rss[threadIdx.x >> 6] = ss; }
    __syncthreads();
    if (threadIdx.x == 0) {
        float S  = rs[0] + rs[1] + rs[2] + rs[3];
        float SS = rss[0] + rss[1] + rss[2] + rss[3];
        float mu = S * (1.f / 65536.f);
        float var = SS * (1.f / 65536.f) - mu * mu;
        stats[g] = make_float2(mu, rsqrtf(var + 1e-5f));
    }
}

// ---------------- normalize + transpose NCHW -> tokens [nt][512] bf16 ----------------
__global__ __launch_bounds__(256) void k_norm_t(const float* __restrict__ x,
                                                const float* __restrict__ w,
                                                const float* __restrict__ b,
                                                const float2* __restrict__ stats,
                                                bf16* __restrict__ t) {
    __shared__ float tile[64][65];
    const int bid = blockIdx.x;
    const int n = bid >> 9, rem = bid & 511;
    const int s0 = (rem >> 3) * 64, c0 = (rem & 7) * 64;
    const int tid = threadIdx.x;
    const int sl = tid & 63, cq = tid >> 6;
    #pragma unroll
    for (int i = 0; i < 16; ++i) {
        const int cl = cq * 16 + i;
        const int c = c0 + cl;
        const float2 st = stats[n * 32 + (c >> 4)];
        const float v = x[((long)(n * 512 + c)) * 4096 + s0 + sl];
        tile[cl][sl] = (v - st.x) * st.y * w[c] + b[c];
    }
    __syncthreads();
    #pragma unroll
    for (int i = 0; i < 16; ++i) {
        const int sl2 = cq * 16 + i;
        const int cl2 = tid & 63;
        t[((long)(n * 4096 + s0 + sl2)) * 512 + c0 + cl2] = (bf16)tile[cl2][sl2];
    }
}

// ---------------- weight conversion (fold log2e/sqrt(512) into q rows) ----------------
__global__ __launch_bounds__(256) void k_convw(const float* __restrict__ qw,
                                               const float* __restrict__ pw,
                                               bf16* __restrict__ qwb,
                                               bf16* __restrict__ pwb) {
    const int i = blockIdx.x * 256 + threadIdx.x;
    if (i < 786432) {
        float v = qw[i];
        if (i < 512 * 512) v *= 0.06376281516217733f;  // log2(e)/sqrt(512)
        qwb[i] = (bf16)v;
    } else {
        const int j = i - 786432;
        pwb[j] = (bf16)pw[j];
    }
}

// ---------------- transpose vbuf [16384][512] -> Vt[n][512][4096] ----------------
__global__ __launch_bounds__(256) void k_vt(const bf16* __restrict__ vbuf,
                                            bf16* __restrict__ Vt) {
    __shared__ bf16 tile[64][66];
    const int bid = blockIdx.x;
    const int n = bid >> 9, rem = bid & 511;
    const int s0 = (rem >> 3) * 64, d0 = (rem & 7) * 64;
    const int tid = threadIdx.x;
    #pragma unroll
    for (int i = 0; i < 16; ++i) {
        const int sl = (tid >> 6) * 16 + i;
        const int dl = tid & 63;
        tile[sl][dl] = vbuf[((long)(n * 4096 + s0 + sl)) * 512 + d0 + dl];
    }
    __syncthreads();
    #pragma unroll
    for (int i = 0; i < 16; ++i) {
        const int dl = (tid >> 6) * 16 + i;
        const int sl = tid & 63;
        Vt[((long)(n * 512 + d0 + dl)) * 4096 + s0 + sl] = tile[sl][dl];
    }
}

// =====================================================================
// 256x256 tile, BK=64, 8-wave, 8-phase GEMM with counted vmcnt (T3+T4+T5)
// LDS swizzle: granule ^= (row>>1)&3  (2-way banks = free)
// EPI 1: P = exp2(acc) bf16 store (scores in log2 domain).
// EPI 2: QKV split store -- q,k into C [row][1024]; v into vbuf [row][512].
// =====================================================================
#define PH(mh, kk, S_, WN)                                                         \
  {                                                                                \
    if ((mh) == 0) {                                                               \
      _Pragma("unroll")                                                            \
      for (int n = 0; n < 4; ++n) {                                                \
        int row = wn * 64 + n * 16 + lr;                                           \
        int cg = lg ^ ((row >> 1) & 3);                                            \
        bfr[n] = *(const bf16x8*)(BsT + (kk) * 8192 + row * 32 + cg * 8);          \
      }                                                                            \
    }                                                                              \
    _Pragma("unroll")                                                              \
    for (int i = 0; i < 4; ++i) {                                                  \
      int row = wm * 128 + ((mh) * 4 + i) * 16 + lr;                               \
      int cg = lg ^ ((row >> 1) & 3);                                              \
      af[i] = *(const bf16x8*)(AsT + (kk) * 8192 + row * 32 + cg * 8);             \
    }                                                                              \
    if ((S_) >= 0) issue_unit(S_);                                                 \
    __builtin_amdgcn_s_barrier();                                                  \
    asm volatile("" ::: "memory");                                                 \
    __builtin_amdgcn_s_setprio(1);                                                 \
    _Pragma("unroll")                                                              \
    for (int i = 0; i < 4; ++i)                                                    \
      _Pragma("unroll")                                                            \
      for (int n = 0; n < 4; ++n)                                                  \
        acc[(mh) * 4 + i][n] =                                                     \
            __builtin_amdgcn_mfma_f32_16x16x32_bf16(af[i], bfr[n],                 \
                                                    acc[(mh) * 4 + i][n], 0, 0, 0);\
    __builtin_amdgcn_s_setprio(0);                                                 \
    if constexpr ((WN) >= 0)                                                       \
      asm volatile("s_waitcnt vmcnt(%0)" ::"i"(WN) : "memory");                    \
    __builtin_amdgcn_s_barrier();                                                  \
    asm volatile("" ::: "memory");                                                 \
  }

template <int EPI>
__global__ __launch_bounds__(512, 2) void gemm256(
    const bf16* __restrict__ A, int lda, long aZ,
    const bf16* __restrict__ B, int ldb, long bZ,
    bf16* __restrict__ C, int ldc, long cZ, int K,
    bf16* __restrict__ vbuf) {
    __shared__ bf16 As[2 * 2 * 256 * 32];
    __shared__ bf16 Bs[2 * 2 * 256 * 32];
    const int t = threadIdx.x;
    const int wid = t >> 6, l = t & 63;
    const int wm = wid >> 2, wn = wid & 3;     // 2 x 4 waves
    const int lr = l & 15;
    const int lg = l >> 4;                     // fragment col-group 0..3
    const long z = blockIdx.z;

    const int gx = gridDim.x;
    int nwg = gx * gridDim.y;
    int flat = blockIdx.y * gx + blockIdx.x;
    if ((nwg & 7) == 0) { int qq = nwg >> 3; flat = (flat & 7) * qq + (flat >> 3); }
    const int bx = flat % gx, by = flat / gx;

    const bf16* Ab = A + z * aZ + (long)bx * 256 * lda;
    const bf16* Bb = B + z * bZ + (long)by * 256 * ldb;

    const int NT = K >> 6;
    const int NT4 = NT << 2;

    f32x4 acc[8][4];
    #pragma unroll
    for (int i = 0; i < 8; ++i)
        #pragma unroll
        for (int n = 0; n < 4; ++n) acc[i][n] = f32x4{0.f, 0.f, 0.f, 0.f};

    const int srow = t >> 2;       // 0..127
    const int scg0 = t & 3;

    auto issue_unit = [&](int s) {
        int ti = s >> 2, idx = s & 3;
        int kh = idx >> 1, isB = idx & 1;
        const bf16* g = isB ? Bb : Ab;
        int ld = isB ? ldb : lda;
        bf16* lp = (isB ? Bs : As) + ((ti & 1) * 2 + kh) * 8192;
        int k0 = ti * 64 + kh * 32;
        #pragma unroll
        for (int j = 0; j < 2; ++j) {
            int row = j * 128 + srow;
            int cg = scg0 ^ ((row >> 1) & 3);
            gload_lds16(g + (long)row * ld + k0 + cg * 8, lp + (j * 512 + t) * 8);
        }
    };

    #pragma unroll
    for (int s = 0; s < 6; ++s) issue_unit(s);
    asm volatile("s_waitcnt vmcnt(8)" ::: "memory");
    __builtin_amdgcn_s_barrier();
    asm volatile("" ::: "memory");

    bf16x8 bfr[4], af[4];

    for (int ti = 0; ti < NT - 2; ++ti) {
        const bf16* AsT = As + (ti & 1) * 16384;
        const bf16* BsT = Bs + (ti & 1) * 16384;
        const int sb = 4 * ti + 6;
        PH(0, 0, sb + 0, -1)
        PH(1, 0, sb + 1, 8)
        PH(0, 1, sb + 2, -1)
        PH(1, 1, sb + 3, 8)
    }
    {
        const bf16* AsT = As + ((NT - 2) & 1) * 16384;
        const bf16* BsT = Bs + ((NT - 2) & 1) * 16384;
        PH(0, 0, NT4 - 2, -1)
        PH(1, 0, NT4 - 1, 8)
        PH(0, 1, -1, -1)
        PH(1, 1, -1, 4)
    }
    {
        const bf16* AsT = As + ((NT - 1) & 1) * 16384;
        const bf16* BsT = Bs + ((NT - 1) & 1) * 16384;
        PH(0, 0, -1, -1)
        PH(1, 0, -1, 0)
        PH(0, 1, -1, -1)
        PH(1, 1, -1, -1)
    }

    const int row0 = bx * 256 + wm * 128;
    const int col0 = by * 256 + wn * 64;
    const int rq = lg * 4;

    if (EPI == 1) {
        bf16* Cz = C + z * cZ;
        #pragma unroll
        for (int i = 0; i < 8; ++i)
            #pragma unroll
            for (int n = 0; n < 4; ++n) {
                const int col = col0 + n * 16 + lr;
                #pragma unroll
                for (int r = 0; r < 4; ++r)
                    Cz[(long)(row0 + i * 16 + rq + r) * ldc + col] = (bf16)exp2f(acc[i][n][r]);
            }
    } else {
        // QKV: q,k -> C [row][1024]; v -> vbuf [row][512]  (both coalesced)
        #pragma unroll
        for (int i = 0; i < 8; ++i) {
            const int row = row0 + i * 16 + rq;
            #pragma unroll
            for (int n = 0; n < 4; ++n) {
                const int col = col0 + n * 16 + lr;
                if (col < 1024) {
                    #pragma unroll
                    for (int r = 0; r < 4; ++r)
                        C[(long)(row + r) * 1024 + col] = (bf16)acc[i][n][r];
                } else {
                    #pragma unroll
                    for (int r = 0; r < 4; ++r)
                        vbuf[(long)(row + r) * 512 + (col - 1024)] = (bf16)acc[i][n][r];
                }
            }
        }
    }
}

// =====================================================================
// PV GEMM (round-11 verified best): O[64 x 512] per block = P[64 x 4096]
// * V (via Vt[512][4096]) / rowsum (own-slot sums). 512 threads, 8 waves,
// BK=64, 2-tile-deep counted vmcnt, grid (64,4) = 256 blocks, 1 dispatch.
// NOTE: XCD z-pin remap tried in R14 -- FETCH 131->82 MB but dur +10us
// (P-stream fetch parallelism restricted). Reverted.
// O stored with leading dim ldo (overwrites the dead q-half of qk).
// =====================================================================
__global__ __launch_bounds__(512, 1) void k_pv(
    const bf16* __restrict__ P, const bf16* __restrict__ Vt,
    bf16* __restrict__ O, int ldo) {
    __shared__ bf16 Bs[2][512 * 64];
    __shared__ bf16 As[2][64 * 64];
    __shared__ float linv[64];
    const int t = threadIdx.x;
    const int w = t >> 6, l = t & 63, lr = l & 15, lg = l >> 4;
    const int lr7 = lr & 7;
    const int sr = t >> 3, sc8 = t & 7, sr7 = sr & 7;
    const long zz = blockIdx.y;
    const int bx = blockIdx.x;

    const bf16* Pg = P + zz * ((long)4096 * 4096) + (long)(bx * 64 + sr) * 4096 + (sc8 ^ sr7) * 8;
    const bf16* Vg = Vt + zz * ((long)512 * 4096) + (long)sr * 4096 + (sc8 ^ sr7) * 8;

    auto issue = [&](int tile, int buf) {
        gload_lds16(Pg + tile * 64, As[buf] + t * 8);
        #pragma unroll
        for (int u = 0; u < 8; ++u)
            gload_lds16(Vg + (long)u * 64 * 4096 + tile * 64, Bs[buf] + u * 4096 + t * 8);
    };

    f32x4 acc[4][4];
    #pragma unroll
    for (int i = 0; i < 4; ++i)
        #pragma unroll
        for (int n = 0; n < 4; ++n) acc[i][n] = f32x4{0.f, 0.f, 0.f, 0.f};

    float lsum = 0.f;

    issue(0, 0);
    issue(1, 1);

    for (int ti = 0; ti < 64; ++ti) {
        if (ti < 63) { asm volatile("s_waitcnt vmcnt(9)" ::: "memory"); }
        else         { asm volatile("s_waitcnt vmcnt(0)" ::: "memory"); }
        __builtin_amdgcn_s_barrier();
        asm volatile("" ::: "memory");

        const bf16* Asb = As[ti & 1];
        const bf16* Bsb = Bs[ti & 1];

        // own-slot row-partial sum (row sr) -- P as quantized to bf16
        {
            bf16x8 sv = *(const bf16x8*)(Asb + t * 8);
            #pragma unroll
            for (int j = 0; j < 8; ++j) lsum += (float)sv[j];
        }

        __builtin_amdgcn_s_setprio(1);
        #pragma unroll
        for (int kk = 0; kk < 2; ++kk) {
            bf16x8 af[4], bfv[4];
            #pragma unroll
            for (int mi = 0; mi < 4; ++mi)
                af[mi] = *(const bf16x8*)(Asb + (mi * 16 + lr) * 64 + (((kk * 4 + lg) ^ lr7) * 8));
            #pragma unroll
            for (int n = 0; n < 4; ++n)
                bfv[n] = *(const bf16x8*)(Bsb + (w * 64 + n * 16 + lr) * 64 + (((kk * 4 + lg) ^ lr7) * 8));
            #pragma unroll
            for (int mi = 0; mi < 4; ++mi)
                #pragma unroll
                for (int n = 0; n < 4; ++n)
                    acc[mi][n] = __builtin_amdgcn_mfma_f32_16x16x32_bf16(af[mi], bfv[n], acc[mi][n], 0, 0, 0);
        }
        __builtin_amdgcn_s_setprio(0);

        __builtin_amdgcn_s_barrier();
        asm volatile("" ::: "memory");
        if (ti < 62) issue(ti + 2, ti & 1);
    }

    lsum += __shfl_xor(lsum, 1);
    lsum += __shfl_xor(lsum, 2);
    lsum += __shfl_xor(lsum, 4);
    if (sc8 == 0) linv[sr] = 1.f / lsum;
    asm volatile("s_waitcnt lgkmcnt(0)" ::: "memory");
    __builtin_amdgcn_s_barrier();
    asm volatile("" ::: "memory");

    bf16* Oz = O + zz * ((long)4096 * ldo);
    #pragma unroll
    for (int mi = 0; mi < 4; ++mi) {
        float4 lv = *(const float4*)&linv[mi * 16 + lg * 4];
        #pragma unroll
        for (int n = 0; n < 4; ++n) {
            const long base = (long)(bx * 64 + mi * 16 + lg * 4) * ldo + w * 64 + n * 16 + lr;
            Oz[base]           = (bf16)(acc[mi][n][0] * lv.x);
            Oz[base + ldo]     = (bf16)(acc[mi][n][1] * lv.y);
            Oz[base + 2 * ldo] = (bf16)(acc[mi][n][2] * lv.z);
            Oz[base + 3 * ldo] = (bf16)(acc[mi][n][3] * lv.w);
        }
    }
}

// =====================================================================
// 256x128 tile, BK=64, 8-wave (4M x 2N), 8-phase, counted vmcnt.
// proj epilogue: f32 + bias, coalesced store [row][512].
// =====================================================================
#define PH128(nh, kk, S_, WN)                                                      \
  {                                                                                \
    if ((nh) == 0) {                                                               \
      _Pragma("unroll")                                                            \
      for (int i = 0; i < 4; ++i) {                                                \
        int row = wm * 64 + i * 16 + lr;                                           \
        int cg = lg ^ ((row >> 1) & 3);                                            \
        af[i] = *(const bf16x8*)(AsT + (kk) * 8192 + row * 32 + cg * 8);           \
      }                                                                            \
    }                                                                              \
    _Pragma("unroll")                                                              \
    for (int j = 0; j < 2; ++j) {                                                  \
      int row = wn * 64 + ((nh) * 2 + j) * 16 + lr;                                \
      int cg = lg ^ ((row >> 1) & 3);                                              \
      bfr[j] = *(const bf16x8*)(BsT + (kk) * 4096 + row * 32 + cg * 8);            \
    }                                                                              \
    if ((S_) >= 0) issue_unit(S_);                                                 \
    __builtin_amdgcn_s_barrier();                                                  \
    asm volatile("" ::: "memory");                                                 \
    __builtin_amdgcn_s_setprio(1);                                                 \
    _Pragma("unroll")                                                              \
    for (int i = 0; i < 4; ++i)                                                    \
      _Pragma("unroll")                                                            \
      for (int j = 0; j < 2; ++j)                                                  \
        acc[i][(nh) * 2 + j] =                                                     \
            __builtin_amdgcn_mfma_f32_16x16x32_bf16(af[i], bfr[j],                 \
                                                    acc[i][(nh) * 2 + j], 0, 0, 0);\
    __builtin_amdgcn_s_setprio(0);                                                 \
    if constexpr ((WN) >= 0)                                                       \
      asm volatile("s_waitcnt vmcnt(%0)" ::"i"(WN) : "memory");                    \
    __builtin_amdgcn_s_barrier();                                                  \
    asm volatile("" ::: "memory");                                                 \
  }

__global__ __launch_bounds__(512, 2) void gemm_proj(
    const bf16* __restrict__ A, int lda,
    const bf16* __restrict__ B, int ldb,
    const float* __restrict__ bias,
    float* __restrict__ Cout) {
    __shared__ bf16 As[2 * 2 * 256 * 32];   // 64 KB
    __shared__ bf16 Bs[2 * 2 * 128 * 32];   // 32 KB
    const int t = threadIdx.x;
    const int wid = t >> 6, l = t & 63;
    const int wm = wid >> 1, wn = wid & 1;   // 4M x 2N waves, wave tile 64x64
    const int lr = l & 15;
    const int lg = l >> 4;

    const int gx = gridDim.x;
    int nwg = gx * gridDim.y;
    int flat = blockIdx.y * gx + blockIdx.x;
    if ((nwg & 7) == 0) { int qq = nwg >> 3; flat = (flat & 7) * qq + (flat >> 3); }
    const int bx = flat % gx, by = flat / gx;

    const bf16* Ab = A + (long)bx * 256 * lda;
    const bf16* Bb = B + (long)by * 128 * ldb;

    const int NT = 8;            // K = 512
    const int NT4 = 32;

    f32x4 acc[4][4];
    #pragma unroll
    for (int i = 0; i < 4; ++i)
        #pragma unroll
        for (int n = 0; n < 4; ++n) acc[i][n] = f32x4{0.f, 0.f, 0.f, 0.f};

    const int srow = t >> 2;       // 0..127
    const int scg0 = t & 3;

    auto issue_unit = [&](int s) {
        int ti = s >> 2, idx = s & 3;
        int kh = idx >> 1, isB = idx & 1;
        int k0 = ti * 64 + kh * 32;
        if (isB) {
            bf16* lp = Bs + ((ti & 1) * 2 + kh) * 4096;
            int cg = scg0 ^ ((srow >> 1) & 3);
            gload_lds16(Bb + (long)srow * ldb + k0 + cg * 8, lp + t * 8);
        } else {
            bf16* lp = As + ((ti & 1) * 2 + kh) * 8192;
            #pragma unroll
            for (int j = 0; j < 2; ++j) {
                int row = j * 128 + srow;
                int cg = scg0 ^ ((row >> 1) & 3);
                gload_lds16(Ab + (long)row * lda + k0 + cg * 8, lp + (j * 512 + t) * 8);
            }
        }
    };

    #pragma unroll
    for (int s = 0; s < 6; ++s) issue_unit(s);
    asm volatile("s_waitcnt vmcnt(6)" ::: "memory");
    __builtin_amdgcn_s_barrier();
    asm volatile("" ::: "memory");

    bf16x8 bfr[2], af[4];

    for (int ti = 0; ti < NT - 2; ++ti) {
        const bf16* AsT = As + (ti & 1) * 16384;
        const bf16* BsT = Bs + (ti & 1) * 8192;
        const int sb = 4 * ti + 6;
        PH128(0, 0, sb + 0, -1)
        PH128(1, 0, sb + 1, 6)
        PH128(0, 1, sb + 2, -1)
        PH128(1, 1, sb + 3, 6)
    }
    {
        const bf16* AsT = As + ((NT - 2) & 1) * 16384;
        const bf16* BsT = Bs + ((NT - 2) & 1) * 8192;
        PH128(0, 0, NT4 - 2, -1)
        PH128(1, 0, NT4 - 1, 6)
        PH128(0, 1, -1, -1)
        PH128(1, 1, -1, 3)
    }
    {
        const bf16* AsT = As + ((NT - 1) & 1) * 16384;
        const bf16* BsT = Bs + ((NT - 1) & 1) * 8192;
        PH128(0, 0, -1, -1)
        PH128(1, 0, -1, 0)
        PH128(0, 1, -1, -1)
        PH128(1, 1, -1, -1)
    }

    const int row0 = bx * 256 + wm * 64;
    const int col0 = by * 128 + wn * 64;
    const int rq = lg * 4;
    #pragma unroll
    for (int i = 0; i < 4; ++i)
        #pragma unroll
        for (int n = 0; n < 4; ++n) {
            const int col = col0 + n * 16 + lr;
            #pragma unroll
            for (int r = 0; r < 4; ++r)
                Cout[(long)(row0 + i * 16 + rq + r) * 512 + col] = acc[i][n][r] + bias[col];
        }
}

// ---------------- proj-out [nt][512] f32 -> NCHW + residual ----------------
__global__ __launch_bounds__(256) void k_final(const float* __restrict__ pb,
                                               const float* __restrict__ x,
                                               float* __restrict__ out) {
    __shared__ float tile[64][65];
    const int bid = blockIdx.x;
    const int n = bid >> 9, rem = bid & 511;
    const int s0 = (rem >> 3) * 64, c0 = (rem & 7) * 64;
    const int tid = threadIdx.x;
    #pragma unroll
    for (int i = 0; i < 16; ++i) {
        const int sl = (tid >> 6) * 16 + i;
        const int cl = tid & 63;
        tile[sl][cl] = pb[((long)(n * 4096 + s0 + sl)) * 512 + c0 + cl];
    }
    __syncthreads();
    #pragma unroll
    for (int i = 0; i < 16; ++i) {
        const int cl = (tid >> 6) * 16 + i;
        const int sl = tid & 63;
        const long oi = ((long)(n * 512 + c0 + cl)) * 4096 + s0 + sl;
        out[oi] = tile[sl][cl] + x[oi];
    }
}

extern "C" void kernel_launch(void* const* d_in, const int* in_sizes, int n_in,
                              void* d_out, int out_size, void* d_ws, size_t ws_size,
                              hipStream_t stream) {
    const float* x     = (const float*)d_in[0];
    const float* gnw   = (const float*)d_in[1];
    const float* gnb   = (const float*)d_in[2];
    const float* qkvw  = (const float*)d_in[3];
    const float* projw = (const float*)d_in[4];
    const float* projb = (const float*)d_in[5];

    char* ws = (char*)d_ws;
    size_t off = 0;
    auto alloc = [&](size_t bytes) {
        void* p = ws + off;
        off += (bytes + 255) & ~(size_t)255;
        return p;
    };
    // fixed: weights 2.1 MB + qk 33.55 MB + Vt 16.78 MB
    bf16*   qwb   = (bf16*)alloc((size_t)1536 * 512 * 2);
    bf16*   pwb   = (bf16*)alloc((size_t)512 * 512 * 2);
    float2* stats = (float2*)alloc((size_t)128 * 8);
    bf16*   qk    = (bf16*)alloc((size_t)16384 * 1024 * 2);  // q|k; q-half becomes O
    bf16*   Vt    = (bf16*)alloc((size_t)4 * 512 * 4096 * 2);
    // aliased region R (134.2 MB): tbuf+vbuf early -> Sbuf(4z) -> pjout f32
    char*   R     = (char*)alloc((size_t)4 * 4096 * 4096 * 2);
    bf16*   tbuf  = (bf16*)R;                                  // tokens [16384][512]
    bf16*   vbuf  = (bf16*)(R + (size_t)16384 * 512 * 2);      // v [16384][512]
    bf16*   Sbuf  = (bf16*)R;                                  // P, all 4 z
    float*  pjout = (float*)R;                                 // proj f32 [16384][512]

    k_gnstats<<<128, 256, 0, stream>>>(x, stats);
    k_norm_t<<<2048, 256, 0, stream>>>(x, gnw, gnb, stats, tbuf);
    k_convw<<<4096, 256, 0, stream>>>(qkvw, projw, qwb, pwb);

    // qkv: q,k -> qk [16384][1024]; v -> vbuf [16384][512]
    gemm256<2><<<dim3(64, 6, 1), 512, 0, stream>>>(
        tbuf, 512, 0, qwb, 512, 0, qk, 1024, 0, 512, vbuf);

    k_vt<<<2048, 256, 0, stream>>>(vbuf, Vt);

    const long QZ = (long)4096 * 1024;   // z-stride in qk
    const long SZ = (long)4096 * 4096;   // z-stride in Sbuf
    // P = exp2(q k^T) for ALL 4 batches in one dispatch (1024 blocks)
    gemm256<1><<<dim3(16, 16, 4), 512, 0, stream>>>(
        qk, 1024, QZ,
        qk + 512, 1024, QZ,
        Sbuf, 4096, SZ, 512, nullptr);
    // O = (P * V) / rowsum, all 4 batches, 256 blocks = 1/CU
    k_pv<<<dim3(64, 4), 512, 0, stream>>>(Sbuf, Vt, qk, 1024);

    // proj: [16384 x 512] f32 + bias (A = O in qk q-half, lda=1024)
    gemm_proj<<<dim3(64, 4), 512, 0, stream>>>(
        qk, 1024, pwb, 512, projb, pjout);

    // transpose back + residual
    k_final<<<2048, 256, 0, stream>>>(pjout, x, (float*)d_out);
}

// Round 16
// 295.915 us; speedup vs baseline: 1.1331x; 1.0290x over previous
//
#include <hip/hip_runtime.h>
#include <hip/hip_bf16.h>

typedef __bf16 bf16;
typedef __bf16 bf16x8 __attribute__((ext_vector_type(8)));
typedef float f32x4 __attribute__((ext_vector_type(4)));

// ---------------- async global->LDS (width 16) ----------------
__device__ __forceinline__ void gload_lds16(const bf16* g, bf16* l) {
    __builtin_amdgcn_global_load_lds(
        (const __attribute__((address_space(1))) void*)g,
        (__attribute__((address_space(3))) void*)l, 16, 0, 0);
}

// ---------------- GroupNorm stats: one block per (n,group) ----------------
__global__ __launch_bounds__(256) void k_gnstats(const float* __restrict__ x,
                                                 float2* __restrict__ stats) {
    const int g = blockIdx.x;            // 0..127
    const float4* p = (const float4*)(x + (long)g * 65536);
    float s = 0.f, ss = 0.f;
    #pragma unroll 8
    for (int i = 0; i < 64; ++i) {
        float4 v = p[threadIdx.x + i * 256];
        s  += v.x + v.y + v.z + v.w;
        ss += v.x * v.x + v.y * v.y + v.z * v.z + v.w * v.w;
    }
    #pragma unroll
    for (int off = 32; off >= 1; off >>= 1) {
        s  += __shfl_down(s, off);
        ss += __shfl_down(ss, off);
    }
    __shared__ float rs[4], rss[4];
    if ((threadIdx.x & 63) == 0) { rs[threadIdx.x >> 6] = s; rss[threadIdx.x >> 6] = ss; }
    __syncthreads();
    if (threadIdx.x == 0) {
        float S  = rs[0] + rs[1] + rs[2] + rs[3];
        float SS = rss[0] + rss[1] + rss[2] + rss[3];
        float mu = S * (1.f / 65536.f);
        float var = SS * (1.f / 65536.f) - mu * mu;
        stats[g] = make_float2(mu, rsqrtf(var + 1e-5f));
    }
}

// ---------------- normalize + transpose NCHW -> tokens [nt][512] bf16 ----------------
__global__ __launch_bounds__(256) void k_norm_t(const float* __restrict__ x,
                                                const float* __restrict__ w,
                                                const float* __restrict__ b,
                                                const float2* __restrict__ stats,
                                                bf16* __restrict__ t) {
    __shared__ float tile[64][65];
    const int bid = blockIdx.x;
    const int n = bid >> 9, rem = bid & 511;
    const int s0 = (rem >> 3) * 64, c0 = (rem & 7) * 64;
    const int tid = threadIdx.x;
    const int sl = tid & 63, cq = tid >> 6;
    #pragma unroll
    for (int i = 0; i < 16; ++i) {
        const int cl = cq * 16 + i;
        const int c = c0 + cl;
        const float2 st = stats[n * 32 + (c >> 4)];
        const float v = x[((long)(n * 512 + c)) * 4096 + s0 + sl];
        tile[cl][sl] = (v - st.x) * st.y * w[c] + b[c];
    }
    __syncthreads();
    #pragma unroll
    for (int i = 0; i < 16; ++i) {
        const int sl2 = cq * 16 + i;
        const int cl2 = tid & 63;
        t[((long)(n * 4096 + s0 + sl2)) * 512 + c0 + cl2] = (bf16)tile[cl2][sl2];
    }
}

// ---------------- weight conversion (fold log2e/sqrt(512) into q rows) ----------------
__global__ __launch_bounds__(256) void k_convw(const float* __restrict__ qw,
                                               const float* __restrict__ pw,
                                               bf16* __restrict__ qwb,
                                               bf16* __restrict__ pwb) {
    const int i = blockIdx.x * 256 + threadIdx.x;
    if (i < 786432) {
        float v = qw[i];
        if (i < 512 * 512) v *= 0.06376281516217733f;  // log2(e)/sqrt(512)
        qwb[i] = (bf16)v;
    } else {
        const int j = i - 786432;
        pwb[j] = (bf16)pw[j];
    }
}

// ---------------- transpose vbuf [16384][512] -> Vt[n][512][4096] ----------------
__global__ __launch_bounds__(256) void k_vt(const bf16* __restrict__ vbuf,
                                            bf16* __restrict__ Vt) {
    __shared__ bf16 tile[64][66];
    const int bid = blockIdx.x;
    const int n = bid >> 9, rem = bid & 511;
    const int s0 = (rem >> 3) * 64, d0 = (rem & 7) * 64;
    const int tid = threadIdx.x;
    #pragma unroll
    for (int i = 0; i < 16; ++i) {
        const int sl = (tid >> 6) * 16 + i;
        const int dl = tid & 63;
        tile[sl][dl] = vbuf[((long)(n * 4096 + s0 + sl)) * 512 + d0 + dl];
    }
    __syncthreads();
    #pragma unroll
    for (int i = 0; i < 16; ++i) {
        const int dl = (tid >> 6) * 16 + i;
        const int sl = tid & 63;
        Vt[((long)(n * 512 + d0 + dl)) * 4096 + s0 + sl] = tile[sl][dl];
    }
}

// =====================================================================
// 256x256 tile, BK=64, 8-wave, 8-phase GEMM with counted vmcnt (T3+T4+T5)
// LDS swizzle: granule ^= (row>>1)&3  (2-way banks = free)
// EPI 1: P = exp2(acc) bf16 store (scores in log2 domain).
// EPI 2: QKV split store -- q,k into C [row][1024]; v into vbuf [row][512].
// =====================================================================
#define PH(mh, kk, S_, WN)                                                         \
  {                                                                                \
    if ((mh) == 0) {                                                               \
      _Pragma("unroll")                                                            \
      for (int n = 0; n < 4; ++n) {                                                \
        int row = wn * 64 + n * 16 + lr;                                           \
        int cg = lg ^ ((row >> 1) & 3);                                            \
        bfr[n] = *(const bf16x8*)(BsT + (kk) * 8192 + row * 32 + cg * 8);          \
      }                                                                            \
    }                                                                              \
    _Pragma("unroll")                                                              \
    for (int i = 0; i < 4; ++i) {                                                  \
      int row = wm * 128 + ((mh) * 4 + i) * 16 + lr;                               \
      int cg = lg ^ ((row >> 1) & 3);                                              \
      af[i] = *(const bf16x8*)(AsT + (kk) * 8192 + row * 32 + cg * 8);             \
    }                                                                              \
    if ((S_) >= 0) issue_unit(S_);                                                 \
    __builtin_amdgcn_s_barrier();                                                  \
    asm volatile("" ::: "memory");                                                 \
    __builtin_amdgcn_s_setprio(1);                                                 \
    _Pragma("unroll")                                                              \
    for (int i = 0; i < 4; ++i)                                                    \
      _Pragma("unroll")                                                            \
      for (int n = 0; n < 4; ++n)                                                  \
        acc[(mh) * 4 + i][n] =                                                     \
            __builtin_amdgcn_mfma_f32_16x16x32_bf16(af[i], bfr[n],                 \
                                                    acc[(mh) * 4 + i][n], 0, 0, 0);\
    __builtin_amdgcn_s_setprio(0);                                                 \
    if constexpr ((WN) >= 0)                                                       \
      asm volatile("s_waitcnt vmcnt(%0)" ::"i"(WN) : "memory");                    \
    __builtin_amdgcn_s_barrier();                                                  \
    asm volatile("" ::: "memory");                                                 \
  }

template <int EPI>
__global__ __launch_bounds__(512, 2) void gemm256(
    const bf16* __restrict__ A, int lda, long aZ,
    const bf16* __restrict__ B, int ldb, long bZ,
    bf16* __restrict__ C, int ldc, long cZ, int K,
    bf16* __restrict__ vbuf) {
    __shared__ bf16 As[2 * 2 * 256 * 32];
    __shared__ bf16 Bs[2 * 2 * 256 * 32];
    const int t = threadIdx.x;
    const int wid = t >> 6, l = t & 63;
    const int wm = wid >> 2, wn = wid & 3;     // 2 x 4 waves
    const int lr = l & 15;
    const int lg = l >> 4;                     // fragment col-group 0..3
    const long z = blockIdx.z;

    const int gx = gridDim.x;
    int nwg = gx * gridDim.y;
    int flat = blockIdx.y * gx + blockIdx.x;
    if ((nwg & 7) == 0) { int qq = nwg >> 3; flat = (flat & 7) * qq + (flat >> 3); }
    const int bx = flat % gx, by = flat / gx;

    const bf16* Ab = A + z * aZ + (long)bx * 256 * lda;
    const bf16* Bb = B + z * bZ + (long)by * 256 * ldb;

    const int NT = K >> 6;
    const int NT4 = NT << 2;

    f32x4 acc[8][4];
    #pragma unroll
    for (int i = 0; i < 8; ++i)
        #pragma unroll
        for (int n = 0; n < 4; ++n) acc[i][n] = f32x4{0.f, 0.f, 0.f, 0.f};

    const int srow = t >> 2;       // 0..127
    const int scg0 = t & 3;

    auto issue_unit = [&](int s) {
        int ti = s >> 2, idx = s & 3;
        int kh = idx >> 1, isB = idx & 1;
        const bf16* g = isB ? Bb : Ab;
        int ld = isB ? ldb : lda;
        bf16* lp = (isB ? Bs : As) + ((ti & 1) * 2 + kh) * 8192;
        int k0 = ti * 64 + kh * 32;
        #pragma unroll
        for (int j = 0; j < 2; ++j) {
            int row = j * 128 + srow;
            int cg = scg0 ^ ((row >> 1) & 3);
            gload_lds16(g + (long)row * ld + k0 + cg * 8, lp + (j * 512 + t) * 8);
        }
    };

    #pragma unroll
    for (int s = 0; s < 6; ++s) issue_unit(s);
    asm volatile("s_waitcnt vmcnt(8)" ::: "memory");
    __builtin_amdgcn_s_barrier();
    asm volatile("" ::: "memory");

    bf16x8 bfr[4], af[4];

    for (int ti = 0; ti < NT - 2; ++ti) {
        const bf16* AsT = As + (ti & 1) * 16384;
        const bf16* BsT = Bs + (ti & 1) * 16384;
        const int sb = 4 * ti + 6;
        PH(0, 0, sb + 0, -1)
        PH(1, 0, sb + 1, 8)
        PH(0, 1, sb + 2, -1)
        PH(1, 1, sb + 3, 8)
    }
    {
        const bf16* AsT = As + ((NT - 2) & 1) * 16384;
        const bf16* BsT = Bs + ((NT - 2) & 1) * 16384;
        PH(0, 0, NT4 - 2, -1)
        PH(1, 0, NT4 - 1, 8)
        PH(0, 1, -1, -1)
        PH(1, 1, -1, 4)
    }
    {
        const bf16* AsT = As + ((NT - 1) & 1) * 16384;
        const bf16* BsT = Bs + ((NT - 1) & 1) * 16384;
        PH(0, 0, -1, -1)
        PH(1, 0, -1, 0)
        PH(0, 1, -1, -1)
        PH(1, 1, -1, -1)
    }

    const int row0 = bx * 256 + wm * 128;
    const int col0 = by * 256 + wn * 64;
    const int rq = lg * 4;

    if (EPI == 1) {
        bf16* Cz = C + z * cZ;
        #pragma unroll
        for (int i = 0; i < 8; ++i)
            #pragma unroll
            for (int n = 0; n < 4; ++n) {
                const int col = col0 + n * 16 + lr;
                #pragma unroll
                for (int r = 0; r < 4; ++r)
                    Cz[(long)(row0 + i * 16 + rq + r) * ldc + col] = (bf16)exp2f(acc[i][n][r]);
            }
    } else {
        // QKV: q,k -> C [row][1024]; v -> vbuf [row][512]  (both coalesced)
        #pragma unroll
        for (int i = 0; i < 8; ++i) {
            const int row = row0 + i * 16 + rq;
            #pragma unroll
            for (int n = 0; n < 4; ++n) {
                const int col = col0 + n * 16 + lr;
                if (col < 1024) {
                    #pragma unroll
                    for (int r = 0; r < 4; ++r)
                        C[(long)(row + r) * 1024 + col] = (bf16)acc[i][n][r];
                } else {
                    #pragma unroll
                    for (int r = 0; r < 4; ++r)
                        vbuf[(long)(row + r) * 512 + (col - 1024)] = (bf16)acc[i][n][r];
                }
            }
        }
    }
}

// =====================================================================
// PV GEMM (round-11 verified best): O[64 x 512] per block = P[64 x 4096]
// * V (via Vt[512][4096]) / rowsum (own-slot sums). 512 threads, 8 waves,
// BK=64, 2-tile-deep counted vmcnt, grid (64,4) = 256 blocks, 1 dispatch.
// O stored with leading dim ldo (overwrites the dead q-half of qk).
// =====================================================================
__global__ __launch_bounds__(512, 1) void k_pv(
    const bf16* __restrict__ P, const bf16* __restrict__ Vt,
    bf16* __restrict__ O, int ldo) {
    __shared__ bf16 Bs[2][512 * 64];
    __shared__ bf16 As[2][64 * 64];
    __shared__ float linv[64];
    const int t = threadIdx.x;
    const int w = t >> 6, l = t & 63, lr = l & 15, lg = l >> 4;
    const int lr7 = lr & 7;
    const int sr = t >> 3, sc8 = t & 7, sr7 = sr & 7;
    const long zz = blockIdx.y;
    const int bx = blockIdx.x;

    const bf16* Pg = P + zz * ((long)4096 * 4096) + (long)(bx * 64 + sr) * 4096 + (sc8 ^ sr7) * 8;
    const bf16* Vg = Vt + zz * ((long)512 * 4096) + (long)sr * 4096 + (sc8 ^ sr7) * 8;

    auto issue = [&](int tile, int buf) {
        gload_lds16(Pg + tile * 64, As[buf] + t * 8);
        #pragma unroll
        for (int u = 0; u < 8; ++u)
            gload_lds16(Vg + (long)u * 64 * 4096 + tile * 64, Bs[buf] + u * 4096 + t * 8);
    };

    f32x4 acc[4][4];
    #pragma unroll
    for (int i = 0; i < 4; ++i)
        #pragma unroll
        for (int n = 0; n < 4; ++n) acc[i][n] = f32x4{0.f, 0.f, 0.f, 0.f};

    float lsum = 0.f;

    issue(0, 0);
    issue(1, 1);

    for (int ti = 0; ti < 64; ++ti) {
        if (ti < 63) { asm volatile("s_waitcnt vmcnt(9)" ::: "memory"); }
        else         { asm volatile("s_waitcnt vmcnt(0)" ::: "memory"); }
        __builtin_amdgcn_s_barrier();
        asm volatile("" ::: "memory");

        const bf16* Asb = As[ti & 1];
        const bf16* Bsb = Bs[ti & 1];

        // own-slot row-partial sum (row sr) -- P as quantized to bf16
        {
            bf16x8 sv = *(const bf16x8*)(Asb + t * 8);
            #pragma unroll
            for (int j = 0; j < 8; ++j) lsum += (float)sv[j];
        }

        __builtin_amdgcn_s_setprio(1);
        #pragma unroll
        for (int kk = 0; kk < 2; ++kk) {
            bf16x8 af[4], bfv[4];
            #pragma unroll
            for (int mi = 0; mi < 4; ++mi)
                af[mi] = *(const bf16x8*)(Asb + (mi * 16 + lr) * 64 + (((kk * 4 + lg) ^ lr7) * 8));
            #pragma unroll
            for (int n = 0; n < 4; ++n)
                bfv[n] = *(const bf16x8*)(Bsb + (w * 64 + n * 16 + lr) * 64 + (((kk * 4 + lg) ^ lr7) * 8));
            #pragma unroll
            for (int mi = 0; mi < 4; ++mi)
                #pragma unroll
                for (int n = 0; n < 4; ++n)
                    acc[mi][n] = __builtin_amdgcn_mfma_f32_16x16x32_bf16(af[mi], bfv[n], acc[mi][n], 0, 0, 0);
        }
        __builtin_amdgcn_s_setprio(0);

        __builtin_amdgcn_s_barrier();
        asm volatile("" ::: "memory");
        if (ti < 62) issue(ti + 2, ti & 1);
    }

    lsum += __shfl_xor(lsum, 1);
    lsum += __shfl_xor(lsum, 2);
    lsum += __shfl_xor(lsum, 4);
    if (sc8 == 0) linv[sr] = 1.f / lsum;
    asm volatile("s_waitcnt lgkmcnt(0)" ::: "memory");
    __builtin_amdgcn_s_barrier();
    asm volatile("" ::: "memory");

    bf16* Oz = O + zz * ((long)4096 * ldo);
    #pragma unroll
    for (int mi = 0; mi < 4; ++mi) {
        float4 lv = *(const float4*)&linv[mi * 16 + lg * 4];
        #pragma unroll
        for (int n = 0; n < 4; ++n) {
            const long base = (long)(bx * 64 + mi * 16 + lg * 4) * ldo + w * 64 + n * 16 + lr;
            Oz[base]           = (bf16)(acc[mi][n][0] * lv.x);
            Oz[base + ldo]     = (bf16)(acc[mi][n][1] * lv.y);
            Oz[base + 2 * ldo] = (bf16)(acc[mi][n][2] * lv.z);
            Oz[base + 3 * ldo] = (bf16)(acc[mi][n][3] * lv.w);
        }
    }
}

// =====================================================================
// 256x128 tile, BK=64, 8-wave (4M x 2N), 8-phase, counted vmcnt.
// FUSED epilogue: transpose -> NCHW + bias + residual, straight to out.
// (LDS As reused as 32x260 f32 transpose tile after the final PH barrier.)
// =====================================================================
#define PH128(nh, kk, S_, WN)                                                      \
  {                                                                                \
    if ((nh) == 0) {                                                               \
      _Pragma("unroll")                                                            \
      for (int i = 0; i < 4; ++i) {                                                \
        int row = wm * 64 + i * 16 + lr;                                           \
        int cg = lg ^ ((row >> 1) & 3);                                            \
        af[i] = *(const bf16x8*)(AsT + (kk) * 8192 + row * 32 + cg * 8);           \
      }                                                                            \
    }                                                                              \
    _Pragma("unroll")                                                              \
    for (int j = 0; j < 2; ++j) {                                                  \
      int row = wn * 64 + ((nh) * 2 + j) * 16 + lr;                                \
      int cg = lg ^ ((row >> 1) & 3);                                              \
      bfr[j] = *(const bf16x8*)(BsT + (kk) * 4096 + row * 32 + cg * 8);            \
    }                                                                              \
    if ((S_) >= 0) issue_unit(S_);                                                 \
    __builtin_amdgcn_s_barrier();                                                  \
    asm volatile("" ::: "memory");                                                 \
    __builtin_amdgcn_s_setprio(1);                                                 \
    _Pragma("unroll")                                                              \
    for (int i = 0; i < 4; ++i)                                                    \
      _Pragma("unroll")                                                            \
      for (int j = 0; j < 2; ++j)                                                  \
        acc[i][(nh) * 2 + j] =                                                     \
            __builtin_amdgcn_mfma_f32_16x16x32_bf16(af[i], bfr[j],                 \
                                                    acc[i][(nh) * 2 + j], 0, 0, 0);\
    __builtin_amdgcn_s_setprio(0);                                                 \
    if constexpr ((WN) >= 0)                                                       \
      asm volatile("s_waitcnt vmcnt(%0)" ::"i"(WN) : "memory");                    \
    __builtin_amdgcn_s_barrier();                                                  \
    asm volatile("" ::: "memory");                                                 \
  }

__global__ __launch_bounds__(512, 2) void gemm_proj(
    const bf16* __restrict__ A, int lda,
    const bf16* __restrict__ B, int ldb,
    const float* __restrict__ bias,
    const float* __restrict__ xres,
    float* __restrict__ outp) {
    __shared__ bf16 As[2 * 2 * 256 * 32];   // 64 KB (reused for transpose)
    __shared__ bf16 Bs[2 * 2 * 128 * 32];   // 32 KB
    const int t = threadIdx.x;
    const int wid = t >> 6, l = t & 63;
    const int wm = wid >> 1, wn = wid & 1;   // 4M x 2N waves, wave tile 64x64
    const int lr = l & 15;
    const int lg = l >> 4;

    const int gx = gridDim.x;
    int nwg = gx * gridDim.y;
    int flat = blockIdx.y * gx + blockIdx.x;
    if ((nwg & 7) == 0) { int qq = nwg >> 3; flat = (flat & 7) * qq + (flat >> 3); }
    const int bx = flat % gx, by = flat / gx;

    const bf16* Ab = A + (long)bx * 256 * lda;
    const bf16* Bb = B + (long)by * 128 * ldb;

    const int NT = 8;            // K = 512
    const int NT4 = 32;

    f32x4 acc[4][4];
    #pragma unroll
    for (int i = 0; i < 4; ++i)
        #pragma unroll
        for (int n = 0; n < 4; ++n) acc[i][n] = f32x4{0.f, 0.f, 0.f, 0.f};

    const int srow = t >> 2;       // 0..127
    const int scg0 = t & 3;

    auto issue_unit = [&](int s) {
        int ti = s >> 2, idx = s & 3;
        int kh = idx >> 1, isB = idx & 1;
        int k0 = ti * 64 + kh * 32;
        if (isB) {
            bf16* lp = Bs + ((ti & 1) * 2 + kh) * 4096;
            int cg = scg0 ^ ((srow >> 1) & 3);
            gload_lds16(Bb + (long)srow * ldb + k0 + cg * 8, lp + t * 8);
        } else {
            bf16* lp = As + ((ti & 1) * 2 + kh) * 8192;
            #pragma unroll
            for (int j = 0; j < 2; ++j) {
                int row = j * 128 + srow;
                int cg = scg0 ^ ((row >> 1) & 3);
                gload_lds16(Ab + (long)row * lda + k0 + cg * 8, lp + (j * 512 + t) * 8);
            }
        }
    };

    #pragma unroll
    for (int s = 0; s < 6; ++s) issue_unit(s);
    asm volatile("s_waitcnt vmcnt(6)" ::: "memory");
    __builtin_amdgcn_s_barrier();
    asm volatile("" ::: "memory");

    bf16x8 bfr[2], af[4];

    for (int ti = 0; ti < NT - 2; ++ti) {
        const bf16* AsT = As + (ti & 1) * 16384;
        const bf16* BsT = Bs + (ti & 1) * 8192;
        const int sb = 4 * ti + 6;
        PH128(0, 0, sb + 0, -1)
        PH128(1, 0, sb + 1, 6)
        PH128(0, 1, sb + 2, -1)
        PH128(1, 1, sb + 3, 6)
    }
    {
        const bf16* AsT = As + ((NT - 2) & 1) * 16384;
        const bf16* BsT = Bs + ((NT - 2) & 1) * 8192;
        PH128(0, 0, NT4 - 2, -1)
        PH128(1, 0, NT4 - 1, 6)
        PH128(0, 1, -1, -1)
        PH128(1, 1, -1, 3)
    }
    {
        const bf16* AsT = As + ((NT - 1) & 1) * 16384;
        const bf16* BsT = Bs + ((NT - 1) & 1) * 8192;
        PH128(0, 0, -1, -1)
        PH128(1, 0, -1, 0)
        PH128(0, 1, -1, -1)
        PH128(1, 1, -1, -1)
    }

    // ---- fused epilogue: transpose -> NCHW + bias + residual ----
    // Block tile: token rows r0..r0+255 (one image: 4096%256==0), cols
    // c0..c0+127. Process in 4 chunks of 32 cols via LDS [32][260] f32.
    const int r0 = bx * 256;
    const int c0b = by * 128;
    const int nb = r0 >> 12;
    const int sp0 = r0 & 4095;
    const int rq = lg * 4;
    float* Lt = (float*)As;                  // 32*260*4 = 33.3 KB < 64 KB
    #pragma unroll
    for (int q = 0; q < 4; ++q) {
        if (wn == (q >> 1)) {
            #pragma unroll
            for (int nn = 0; nn < 2; ++nn) {
                const int n = (q & 1) * 2 + nn;
                const int cl = nn * 16 + lr;             // 0..31
                #pragma unroll
                for (int i = 0; i < 4; ++i) {
                    const int sp = wm * 64 + i * 16 + rq;   // 0..255, mult of 4
                    float4 v;
                    v.x = acc[i][n][0]; v.y = acc[i][n][1];
                    v.z = acc[i][n][2]; v.w = acc[i][n][3];
                    *(float4*)(Lt + cl * 260 + sp) = v;
                }
            }
        }
        __syncthreads();
        {
            const int cl2 = t >> 4;                  // 0..31
            const int spc = (t & 15) * 16;           // 0..240
            const int col = c0b + q * 32 + cl2;
            const float bb = bias[col];
            const long ob = ((long)nb * 512 + col) * 4096 + sp0 + spc;
            #pragma unroll
            for (int j = 0; j < 4; ++j) {
                float4 lv = *(const float4*)(Lt + cl2 * 260 + spc + j * 4);
                float4 xv = *(const float4*)(xres + ob + j * 4);
                float4 ov;
                ov.x = lv.x + bb + xv.x; ov.y = lv.y + bb + xv.y;
                ov.z = lv.z + bb + xv.z; ov.w = lv.w + bb + xv.w;
                *(float4*)(outp + ob + j * 4) = ov;
            }
        }
        __syncthreads();
    }
}

extern "C" void kernel_launch(void* const* d_in, const int* in_sizes, int n_in,
                              void* d_out, int out_size, void* d_ws, size_t ws_size,
                              hipStream_t stream) {
    const float* x     = (const float*)d_in[0];
    const float* gnw   = (const float*)d_in[1];
    const float* gnb   = (const float*)d_in[2];
    const float* qkvw  = (const float*)d_in[3];
    const float* projw = (const float*)d_in[4];
    const float* projb = (const float*)d_in[5];

    char* ws = (char*)d_ws;
    size_t off = 0;
    auto alloc = [&](size_t bytes) {
        void* p = ws + off;
        off += (bytes + 255) & ~(size_t)255;
        return p;
    };
    // fixed: weights 2.1 MB + qk 33.55 MB + Vt 16.78 MB
    bf16*   qwb   = (bf16*)alloc((size_t)1536 * 512 * 2);
    bf16*   pwb   = (bf16*)alloc((size_t)512 * 512 * 2);
    float2* stats = (float2*)alloc((size_t)128 * 8);
    bf16*   qk    = (bf16*)alloc((size_t)16384 * 1024 * 2);  // q|k; q-half becomes O
    bf16*   Vt    = (bf16*)alloc((size_t)4 * 512 * 4096 * 2);
    // aliased region R (134.2 MB): tbuf+vbuf early -> Sbuf(4z)
    char*   R     = (char*)alloc((size_t)4 * 4096 * 4096 * 2);
    bf16*   tbuf  = (bf16*)R;                                  // tokens [16384][512]
    bf16*   vbuf  = (bf16*)(R + (size_t)16384 * 512 * 2);      // v [16384][512]
    bf16*   Sbuf  = (bf16*)R;                                  // P, all 4 z

    k_gnstats<<<128, 256, 0, stream>>>(x, stats);
    k_norm_t<<<2048, 256, 0, stream>>>(x, gnw, gnb, stats, tbuf);
    k_convw<<<4096, 256, 0, stream>>>(qkvw, projw, qwb, pwb);

    // qkv: q,k -> qk [16384][1024]; v -> vbuf [16384][512]
    gemm256<2><<<dim3(64, 6, 1), 512, 0, stream>>>(
        tbuf, 512, 0, qwb, 512, 0, qk, 1024, 0, 512, vbuf);

    k_vt<<<2048, 256, 0, stream>>>(vbuf, Vt);

    const long QZ = (long)4096 * 1024;   // z-stride in qk
    const long SZ = (long)4096 * 4096;   // z-stride in Sbuf
    // P = exp2(q k^T) for ALL 4 batches in one dispatch (1024 blocks)
    gemm256<1><<<dim3(16, 16, 4), 512, 0, stream>>>(
        qk, 1024, QZ,
        qk + 512, 1024, QZ,
        Sbuf, 4096, SZ, 512, nullptr);
    // O = (P * V) / rowsum, all 4 batches, 256 blocks = 1/CU
    k_pv<<<dim3(64, 4), 512, 0, stream>>>(Sbuf, Vt, qk, 1024);

    // proj + bias + residual + NCHW transpose, straight to d_out
    gemm_proj<<<dim3(64, 4), 512, 0, stream>>>(
        qk, 1024, pwb, 512, projb, x, (float*)d_out);
}

// Round 17
// 291.245 us; speedup vs baseline: 1.1512x; 1.0160x over previous
//
#include <hip/hip_runtime.h>
#include <hip/hip_bf16.h>

typedef __bf16 bf16;
typedef __bf16 bf16x4 __attribute__((ext_vector_type(4)));
typedef __bf16 bf16x8 __attribute__((ext_vector_type(8)));
typedef float f32x4 __attribute__((ext_vector_type(4)));

// ---------------- async global->LDS (width 16) ----------------
__device__ __forceinline__ void gload_lds16(const bf16* g, bf16* l) {
    __builtin_amdgcn_global_load_lds(
        (const __attribute__((address_space(1))) void*)g,
        (__attribute__((address_space(3))) void*)l, 16, 0, 0);
}

// ---------------- GroupNorm stats: one block per (n,group) ----------------
__global__ __launch_bounds__(256) void k_gnstats(const float* __restrict__ x,
                                                 float2* __restrict__ stats) {
    const int g = blockIdx.x;            // 0..127
    const float4* p = (const float4*)(x + (long)g * 65536);
    float s = 0.f, ss = 0.f;
    #pragma unroll 8
    for (int i = 0; i < 64; ++i) {
        float4 v = p[threadIdx.x + i * 256];
        s  += v.x + v.y + v.z + v.w;
        ss += v.x * v.x + v.y * v.y + v.z * v.z + v.w * v.w;
    }
    #pragma unroll
    for (int off = 32; off >= 1; off >>= 1) {
        s  += __shfl_down(s, off);
        ss += __shfl_down(ss, off);
    }
    __shared__ float rs[4], rss[4];
    if ((threadIdx.x & 63) == 0) { rs[threadIdx.x >> 6] = s; rss[threadIdx.x >> 6] = ss; }
    __syncthreads();
    if (threadIdx.x == 0) {
        float S  = rs[0] + rs[1] + rs[2] + rs[3];
        float SS = rss[0] + rss[1] + rss[2] + rss[3];
        float mu = S * (1.f / 65536.f);
        float var = SS * (1.f / 65536.f) - mu * mu;
        stats[g] = make_float2(mu, rsqrtf(var + 1e-5f));
    }
}

// ---------------- normalize + transpose NCHW -> tokens [nt][512] bf16 ----------------
__global__ __launch_bounds__(256) void k_norm_t(const float* __restrict__ x,
                                                const float* __restrict__ w,
                                                const float* __restrict__ b,
                                                const float2* __restrict__ stats,
                                                bf16* __restrict__ t) {
    __shared__ float tile[64][65];
    const int bid = blockIdx.x;
    const int n = bid >> 9, rem = bid & 511;
    const int s0 = (rem >> 3) * 64, c0 = (rem & 7) * 64;
    const int tid = threadIdx.x;
    const int sl = tid & 63, cq = tid >> 6;
    #pragma unroll
    for (int i = 0; i < 16; ++i) {
        const int cl = cq * 16 + i;
        const int c = c0 + cl;
        const float2 st = stats[n * 32 + (c >> 4)];
        const float v = x[((long)(n * 512 + c)) * 4096 + s0 + sl];
        tile[cl][sl] = (v - st.x) * st.y * w[c] + b[c];
    }
    __syncthreads();
    #pragma unroll
    for (int i = 0; i < 16; ++i) {
        const int sl2 = cq * 16 + i;
        const int cl2 = tid & 63;
        t[((long)(n * 4096 + s0 + sl2)) * 512 + c0 + cl2] = (bf16)tile[cl2][sl2];
    }
}

// ---------------- weight conversion (fold log2e/sqrt(512) into q rows) ----------------
__global__ __launch_bounds__(256) void k_convw(const float* __restrict__ qw,
                                               const float* __restrict__ pw,
                                               bf16* __restrict__ qwb,
                                               bf16* __restrict__ pwb) {
    const int i = blockIdx.x * 256 + threadIdx.x;
    if (i < 786432) {
        float v = qw[i];
        if (i < 512 * 512) v *= 0.06376281516217733f;  // log2(e)/sqrt(512)
        qwb[i] = (bf16)v;
    } else {
        const int j = i - 786432;
        pwb[j] = (bf16)pw[j];
    }
}

// =====================================================================
// 256x256 tile, BK=64, 8-wave, 8-phase GEMM with counted vmcnt (T3+T4+T5)
// LDS swizzle: granule ^= (row>>1)&3  (2-way banks = free)
// EPI 1: P = exp2(acc) bf16 store (scores in log2 domain).
// EPI 2: QKV -- by<4: q,k into C [row][1024] (coalesced);
//        by>=4: v TRANSPOSED in-epilogue into Vt[nb][512][4096]
//        (LDS-staged via As, granule-XOR swizzle, 128B coalesced stores).
// =====================================================================
#define PH(mh, kk, S_, WN)                                                         \
  {                                                                                \
    if ((mh) == 0) {                                                               \
      _Pragma("unroll")                                                            \
      for (int n = 0; n < 4; ++n) {                                                \
        int row = wn * 64 + n * 16 + lr;                                           \
        int cg = lg ^ ((row >> 1) & 3);                                            \
        bfr[n] = *(const bf16x8*)(BsT + (kk) * 8192 + row * 32 + cg * 8);          \
      }                                                                            \
    }                                                                              \
    _Pragma("unroll")                                                              \
    for (int i = 0; i < 4; ++i) {                                                  \
      int row = wm * 128 + ((mh) * 4 + i) * 16 + lr;                               \
      int cg = lg ^ ((row >> 1) & 3);                                              \
      af[i] = *(const bf16x8*)(AsT + (kk) * 8192 + row * 32 + cg * 8);             \
    }                                                                              \
    if ((S_) >= 0) issue_unit(S_);                                                 \
    __builtin_amdgcn_s_barrier();                                                  \
    asm volatile("" ::: "memory");                                                 \
    __builtin_amdgcn_s_setprio(1);                                                 \
    _Pragma("unroll")                                                              \
    for (int i = 0; i < 4; ++i)                                                    \
      _Pragma("unroll")                                                            \
      for (int n = 0; n < 4; ++n)                                                  \
        acc[(mh) * 4 + i][n] =                                                     \
            __builtin_amdgcn_mfma_f32_16x16x32_bf16(af[i], bfr[n],                 \
                                                    acc[(mh) * 4 + i][n], 0, 0, 0);\
    __builtin_amdgcn_s_setprio(0);                                                 \
    if constexpr ((WN) >= 0)                                                       \
      asm volatile("s_waitcnt vmcnt(%0)" ::"i"(WN) : "memory");                    \
    __builtin_amdgcn_s_barrier();                                                  \
    asm volatile("" ::: "memory");                                                 \
  }

template <int EPI>
__global__ __launch_bounds__(512, 2) void gemm256(
    const bf16* __restrict__ A, int lda, long aZ,
    const bf16* __restrict__ B, int ldb, long bZ,
    bf16* __restrict__ C, int ldc, long cZ, int K,
    bf16* __restrict__ Vt) {
    __shared__ bf16 As[2 * 2 * 256 * 32];
    __shared__ bf16 Bs[2 * 2 * 256 * 32];
    const int t = threadIdx.x;
    const int wid = t >> 6, l = t & 63;
    const int wm = wid >> 2, wn = wid & 3;     // 2 x 4 waves
    const int lr = l & 15;
    const int lg = l >> 4;                     // fragment col-group 0..3
    const long z = blockIdx.z;

    const int gx = gridDim.x;
    int nwg = gx * gridDim.y;
    int flat = blockIdx.y * gx + blockIdx.x;
    if ((nwg & 7) == 0) { int qq = nwg >> 3; flat = (flat & 7) * qq + (flat >> 3); }
    const int bx = flat % gx, by = flat / gx;

    const bf16* Ab = A + z * aZ + (long)bx * 256 * lda;
    const bf16* Bb = B + z * bZ + (long)by * 256 * ldb;

    const int NT = K >> 6;
    const int NT4 = NT << 2;

    f32x4 acc[8][4];
    #pragma unroll
    for (int i = 0; i < 8; ++i)
        #pragma unroll
        for (int n = 0; n < 4; ++n) acc[i][n] = f32x4{0.f, 0.f, 0.f, 0.f};

    const int srow = t >> 2;       // 0..127
    const int scg0 = t & 3;

    auto issue_unit = [&](int s) {
        int ti = s >> 2, idx = s & 3;
        int kh = idx >> 1, isB = idx & 1;
        const bf16* g = isB ? Bb : Ab;
        int ld = isB ? ldb : lda;
        bf16* lp = (isB ? Bs : As) + ((ti & 1) * 2 + kh) * 8192;
        int k0 = ti * 64 + kh * 32;
        #pragma unroll
        for (int j = 0; j < 2; ++j) {
            int row = j * 128 + srow;
            int cg = scg0 ^ ((row >> 1) & 3);
            gload_lds16(g + (long)row * ld + k0 + cg * 8, lp + (j * 512 + t) * 8);
        }
    };

    #pragma unroll
    for (int s = 0; s < 6; ++s) issue_unit(s);
    asm volatile("s_waitcnt vmcnt(8)" ::: "memory");
    __builtin_amdgcn_s_barrier();
    asm volatile("" ::: "memory");

    bf16x8 bfr[4], af[4];

    for (int ti = 0; ti < NT - 2; ++ti) {
        const bf16* AsT = As + (ti & 1) * 16384;
        const bf16* BsT = Bs + (ti & 1) * 16384;
        const int sb = 4 * ti + 6;
        PH(0, 0, sb + 0, -1)
        PH(1, 0, sb + 1, 8)
        PH(0, 1, sb + 2, -1)
        PH(1, 1, sb + 3, 8)
    }
    {
        const bf16* AsT = As + ((NT - 2) & 1) * 16384;
        const bf16* BsT = Bs + ((NT - 2) & 1) * 16384;
        PH(0, 0, NT4 - 2, -1)
        PH(1, 0, NT4 - 1, 8)
        PH(0, 1, -1, -1)
        PH(1, 1, -1, 4)
    }
    {
        const bf16* AsT = As + ((NT - 1) & 1) * 16384;
        const bf16* BsT = Bs + ((NT - 1) & 1) * 16384;
        PH(0, 0, -1, -1)
        PH(1, 0, -1, 0)
        PH(0, 1, -1, -1)
        PH(1, 1, -1, -1)
    }

    const int row0 = bx * 256 + wm * 128;
    const int col0 = by * 256 + wn * 64;
    const int rq = lg * 4;

    if (EPI == 1) {
        bf16* Cz = C + z * cZ;
        #pragma unroll
        for (int i = 0; i < 8; ++i)
            #pragma unroll
            for (int n = 0; n < 4; ++n) {
                const int col = col0 + n * 16 + lr;
                #pragma unroll
                for (int r = 0; r < 4; ++r)
                    Cz[(long)(row0 + i * 16 + rq + r) * ldc + col] = (bf16)exp2f(acc[i][n][r]);
            }
    } else {
        if (by < 4) {
            // q,k -> C [row][1024] (coalesced)
            #pragma unroll
            for (int i = 0; i < 8; ++i) {
                const int row = row0 + i * 16 + rq;
                #pragma unroll
                for (int n = 0; n < 4; ++n) {
                    const int col = col0 + n * 16 + lr;
                    #pragma unroll
                    for (int r = 0; r < 4; ++r)
                        C[(long)(row + r) * 1024 + col] = (bf16)acc[i][n][r];
                }
            }
        } else {
            // v-transpose into Vt: block rows = 256 consecutive sp of one
            // image, block cols = 256 d's. 4 chunks of 64 d via LDS As.
            const int d0 = by * 256 - 1024;          // 0 or 256
            const int rb0 = bx * 256;
            const int nb = rb0 >> 12;
            const int sp0 = rb0 & 4095;
            bf16* Lt = As;                            // [64][264] bf16 = 33 KB
            #pragma unroll 1
            for (int q = 0; q < 4; ++q) {
                if (wn == q) {
                    #pragma unroll
                    for (int n = 0; n < 4; ++n) {
                        const int dl = n * 16 + lr;          // 0..63 chunk-local d
                        const int a = dl & 7;
                        #pragma unroll
                        for (int i = 0; i < 8; ++i) {
                            const int sp = wm * 128 + i * 16 + rq;   // 0..255
                            const int g = sp >> 3;
                            bf16x4 v;
                            v[0] = (bf16)acc[i][n][0]; v[1] = (bf16)acc[i][n][1];
                            v[2] = (bf16)acc[i][n][2]; v[3] = (bf16)acc[i][n][3];
                            *(bf16x4*)(Lt + dl * 264 + ((g ^ a) * 8) + (sp & 7)) = v;
                        }
                    }
                }
                __syncthreads();
                {
                    const int dl = t >> 3, c8 = t & 7, a2 = dl & 7;
                    bf16* vd = Vt + ((long)nb * 512 + d0 + q * 64 + dl) * 4096 + sp0;
                    #pragma unroll
                    for (int j = 0; j < 4; ++j) {
                        const int gr = c8 + j * 8;
                        bf16x8 vv = *(const bf16x8*)(Lt + dl * 264 + ((gr ^ a2) * 8));
                        *(bf16x8*)(vd + gr * 8) = vv;
                    }
                }
                __syncthreads();
            }
        }
    }
}

// =====================================================================
// PV GEMM (round-11 verified best): O[64 x 512] per block = P[64 x 4096]
// * V (via Vt[512][4096]) / rowsum (own-slot sums). 512 threads, 8 waves,
// BK=64, 2-tile-deep counted vmcnt, grid (64,4) = 256 blocks, 1 dispatch.
// O stored with leading dim ldo (overwrites the dead q-half of qk).
// =====================================================================
__global__ __launch_bounds__(512, 1) void k_pv(
    const bf16* __restrict__ P, const bf16* __restrict__ Vt,
    bf16* __restrict__ O, int ldo) {
    __shared__ bf16 Bs[2][512 * 64];
    __shared__ bf16 As[2][64 * 64];
    __shared__ float linv[64];
    const int t = threadIdx.x;
    const int w = t >> 6, l = t & 63, lr = l & 15, lg = l >> 4;
    const int lr7 = lr & 7;
    const int sr = t >> 3, sc8 = t & 7, sr7 = sr & 7;
    const long zz = blockIdx.y;
    const int bx = blockIdx.x;

    const bf16* Pg = P + zz * ((long)4096 * 4096) + (long)(bx * 64 + sr) * 4096 + (sc8 ^ sr7) * 8;
    const bf16* Vg = Vt + zz * ((long)512 * 4096) + (long)sr * 4096 + (sc8 ^ sr7) * 8;

    auto issue = [&](int tile, int buf) {
        gload_lds16(Pg + tile * 64, As[buf] + t * 8);
        #pragma unroll
        for (int u = 0; u < 8; ++u)
            gload_lds16(Vg + (long)u * 64 * 4096 + tile * 64, Bs[buf] + u * 4096 + t * 8);
    };

    f32x4 acc[4][4];
    #pragma unroll
    for (int i = 0; i < 4; ++i)
        #pragma unroll
        for (int n = 0; n < 4; ++n) acc[i][n] = f32x4{0.f, 0.f, 0.f, 0.f};

    float lsum = 0.f;

    issue(0, 0);
    issue(1, 1);

    for (int ti = 0; ti < 64; ++ti) {
        if (ti < 63) { asm volatile("s_waitcnt vmcnt(9)" ::: "memory"); }
        else         { asm volatile("s_waitcnt vmcnt(0)" ::: "memory"); }
        __builtin_amdgcn_s_barrier();
        asm volatile("" ::: "memory");

        const bf16* Asb = As[ti & 1];
        const bf16* Bsb = Bs[ti & 1];

        // own-slot row-partial sum (row sr) -- P as quantized to bf16
        {
            bf16x8 sv = *(const bf16x8*)(Asb + t * 8);
            #pragma unroll
            for (int j = 0; j < 8; ++j) lsum += (float)sv[j];
        }

        __builtin_amdgcn_s_setprio(1);
        #pragma unroll
        for (int kk = 0; kk < 2; ++kk) {
            bf16x8 af[4], bfv[4];
            #pragma unroll
            for (int mi = 0; mi < 4; ++mi)
                af[mi] = *(const bf16x8*)(Asb + (mi * 16 + lr) * 64 + (((kk * 4 + lg) ^ lr7) * 8));
            #pragma unroll
            for (int n = 0; n < 4; ++n)
                bfv[n] = *(const bf16x8*)(Bsb + (w * 64 + n * 16 + lr) * 64 + (((kk * 4 + lg) ^ lr7) * 8));
            #pragma unroll
            for (int mi = 0; mi < 4; ++mi)
                #pragma unroll
                for (int n = 0; n < 4; ++n)
                    acc[mi][n] = __builtin_amdgcn_mfma_f32_16x16x32_bf16(af[mi], bfv[n], acc[mi][n], 0, 0, 0);
        }
        __builtin_amdgcn_s_setprio(0);

        __builtin_amdgcn_s_barrier();
        asm volatile("" ::: "memory");
        if (ti < 62) issue(ti + 2, ti & 1);
    }

    lsum += __shfl_xor(lsum, 1);
    lsum += __shfl_xor(lsum, 2);
    lsum += __shfl_xor(lsum, 4);
    if (sc8 == 0) linv[sr] = 1.f / lsum;
    asm volatile("s_waitcnt lgkmcnt(0)" ::: "memory");
    __builtin_amdgcn_s_barrier();
    asm volatile("" ::: "memory");

    bf16* Oz = O + zz * ((long)4096 * ldo);
    #pragma unroll
    for (int mi = 0; mi < 4; ++mi) {
        float4 lv = *(const float4*)&linv[mi * 16 + lg * 4];
        #pragma unroll
        for (int n = 0; n < 4; ++n) {
            const long base = (long)(bx * 64 + mi * 16 + lg * 4) * ldo + w * 64 + n * 16 + lr;
            Oz[base]           = (bf16)(acc[mi][n][0] * lv.x);
            Oz[base + ldo]     = (bf16)(acc[mi][n][1] * lv.y);
            Oz[base + 2 * ldo] = (bf16)(acc[mi][n][2] * lv.z);
            Oz[base + 3 * ldo] = (bf16)(acc[mi][n][3] * lv.w);
        }
    }
}

// =====================================================================
// 256x128 tile, BK=64, 8-wave (4M x 2N), 8-phase, counted vmcnt.
// FUSED epilogue: transpose -> NCHW + bias + residual, straight to out.
// (LDS As reused as 32x260 f32 transpose tile after the final PH barrier.)
// =====================================================================
#define PH128(nh, kk, S_, WN)                                                      \
  {                                                                                \
    if ((nh) == 0) {                                                               \
      _Pragma("unroll")                                                            \
      for (int i = 0; i < 4; ++i) {                                                \
        int row = wm * 64 + i * 16 + lr;                                           \
        int cg = lg ^ ((row >> 1) & 3);                                            \
        af[i] = *(const bf16x8*)(AsT + (kk) * 8192 + row * 32 + cg * 8);           \
      }                                                                            \
    }                                                                              \
    _Pragma("unroll")                                                              \
    for (int j = 0; j < 2; ++j) {                                                  \
      int row = wn * 64 + ((nh) * 2 + j) * 16 + lr;                                \
      int cg = lg ^ ((row >> 1) & 3);                                              \
      bfr[j] = *(const bf16x8*)(BsT + (kk) * 4096 + row * 32 + cg * 8);            \
    }                                                                              \
    if ((S_) >= 0) issue_unit(S_);                                                 \
    __builtin_amdgcn_s_barrier();                                                  \
    asm volatile("" ::: "memory");                                                 \
    __builtin_amdgcn_s_setprio(1);                                                 \
    _Pragma("unroll")                                                              \
    for (int i = 0; i < 4; ++i)                                                    \
      _Pragma("unroll")                                                            \
      for (int j = 0; j < 2; ++j)                                                  \
        acc[i][(nh) * 2 + j] =                                                     \
            __builtin_amdgcn_mfma_f32_16x16x32_bf16(af[i], bfr[j],                 \
                                                    acc[i][(nh) * 2 + j], 0, 0, 0);\
    __builtin_amdgcn_s_setprio(0);                                                 \
    if constexpr ((WN) >= 0)                                                       \
      asm volatile("s_waitcnt vmcnt(%0)" ::"i"(WN) : "memory");                    \
    __builtin_amdgcn_s_barrier();                                                  \
    asm volatile("" ::: "memory");                                                 \
  }

__global__ __launch_bounds__(512, 2) void gemm_proj(
    const bf16* __restrict__ A, int lda,
    const bf16* __restrict__ B, int ldb,
    const float* __restrict__ bias,
    const float* __restrict__ xres,
    float* __restrict__ outp) {
    __shared__ bf16 As[2 * 2 * 256 * 32];   // 64 KB (reused for transpose)
    __shared__ bf16 Bs[2 * 2 * 128 * 32];   // 32 KB
    const int t = threadIdx.x;
    const int wid = t >> 6, l = t & 63;
    const int wm = wid >> 1, wn = wid & 1;   // 4M x 2N waves, wave tile 64x64
    const int lr = l & 15;
    const int lg = l >> 4;

    const int gx = gridDim.x;
    int nwg = gx * gridDim.y;
    int flat = blockIdx.y * gx + blockIdx.x;
    if ((nwg & 7) == 0) { int qq = nwg >> 3; flat = (flat & 7) * qq + (flat >> 3); }
    const int bx = flat % gx, by = flat / gx;

    const bf16* Ab = A + (long)bx * 256 * lda;
    const bf16* Bb = B + (long)by * 128 * ldb;

    const int NT = 8;            // K = 512
    const int NT4 = 32;

    f32x4 acc[4][4];
    #pragma unroll
    for (int i = 0; i < 4; ++i)
        #pragma unroll
        for (int n = 0; n < 4; ++n) acc[i][n] = f32x4{0.f, 0.f, 0.f, 0.f};

    const int srow = t >> 2;       // 0..127
    const int scg0 = t & 3;

    auto issue_unit = [&](int s) {
        int ti = s >> 2, idx = s & 3;
        int kh = idx >> 1, isB = idx & 1;
        int k0 = ti * 64 + kh * 32;
        if (isB) {
            bf16* lp = Bs + ((ti & 1) * 2 + kh) * 4096;
            int cg = scg0 ^ ((srow >> 1) & 3);
            gload_lds16(Bb + (long)srow * ldb + k0 + cg * 8, lp + t * 8);
        } else {
            bf16* lp = As + ((ti & 1) * 2 + kh) * 8192;
            #pragma unroll
            for (int j = 0; j < 2; ++j) {
                int row = j * 128 + srow;
                int cg = scg0 ^ ((row >> 1) & 3);
                gload_lds16(Ab + (long)row * lda + k0 + cg * 8, lp + (j * 512 + t) * 8);
            }
        }
    };

    #pragma unroll
    for (int s = 0; s < 6; ++s) issue_unit(s);
    asm volatile("s_waitcnt vmcnt(6)" ::: "memory");
    __builtin_amdgcn_s_barrier();
    asm volatile("" ::: "memory");

    bf16x8 bfr[2], af[4];

    for (int ti = 0; ti < NT - 2; ++ti) {
        const bf16* AsT = As + (ti & 1) * 16384;
        const bf16* BsT = Bs + (ti & 1) * 8192;
        const int sb = 4 * ti + 6;
        PH128(0, 0, sb + 0, -1)
        PH128(1, 0, sb + 1, 6)
        PH128(0, 1, sb + 2, -1)
        PH128(1, 1, sb + 3, 6)
    }
    {
        const bf16* AsT = As + ((NT - 2) & 1) * 16384;
        const bf16* BsT = Bs + ((NT - 2) & 1) * 8192;
        PH128(0, 0, NT4 - 2, -1)
        PH128(1, 0, NT4 - 1, 6)
        PH128(0, 1, -1, -1)
        PH128(1, 1, -1, 3)
    }
    {
        const bf16* AsT = As + ((NT - 1) & 1) * 16384;
        const bf16* BsT = Bs + ((NT - 1) & 1) * 8192;
        PH128(0, 0, -1, -1)
        PH128(1, 0, -1, 0)
        PH128(0, 1, -1, -1)
        PH128(1, 1, -1, -1)
    }

    // ---- fused epilogue: transpose -> NCHW + bias + residual ----
    const int r0 = bx * 256;
    const int c0b = by * 128;
    const int nb = r0 >> 12;
    const int sp0 = r0 & 4095;
    const int rq = lg * 4;
    float* Lt = (float*)As;                  // 32*260*4 = 33.3 KB < 64 KB
    #pragma unroll
    for (int q = 0; q < 4; ++q) {
        if (wn == (q >> 1)) {
            #pragma unroll
            for (int nn = 0; nn < 2; ++nn) {
                const int n = (q & 1) * 2 + nn;
                const int cl = nn * 16 + lr;             // 0..31
                #pragma unroll
                for (int i = 0; i < 4; ++i) {
                    const int sp = wm * 64 + i * 16 + rq;   // 0..255, mult of 4
                    float4 v;
                    v.x = acc[i][n][0]; v.y = acc[i][n][1];
                    v.z = acc[i][n][2]; v.w = acc[i][n][3];
                    *(float4*)(Lt + cl * 260 + sp) = v;
                }
            }
        }
        __syncthreads();
        {
            const int cl2 = t >> 4;                  // 0..31
            const int spc = (t & 15) * 16;           // 0..240
            const int col = c0b + q * 32 + cl2;
            const float bb = bias[col];
            const long ob = ((long)nb * 512 + col) * 4096 + sp0 + spc;
            #pragma unroll
            for (int j = 0; j < 4; ++j) {
                float4 lv = *(const float4*)(Lt + cl2 * 260 + spc + j * 4);
                float4 xv = *(const float4*)(xres + ob + j * 4);
                float4 ov;
                ov.x = lv.x + bb + xv.x; ov.y = lv.y + bb + xv.y;
                ov.z = lv.z + bb + xv.z; ov.w = lv.w + bb + xv.w;
                *(float4*)(outp + ob + j * 4) = ov;
            }
        }
        __syncthreads();
    }
}

extern "C" void kernel_launch(void* const* d_in, const int* in_sizes, int n_in,
                              void* d_out, int out_size, void* d_ws, size_t ws_size,
                              hipStream_t stream) {
    const float* x     = (const float*)d_in[0];
    const float* gnw   = (const float*)d_in[1];
    const float* gnb   = (const float*)d_in[2];
    const float* qkvw  = (const float*)d_in[3];
    const float* projw = (const float*)d_in[4];
    const float* projb = (const float*)d_in[5];

    char* ws = (char*)d_ws;
    size_t off = 0;
    auto alloc = [&](size_t bytes) {
        void* p = ws + off;
        off += (bytes + 255) & ~(size_t)255;
        return p;
    };
    // fixed: weights 2.1 MB + qk 33.55 MB + Vt 16.78 MB
    bf16*   qwb   = (bf16*)alloc((size_t)1536 * 512 * 2);
    bf16*   pwb   = (bf16*)alloc((size_t)512 * 512 * 2);
    float2* stats = (float2*)alloc((size_t)128 * 8);
    bf16*   qk    = (bf16*)alloc((size_t)16384 * 1024 * 2);  // q|k; q-half becomes O
    bf16*   Vt    = (bf16*)alloc((size_t)4 * 512 * 4096 * 2);
    // aliased region R (134.2 MB): tbuf early -> Sbuf(4z)
    char*   R     = (char*)alloc((size_t)4 * 4096 * 4096 * 2);
    bf16*   tbuf  = (bf16*)R;                                  // tokens [16384][512]
    bf16*   Sbuf  = (bf16*)R;                                  // P, all 4 z

    k_gnstats<<<128, 256, 0, stream>>>(x, stats);
    k_norm_t<<<2048, 256, 0, stream>>>(x, gnw, gnb, stats, tbuf);
    k_convw<<<4096, 256, 0, stream>>>(qkvw, projw, qwb, pwb);

    // qkv: q,k -> qk [16384][1024]; v transposed in-epilogue -> Vt
    gemm256<2><<<dim3(64, 6, 1), 512, 0, stream>>>(
        tbuf, 512, 0, qwb, 512, 0, qk, 1024, 0, 512, Vt);

    const long QZ = (long)4096 * 1024;   // z-stride in qk
    const long SZ = (long)4096 * 4096;   // z-stride in Sbuf
    // P = exp2(q k^T) for ALL 4 batches in one dispatch (1024 blocks)
    gemm256<1><<<dim3(16, 16, 4), 512, 0, stream>>>(
        qk, 1024, QZ,
        qk + 512, 1024, QZ,
        Sbuf, 4096, SZ, 512, nullptr);
    // O = (P * V) / rowsum, all 4 batches, 256 blocks = 1/CU
    k_pv<<<dim3(64, 4), 512, 0, stream>>>(Sbuf, Vt, qk, 1024);

    // proj + bias + residual + NCHW transpose, straight to d_out
    gemm_proj<<<dim3(64, 4), 512, 0, stream>>>(
        qk, 1024, pwb, 512, projb, x, (float*)d_out);
}

// Round 18
// 288.817 us; speedup vs baseline: 1.1609x; 1.0084x over previous
//
#include <hip/hip_runtime.h>
#include <hip/hip_bf16.h>

typedef __bf16 bf16;
typedef __bf16 bf16x4 __attribute__((ext_vector_type(4)));
typedef __bf16 bf16x8 __attribute__((ext_vector_type(8)));
typedef float f32x4 __attribute__((ext_vector_type(4)));

// ---------------- async global->LDS (width 16) ----------------
__device__ __forceinline__ void gload_lds16(const bf16* g, bf16* l) {
    __builtin_amdgcn_global_load_lds(
        (const __attribute__((address_space(1))) void*)g,
        (__attribute__((address_space(3))) void*)l, 16, 0, 0);
}

// ---------------- fused prologue: partial GN stats + weight conversion ----
// blocks 0..1023: group g=b>>3, slice s=b&7 -> partial (sum, sumsq) over 8192
// blocks 1024..5119: weight conversion (fold log2e/sqrt(512) into q rows)
__global__ __launch_bounds__(256) void k_pre(const float* __restrict__ x,
                                             const float* __restrict__ qw,
                                             const float* __restrict__ pw,
                                             float2* __restrict__ part,
                                             bf16* __restrict__ qwb,
                                             bf16* __restrict__ pwb) {
    const int b = blockIdx.x;
    if (b < 1024) {
        const float4* p = (const float4*)(x + (long)b * 8192);
        float s = 0.f, ss = 0.f;
        #pragma unroll
        for (int i = 0; i < 8; ++i) {
            float4 v = p[threadIdx.x + i * 256];
            s  += v.x + v.y + v.z + v.w;
            ss += v.x * v.x + v.y * v.y + v.z * v.z + v.w * v.w;
        }
        #pragma unroll
        for (int off = 32; off >= 1; off >>= 1) {
            s  += __shfl_down(s, off);
            ss += __shfl_down(ss, off);
        }
        __shared__ float rs[4], rss[4];
        if ((threadIdx.x & 63) == 0) { rs[threadIdx.x >> 6] = s; rss[threadIdx.x >> 6] = ss; }
        __syncthreads();
        if (threadIdx.x == 0)
            part[b] = make_float2(rs[0] + rs[1] + rs[2] + rs[3],
                                  rss[0] + rss[1] + rss[2] + rss[3]);
    } else {
        const int i = (b - 1024) * 256 + threadIdx.x;
        if (i < 786432) {
            float v = qw[i];
            if (i < 512 * 512) v *= 0.06376281516217733f;  // log2(e)/sqrt(512)
            qwb[i] = (bf16)v;
        } else {
            const int j = i - 786432;
            pwb[j] = (bf16)pw[j];
        }
    }
}

// ---------------- normalize + transpose NCHW -> tokens [nt][512] bf16 ------
// Finalizes GN stats inline from the 8 partials of each of its 4 groups.
__global__ __launch_bounds__(256) void k_norm_t(const float* __restrict__ x,
                                                const float* __restrict__ w,
                                                const float* __restrict__ b,
                                                const float2* __restrict__ part,
                                                bf16* __restrict__ t) {
    __shared__ float tile[64][65];
    __shared__ float2 sgs[4];
    const int bid = blockIdx.x;
    const int n = bid >> 9, rem = bid & 511;
    const int s0 = (rem >> 3) * 64, c0 = (rem & 7) * 64;
    const int tid = threadIdx.x;
    const int sl = tid & 63, cq = tid >> 6;
    if (tid < 4) {
        const float2* pp = part + ((long)(n * 32 + (c0 >> 4) + tid)) * 8;
        float S = 0.f, SS = 0.f;
        #pragma unroll
        for (int j = 0; j < 8; ++j) { S += pp[j].x; SS += pp[j].y; }
        const float mu = S * (1.f / 65536.f);
        const float var = SS * (1.f / 65536.f) - mu * mu;
        sgs[tid] = make_float2(mu, rsqrtf(var + 1e-5f));
    }
    __syncthreads();
    #pragma unroll
    for (int i = 0; i < 16; ++i) {
        const int cl = cq * 16 + i;
        const int c = c0 + cl;
        const float2 st = sgs[cl >> 4];
        const float v = x[((long)(n * 512 + c)) * 4096 + s0 + sl];
        tile[cl][sl] = (v - st.x) * st.y * w[c] + b[c];
    }
    __syncthreads();
    #pragma unroll
    for (int i = 0; i < 16; ++i) {
        const int sl2 = cq * 16 + i;
        const int cl2 = tid & 63;
        t[((long)(n * 4096 + s0 + sl2)) * 512 + c0 + cl2] = (bf16)tile[cl2][sl2];
    }
}

// =====================================================================
// 256x256 tile, BK=64, 8-wave, 8-phase GEMM with counted vmcnt (T3+T4+T5)
// LDS swizzle: granule ^= (row>>1)&3  (2-way banks = free)
// EPI 1: P = exp2(acc) bf16 store (scores in log2 domain).
// EPI 2: QKV -- by<4: q,k into C [row][1024] (coalesced);
//        by>=4: v TRANSPOSED in-epilogue into Vt[nb][512][4096].
// =====================================================================
#define PH(mh, kk, S_, WN)                                                         \
  {                                                                                \
    if ((mh) == 0) {                                                               \
      _Pragma("unroll")                                                            \
      for (int n = 0; n < 4; ++n) {                                                \
        int row = wn * 64 + n * 16 + lr;                                           \
        int cg = lg ^ ((row >> 1) & 3);                                            \
        bfr[n] = *(const bf16x8*)(BsT + (kk) * 8192 + row * 32 + cg * 8);          \
      }                                                                            \
    }                                                                              \
    _Pragma("unroll")                                                              \
    for (int i = 0; i < 4; ++i) {                                                  \
      int row = wm * 128 + ((mh) * 4 + i) * 16 + lr;                               \
      int cg = lg ^ ((row >> 1) & 3);                                              \
      af[i] = *(const bf16x8*)(AsT + (kk) * 8192 + row * 32 + cg * 8);             \
    }                                                                              \
    if ((S_) >= 0) issue_unit(S_);                                                 \
    __builtin_amdgcn_s_barrier();                                                  \
    asm volatile("" ::: "memory");                                                 \
    __builtin_amdgcn_s_setprio(1);                                                 \
    _Pragma("unroll")                                                              \
    for (int i = 0; i < 4; ++i)                                                    \
      _Pragma("unroll")                                                            \
      for (int n = 0; n < 4; ++n)                                                  \
        acc[(mh) * 4 + i][n] =                                                     \
            __builtin_amdgcn_mfma_f32_16x16x32_bf16(af[i], bfr[n],                 \
                                                    acc[(mh) * 4 + i][n], 0, 0, 0);\
    __builtin_amdgcn_s_setprio(0);                                                 \
    if constexpr ((WN) >= 0)                                                       \
      asm volatile("s_waitcnt vmcnt(%0)" ::"i"(WN) : "memory");                    \
    __builtin_amdgcn_s_barrier();                                                  \
    asm volatile("" ::: "memory");                                                 \
  }

template <int EPI>
__global__ __launch_bounds__(512, 2) void gemm256(
    const bf16* __restrict__ A, int lda, long aZ,
    const bf16* __restrict__ B, int ldb, long bZ,
    bf16* __restrict__ C, int ldc, long cZ, int K,
    bf16* __restrict__ Vt) {
    __shared__ bf16 As[2 * 2 * 256 * 32];
    __shared__ bf16 Bs[2 * 2 * 256 * 32];
    const int t = threadIdx.x;
    const int wid = t >> 6, l = t & 63;
    const int wm = wid >> 2, wn = wid & 3;     // 2 x 4 waves
    const int lr = l & 15;
    const int lg = l >> 4;                     // fragment col-group 0..3
    const long z = blockIdx.z;

    const int gx = gridDim.x;
    int nwg = gx * gridDim.y;
    int flat = blockIdx.y * gx + blockIdx.x;
    if ((nwg & 7) == 0) { int qq = nwg >> 3; flat = (flat & 7) * qq + (flat >> 3); }
    const int bx = flat % gx, by = flat / gx;

    const bf16* Ab = A + z * aZ + (long)bx * 256 * lda;
    const bf16* Bb = B + z * bZ + (long)by * 256 * ldb;

    const int NT = K >> 6;
    const int NT4 = NT << 2;

    f32x4 acc[8][4];
    #pragma unroll
    for (int i = 0; i < 8; ++i)
        #pragma unroll
        for (int n = 0; n < 4; ++n) acc[i][n] = f32x4{0.f, 0.f, 0.f, 0.f};

    const int srow = t >> 2;       // 0..127
    const int scg0 = t & 3;

    auto issue_unit = [&](int s) {
        int ti = s >> 2, idx = s & 3;
        int kh = idx >> 1, isB = idx & 1;
        const bf16* g = isB ? Bb : Ab;
        int ld = isB ? ldb : lda;
        bf16* lp = (isB ? Bs : As) + ((ti & 1) * 2 + kh) * 8192;
        int k0 = ti * 64 + kh * 32;
        #pragma unroll
        for (int j = 0; j < 2; ++j) {
            int row = j * 128 + srow;
            int cg = scg0 ^ ((row >> 1) & 3);
            gload_lds16(g + (long)row * ld + k0 + cg * 8, lp + (j * 512 + t) * 8);
        }
    };

    #pragma unroll
    for (int s = 0; s < 6; ++s) issue_unit(s);
    asm volatile("s_waitcnt vmcnt(8)" ::: "memory");
    __builtin_amdgcn_s_barrier();
    asm volatile("" ::: "memory");

    bf16x8 bfr[4], af[4];

    for (int ti = 0; ti < NT - 2; ++ti) {
        const bf16* AsT = As + (ti & 1) * 16384;
        const bf16* BsT = Bs + (ti & 1) * 16384;
        const int sb = 4 * ti + 6;
        PH(0, 0, sb + 0, -1)
        PH(1, 0, sb + 1, 8)
        PH(0, 1, sb + 2, -1)
        PH(1, 1, sb + 3, 8)
    }
    {
        const bf16* AsT = As + ((NT - 2) & 1) * 16384;
        const bf16* BsT = Bs + ((NT - 2) & 1) * 16384;
        PH(0, 0, NT4 - 2, -1)
        PH(1, 0, NT4 - 1, 8)
        PH(0, 1, -1, -1)
        PH(1, 1, -1, 4)
    }
    {
        const bf16* AsT = As + ((NT - 1) & 1) * 16384;
        const bf16* BsT = Bs + ((NT - 1) & 1) * 16384;
        PH(0, 0, -1, -1)
        PH(1, 0, -1, 0)
        PH(0, 1, -1, -1)
        PH(1, 1, -1, -1)
    }

    const int row0 = bx * 256 + wm * 128;
    const int col0 = by * 256 + wn * 64;
    const int rq = lg * 4;

    if (EPI == 1) {
        bf16* Cz = C + z * cZ;
        #pragma unroll
        for (int i = 0; i < 8; ++i)
            #pragma unroll
            for (int n = 0; n < 4; ++n) {
                const int col = col0 + n * 16 + lr;
                #pragma unroll
                for (int r = 0; r < 4; ++r)
                    Cz[(long)(row0 + i * 16 + rq + r) * ldc + col] = (bf16)exp2f(acc[i][n][r]);
            }
    } else {
        if (by < 4) {
            // q,k -> C [row][1024] (coalesced)
            #pragma unroll
            for (int i = 0; i < 8; ++i) {
                const int row = row0 + i * 16 + rq;
                #pragma unroll
                for (int n = 0; n < 4; ++n) {
                    const int col = col0 + n * 16 + lr;
                    #pragma unroll
                    for (int r = 0; r < 4; ++r)
                        C[(long)(row + r) * 1024 + col] = (bf16)acc[i][n][r];
                }
            }
        } else {
            // v-transpose into Vt: 4 chunks of 64 d via LDS As.
            const int d0 = by * 256 - 1024;          // 0 or 256
            const int rb0 = bx * 256;
            const int nb = rb0 >> 12;
            const int sp0 = rb0 & 4095;
            bf16* Lt = As;                            // [64][264] bf16 = 33 KB
            #pragma unroll 1
            for (int q = 0; q < 4; ++q) {
                if (wn == q) {
                    #pragma unroll
                    for (int n = 0; n < 4; ++n) {
                        const int dl = n * 16 + lr;          // 0..63 chunk-local d
                        const int a = dl & 7;
                        #pragma unroll
                        for (int i = 0; i < 8; ++i) {
                            const int sp = wm * 128 + i * 16 + rq;   // 0..255
                            const int g = sp >> 3;
                            bf16x4 v;
                            v[0] = (bf16)acc[i][n][0]; v[1] = (bf16)acc[i][n][1];
                            v[2] = (bf16)acc[i][n][2]; v[3] = (bf16)acc[i][n][3];
                            *(bf16x4*)(Lt + dl * 264 + ((g ^ a) * 8) + (sp & 7)) = v;
                        }
                    }
                }
                __syncthreads();
                {
                    const int dl = t >> 3, c8 = t & 7, a2 = dl & 7;
                    bf16* vd = Vt + ((long)nb * 512 + d0 + q * 64 + dl) * 4096 + sp0;
                    #pragma unroll
                    for (int j = 0; j < 4; ++j) {
                        const int gr = c8 + j * 8;
                        bf16x8 vv = *(const bf16x8*)(Lt + dl * 264 + ((gr ^ a2) * 8));
                        *(bf16x8*)(vd + gr * 8) = vv;
                    }
                }
                __syncthreads();
            }
        }
    }
}

// =====================================================================
// PV GEMM (round-11 verified best): O[64 x 512] per block = P[64 x 4096]
// * V (via Vt[512][4096]) / rowsum (own-slot sums). 512 threads, 8 waves,
// BK=64, 2-tile-deep counted vmcnt, grid (64,4) = 256 blocks, 1 dispatch.
// O stored with leading dim ldo (overwrites the dead q-half of qk).
// =====================================================================
__global__ __launch_bounds__(512, 1) void k_pv(
    const bf16* __restrict__ P, const bf16* __restrict__ Vt,
    bf16* __restrict__ O, int ldo) {
    __shared__ bf16 Bs[2][512 * 64];
    __shared__ bf16 As[2][64 * 64];
    __shared__ float linv[64];
    const int t = threadIdx.x;
    const int w = t >> 6, l = t & 63, lr = l & 15, lg = l >> 4;
    const int lr7 = lr & 7;
    const int sr = t >> 3, sc8 = t & 7, sr7 = sr & 7;
    const long zz = blockIdx.y;
    const int bx = blockIdx.x;

    const bf16* Pg = P + zz * ((long)4096 * 4096) + (long)(bx * 64 + sr) * 4096 + (sc8 ^ sr7) * 8;
    const bf16* Vg = Vt + zz * ((long)512 * 4096) + (long)sr * 4096 + (sc8 ^ sr7) * 8;

    auto issue = [&](int tile, int buf) {
        gload_lds16(Pg + tile * 64, As[buf] + t * 8);
        #pragma unroll
        for (int u = 0; u < 8; ++u)
            gload_lds16(Vg + (long)u * 64 * 4096 + tile * 64, Bs[buf] + u * 4096 + t * 8);
    };

    f32x4 acc[4][4];
    #pragma unroll
    for (int i = 0; i < 4; ++i)
        #pragma unroll
        for (int n = 0; n < 4; ++n) acc[i][n] = f32x4{0.f, 0.f, 0.f, 0.f};

    float lsum = 0.f;

    issue(0, 0);
    issue(1, 1);

    for (int ti = 0; ti < 64; ++ti) {
        if (ti < 63) { asm volatile("s_waitcnt vmcnt(9)" ::: "memory"); }
        else         { asm volatile("s_waitcnt vmcnt(0)" ::: "memory"); }
        __builtin_amdgcn_s_barrier();
        asm volatile("" ::: "memory");

        const bf16* Asb = As[ti & 1];
        const bf16* Bsb = Bs[ti & 1];

        // own-slot row-partial sum (row sr) -- P as quantized to bf16
        {
            bf16x8 sv = *(const bf16x8*)(Asb + t * 8);
            #pragma unroll
            for (int j = 0; j < 8; ++j) lsum += (float)sv[j];
        }

        __builtin_amdgcn_s_setprio(1);
        #pragma unroll
        for (int kk = 0; kk < 2; ++kk) {
            bf16x8 af[4], bfv[4];
            #pragma unroll
            for (int mi = 0; mi < 4; ++mi)
                af[mi] = *(const bf16x8*)(Asb + (mi * 16 + lr) * 64 + (((kk * 4 + lg) ^ lr7) * 8));
            #pragma unroll
            for (int n = 0; n < 4; ++n)
                bfv[n] = *(const bf16x8*)(Bsb + (w * 64 + n * 16 + lr) * 64 + (((kk * 4 + lg) ^ lr7) * 8));
            #pragma unroll
            for (int mi = 0; mi < 4; ++mi)
                #pragma unroll
                for (int n = 0; n < 4; ++n)
                    acc[mi][n] = __builtin_amdgcn_mfma_f32_16x16x32_bf16(af[mi], bfv[n], acc[mi][n], 0, 0, 0);
        }
        __builtin_amdgcn_s_setprio(0);

        __builtin_amdgcn_s_barrier();
        asm volatile("" ::: "memory");
        if (ti < 62) issue(ti + 2, ti & 1);
    }

    lsum += __shfl_xor(lsum, 1);
    lsum += __shfl_xor(lsum, 2);
    lsum += __shfl_xor(lsum, 4);
    if (sc8 == 0) linv[sr] = 1.f / lsum;
    asm volatile("s_waitcnt lgkmcnt(0)" ::: "memory");
    __builtin_amdgcn_s_barrier();
    asm volatile("" ::: "memory");

    bf16* Oz = O + zz * ((long)4096 * ldo);
    #pragma unroll
    for (int mi = 0; mi < 4; ++mi) {
        float4 lv = *(const float4*)&linv[mi * 16 + lg * 4];
        #pragma unroll
        for (int n = 0; n < 4; ++n) {
            const long base = (long)(bx * 64 + mi * 16 + lg * 4) * ldo + w * 64 + n * 16 + lr;
            Oz[base]           = (bf16)(acc[mi][n][0] * lv.x);
            Oz[base + ldo]     = (bf16)(acc[mi][n][1] * lv.y);
            Oz[base + 2 * ldo] = (bf16)(acc[mi][n][2] * lv.z);
            Oz[base + 3 * ldo] = (bf16)(acc[mi][n][3] * lv.w);
        }
    }
}

// =====================================================================
// 256x128 tile, BK=64, 8-wave (4M x 2N), 8-phase, counted vmcnt.
// FUSED epilogue: transpose -> NCHW + bias + residual, straight to out.
// =====================================================================
#define PH128(nh, kk, S_, WN)                                                      \
  {                                                                                \
    if ((nh) == 0) {                                                               \
      _Pragma("unroll")                                                            \
      for (int i = 0; i < 4; ++i) {                                                \
        int row = wm * 64 + i * 16 + lr;                                           \
        int cg = lg ^ ((row >> 1) & 3);                                            \
        af[i] = *(const bf16x8*)(AsT + (kk) * 8192 + row * 32 + cg * 8);           \
      }                                                                            \
    }                                                                              \
    _Pragma("unroll")                                                              \
    for (int j = 0; j < 2; ++j) {                                                  \
      int row = wn * 64 + ((nh) * 2 + j) * 16 + lr;                                \
      int cg = lg ^ ((row >> 1) & 3);                                              \
      bfr[j] = *(const bf16x8*)(BsT + (kk) * 4096 + row * 32 + cg * 8);            \
    }                                                                              \
    if ((S_) >= 0) issue_unit(S_);                                                 \
    __builtin_amdgcn_s_barrier();                                                  \
    asm volatile("" ::: "memory");                                                 \
    __builtin_amdgcn_s_setprio(1);                                                 \
    _Pragma("unroll")                                                              \
    for (int i = 0; i < 4; ++i)                                                    \
      _Pragma("unroll")                                                            \
      for (int j = 0; j < 2; ++j)                                                  \
        acc[i][(nh) * 2 + j] =                                                     \
            __builtin_amdgcn_mfma_f32_16x16x32_bf16(af[i], bfr[j],                 \
                                                    acc[i][(nh) * 2 + j], 0, 0, 0);\
    __builtin_amdgcn_s_setprio(0);                                                 \
    if constexpr ((WN) >= 0)                                                       \
      asm volatile("s_waitcnt vmcnt(%0)" ::"i"(WN) : "memory");                    \
    __builtin_amdgcn_s_barrier();                                                  \
    asm volatile("" ::: "memory");                                                 \
  }

__global__ __launch_bounds__(512, 2) void gemm_proj(
    const bf16* __restrict__ A, int lda,
    const bf16* __restrict__ B, int ldb,
    const float* __restrict__ bias,
    const float* __restrict__ xres,
    float* __restrict__ outp) {
    __shared__ bf16 As[2 * 2 * 256 * 32];   // 64 KB (reused for transpose)
    __shared__ bf16 Bs[2 * 2 * 128 * 32];   // 32 KB
    const int t = threadIdx.x;
    const int wid = t >> 6, l = t & 63;
    const int wm = wid >> 1, wn = wid & 1;   // 4M x 2N waves, wave tile 64x64
    const int lr = l & 15;
    const int lg = l >> 4;

    const int gx = gridDim.x;
    int nwg = gx * gridDim.y;
    int flat = blockIdx.y * gx + blockIdx.x;
    if ((nwg & 7) == 0) { int qq = nwg >> 3; flat = (flat & 7) * qq + (flat >> 3); }
    const int bx = flat % gx, by = flat / gx;

    const bf16* Ab = A + (long)bx * 256 * lda;
    const bf16* Bb = B + (long)by * 128 * ldb;

    const int NT = 8;            // K = 512
    const int NT4 = 32;

    f32x4 acc[4][4];
    #pragma unroll
    for (int i = 0; i < 4; ++i)
        #pragma unroll
        for (int n = 0; n < 4; ++n) acc[i][n] = f32x4{0.f, 0.f, 0.f, 0.f};

    const int srow = t >> 2;       // 0..127
    const int scg0 = t & 3;

    auto issue_unit = [&](int s) {
        int ti = s >> 2, idx = s & 3;
        int kh = idx >> 1, isB = idx & 1;
        int k0 = ti * 64 + kh * 32;
        if (isB) {
            bf16* lp = Bs + ((ti & 1) * 2 + kh) * 4096;
            int cg = scg0 ^ ((srow >> 1) & 3);
            gload_lds16(Bb + (long)srow * ldb + k0 + cg * 8, lp + t * 8);
        } else {
            bf16* lp = As + ((ti & 1) * 2 + kh) * 8192;
            #pragma unroll
            for (int j = 0; j < 2; ++j) {
                int row = j * 128 + srow;
                int cg = scg0 ^ ((row >> 1) & 3);
                gload_lds16(Ab + (long)row * lda + k0 + cg * 8, lp + (j * 512 + t) * 8);
            }
        }
    };

    #pragma unroll
    for (int s = 0; s < 6; ++s) issue_unit(s);
    asm volatile("s_waitcnt vmcnt(6)" ::: "memory");
    __builtin_amdgcn_s_barrier();
    asm volatile("" ::: "memory");

    bf16x8 bfr[2], af[4];

    for (int ti = 0; ti < NT - 2; ++ti) {
        const bf16* AsT = As + (ti & 1) * 16384;
        const bf16* BsT = Bs + (ti & 1) * 8192;
        const int sb = 4 * ti + 6;
        PH128(0, 0, sb + 0, -1)
        PH128(1, 0, sb + 1, 6)
        PH128(0, 1, sb + 2, -1)
        PH128(1, 1, sb + 3, 6)
    }
    {
        const bf16* AsT = As + ((NT - 2) & 1) * 16384;
        const bf16* BsT = Bs + ((NT - 2) & 1) * 8192;
        PH128(0, 0, NT4 - 2, -1)
        PH128(1, 0, NT4 - 1, 6)
        PH128(0, 1, -1, -1)
        PH128(1, 1, -1, 3)
    }
    {
        const bf16* AsT = As + ((NT - 1) & 1) * 16384;
        const bf16* BsT = Bs + ((NT - 1) & 1) * 8192;
        PH128(0, 0, -1, -1)
        PH128(1, 0, -1, 0)
        PH128(0, 1, -1, -1)
        PH128(1, 1, -1, -1)
    }

    // ---- fused epilogue: transpose -> NCHW + bias + residual ----
    const int r0 = bx * 256;
    const int c0b = by * 128;
    const int nb = r0 >> 12;
    const int sp0 = r0 & 4095;
    const int rq = lg * 4;
    float* Lt = (float*)As;                  // 32*260*4 = 33.3 KB < 64 KB
    #pragma unroll
    for (int q = 0; q < 4; ++q) {
        if (wn == (q >> 1)) {
            #pragma unroll
            for (int nn = 0; nn < 2; ++nn) {
                const int n = (q & 1) * 2 + nn;
                const int cl = nn * 16 + lr;             // 0..31
                #pragma unroll
                for (int i = 0; i < 4; ++i) {
                    const int sp = wm * 64 + i * 16 + rq;   // 0..255, mult of 4
                    float4 v;
                    v.x = acc[i][n][0]; v.y = acc[i][n][1];
                    v.z = acc[i][n][2]; v.w = acc[i][n][3];
                    *(float4*)(Lt + cl * 260 + sp) = v;
                }
            }
        }
        __syncthreads();
        {
            const int cl2 = t >> 4;                  // 0..31
            const int spc = (t & 15) * 16;           // 0..240
            const int col = c0b + q * 32 + cl2;
            const float bb = bias[col];
            const long ob = ((long)nb * 512 + col) * 4096 + sp0 + spc;
            #pragma unroll
            for (int j = 0; j < 4; ++j) {
                float4 lv = *(const float4*)(Lt + cl2 * 260 + spc + j * 4);
                float4 xv = *(const float4*)(xres + ob + j * 4);
                float4 ov;
                ov.x = lv.x + bb + xv.x; ov.y = lv.y + bb + xv.y;
                ov.z = lv.z + bb + xv.z; ov.w = lv.w + bb + xv.w;
                *(float4*)(outp + ob + j * 4) = ov;
            }
        }
        __syncthreads();
    }
}

extern "C" void kernel_launch(void* const* d_in, const int* in_sizes, int n_in,
                              void* d_out, int out_size, void* d_ws, size_t ws_size,
                              hipStream_t stream) {
    const float* x     = (const float*)d_in[0];
    const float* gnw   = (const float*)d_in[1];
    const float* gnb   = (const float*)d_in[2];
    const float* qkvw  = (const float*)d_in[3];
    const float* projw = (const float*)d_in[4];
    const float* projb = (const float*)d_in[5];

    char* ws = (char*)d_ws;
    size_t off = 0;
    auto alloc = [&](size_t bytes) {
        void* p = ws + off;
        off += (bytes + 255) & ~(size_t)255;
        return p;
    };
    // fixed: weights 2.1 MB + qk 33.55 MB + Vt 16.78 MB
    bf16*   qwb   = (bf16*)alloc((size_t)1536 * 512 * 2);
    bf16*   pwb   = (bf16*)alloc((size_t)512 * 512 * 2);
    float2* part  = (float2*)alloc((size_t)1024 * 8);
    bf16*   qk    = (bf16*)alloc((size_t)16384 * 1024 * 2);  // q|k; q-half becomes O
    bf16*   Vt    = (bf16*)alloc((size_t)4 * 512 * 4096 * 2);
    // aliased region R (134.2 MB): tbuf early -> Sbuf(4z)
    char*   R     = (char*)alloc((size_t)4 * 4096 * 4096 * 2);
    bf16*   tbuf  = (bf16*)R;                                  // tokens [16384][512]
    bf16*   Sbuf  = (bf16*)R;                                  // P, all 4 z

    // fused prologue: partial GN stats (1024 blocks) + weight conv (4096)
    k_pre<<<5120, 256, 0, stream>>>(x, qkvw, projw, part, qwb, pwb);
    k_norm_t<<<2048, 256, 0, stream>>>(x, gnw, gnb, part, tbuf);

    // qkv: q,k -> qk [16384][1024]; v transposed in-epilogue -> Vt
    gemm256<2><<<dim3(64, 6, 1), 512, 0, stream>>>(
        tbuf, 512, 0, qwb, 512, 0, qk, 1024, 0, 512, Vt);

    const long QZ = (long)4096 * 1024;   // z-stride in qk
    const long SZ = (long)4096 * 4096;   // z-stride in Sbuf
    // P = exp2(q k^T) for ALL 4 batches in one dispatch (1024 blocks)
    gemm256<1><<<dim3(16, 16, 4), 512, 0, stream>>>(
        qk, 1024, QZ,
        qk + 512, 1024, QZ,
        Sbuf, 4096, SZ, 512, nullptr);
    // O = (P * V) / rowsum, all 4 batches, 256 blocks = 1/CU
    k_pv<<<dim3(64, 4), 512, 0, stream>>>(Sbuf, Vt, qk, 1024);

    // proj + bias + residual + NCHW transpose, straight to d_out
    gemm_proj<<<dim3(64, 4), 512, 0, stream>>>(
        qk, 1024, pwb, 512, projb, x, (float*)d_out);
}

// Round 19
// 267.240 us; speedup vs baseline: 1.2547x; 1.0807x over previous
//
#include <hip/hip_runtime.h>
#include <hip/hip_bf16.h>

typedef __bf16 bf16;
typedef __bf16 bf16x4 __attribute__((ext_vector_type(4)));
typedef __bf16 bf16x8 __attribute__((ext_vector_type(8)));
typedef float f32x4 __attribute__((ext_vector_type(4)));

// ---------------- async global->LDS (width 16) ----------------
__device__ __forceinline__ void gload_lds16(const bf16* g, bf16* l) {
    __builtin_amdgcn_global_load_lds(
        (const __attribute__((address_space(1))) void*)g,
        (__attribute__((address_space(3))) void*)l, 16, 0, 0);
}

// ---------------- fused prologue: partial GN stats + weight conversion ----
__global__ __launch_bounds__(256) void k_pre(const float* __restrict__ x,
                                             const float* __restrict__ qw,
                                             const float* __restrict__ pw,
                                             float2* __restrict__ part,
                                             bf16* __restrict__ qwb,
                                             bf16* __restrict__ pwb) {
    const int b = blockIdx.x;
    if (b < 1024) {
        const float4* p = (const float4*)(x + (long)b * 8192);
        float s = 0.f, ss = 0.f;
        #pragma unroll
        for (int i = 0; i < 8; ++i) {
            float4 v = p[threadIdx.x + i * 256];
            s  += v.x + v.y + v.z + v.w;
            ss += v.x * v.x + v.y * v.y + v.z * v.z + v.w * v.w;
        }
        #pragma unroll
        for (int off = 32; off >= 1; off >>= 1) {
            s  += __shfl_down(s, off);
            ss += __shfl_down(ss, off);
        }
        __shared__ float rs[4], rss[4];
        if ((threadIdx.x & 63) == 0) { rs[threadIdx.x >> 6] = s; rss[threadIdx.x >> 6] = ss; }
        __syncthreads();
        if (threadIdx.x == 0)
            part[b] = make_float2(rs[0] + rs[1] + rs[2] + rs[3],
                                  rss[0] + rss[1] + rss[2] + rss[3]);
    } else {
        const int i = (b - 1024) * 256 + threadIdx.x;
        if (i < 786432) {
            float v = qw[i];
            if (i < 512 * 512) v *= 0.06376281516217733f;  // log2(e)/sqrt(512)
            qwb[i] = (bf16)v;
        } else {
            const int j = i - 786432;
            pwb[j] = (bf16)pw[j];
        }
    }
}

// ---------------- normalize + transpose NCHW -> tokens [nt][512] bf16 ------
__global__ __launch_bounds__(256) void k_norm_t(const float* __restrict__ x,
                                                const float* __restrict__ w,
                                                const float* __restrict__ b,
                                                const float2* __restrict__ part,
                                                bf16* __restrict__ t) {
    __shared__ float tile[64][65];
    __shared__ float2 sgs[4];
    const int bid = blockIdx.x;
    const int n = bid >> 9, rem = bid & 511;
    const int s0 = (rem >> 3) * 64, c0 = (rem & 7) * 64;
    const int tid = threadIdx.x;
    const int sl = tid & 63, cq = tid >> 6;
    if (tid < 4) {
        const float2* pp = part + ((long)(n * 32 + (c0 >> 4) + tid)) * 8;
        float S = 0.f, SS = 0.f;
        #pragma unroll
        for (int j = 0; j < 8; ++j) { S += pp[j].x; SS += pp[j].y; }
        const float mu = S * (1.f / 65536.f);
        const float var = SS * (1.f / 65536.f) - mu * mu;
        sgs[tid] = make_float2(mu, rsqrtf(var + 1e-5f));
    }
    __syncthreads();
    #pragma unroll
    for (int i = 0; i < 16; ++i) {
        const int cl = cq * 16 + i;
        const int c = c0 + cl;
        const float2 st = sgs[cl >> 4];
        const float v = x[((long)(n * 512 + c)) * 4096 + s0 + sl];
        tile[cl][sl] = (v - st.x) * st.y * w[c] + b[c];
    }
    __syncthreads();
    #pragma unroll
    for (int i = 0; i < 16; ++i) {
        const int sl2 = cq * 16 + i;
        const int cl2 = tid & 63;
        t[((long)(n * 4096 + s0 + sl2)) * 512 + c0 + cl2] = (bf16)tile[cl2][sl2];
    }
}

// =====================================================================
// 256x256 tile, BK=64, 8-wave, 8-phase GEMM with counted vmcnt (T3+T4+T5)
// LDS swizzle: granule ^= (row>>1)&3  (2-way banks = free)
// EPI 1: P = exp2(acc) bf16 store (scores in log2 domain).
// EPI 2: QKV -- by<4: q,k into C [row][1024]; by>=4: v transposed -> Vt.
// =====================================================================
#define PH(mh, kk, S_, WN)                                                         \
  {                                                                                \
    if ((mh) == 0) {                                                               \
      _Pragma("unroll")                                                            \
      for (int n = 0; n < 4; ++n) {                                                \
        int row = wn * 64 + n * 16 + lr;                                           \
        int cg = lg ^ ((row >> 1) & 3);                                            \
        bfr[n] = *(const bf16x8*)(BsT + (kk) * 8192 + row * 32 + cg * 8);          \
      }                                                                            \
    }                                                                              \
    _Pragma("unroll")                                                              \
    for (int i = 0; i < 4; ++i) {                                                  \
      int row = wm * 128 + ((mh) * 4 + i) * 16 + lr;                               \
      int cg = lg ^ ((row >> 1) & 3);                                              \
      af[i] = *(const bf16x8*)(AsT + (kk) * 8192 + row * 32 + cg * 8);             \
    }                                                                              \
    if ((S_) >= 0) issue_unit(S_);                                                 \
    __builtin_amdgcn_s_barrier();                                                  \
    asm volatile("" ::: "memory");                                                 \
    __builtin_amdgcn_s_setprio(1);                                                 \
    _Pragma("unroll")                                                              \
    for (int i = 0; i < 4; ++i)                                                    \
      _Pragma("unroll")                                                            \
      for (int n = 0; n < 4; ++n)                                                  \
        acc[(mh) * 4 + i][n] =                                                     \
            __builtin_amdgcn_mfma_f32_16x16x32_bf16(af[i], bfr[n],                 \
                                                    acc[(mh) * 4 + i][n], 0, 0, 0);\
    __builtin_amdgcn_s_setprio(0);                                                 \
    if constexpr ((WN) >= 0)                                                       \
      asm volatile("s_waitcnt vmcnt(%0)" ::"i"(WN) : "memory");                    \
    __builtin_amdgcn_s_barrier();                                                  \
    asm volatile("" ::: "memory");                                                 \
  }

template <int EPI>
__global__ __launch_bounds__(512, 2) void gemm256(
    const bf16* __restrict__ A, int lda, long aZ,
    const bf16* __restrict__ B, int ldb, long bZ,
    bf16* __restrict__ C, int ldc, long cZ, int K,
    bf16* __restrict__ Vt) {
    __shared__ bf16 As[2 * 2 * 256 * 32];
    __shared__ bf16 Bs[2 * 2 * 256 * 32];
    const int t = threadIdx.x;
    const int wid = t >> 6, l = t & 63;
    const int wm = wid >> 2, wn = wid & 3;     // 2 x 4 waves
    const int lr = l & 15;
    const int lg = l >> 4;                     // fragment col-group 0..3
    const long z = blockIdx.z;

    const int gx = gridDim.x;
    int nwg = gx * gridDim.y;
    int flat = blockIdx.y * gx + blockIdx.x;
    if ((nwg & 7) == 0) { int qq = nwg >> 3; flat = (flat & 7) * qq + (flat >> 3); }
    const int bx = flat % gx, by = flat / gx;

    const bf16* Ab = A + z * aZ + (long)bx * 256 * lda;
    const bf16* Bb = B + z * bZ + (long)by * 256 * ldb;

    const int NT = K >> 6;
    const int NT4 = NT << 2;

    f32x4 acc[8][4];
    #pragma unroll
    for (int i = 0; i < 8; ++i)
        #pragma unroll
        for (int n = 0; n < 4; ++n) acc[i][n] = f32x4{0.f, 0.f, 0.f, 0.f};

    const int srow = t >> 2;       // 0..127
    const int scg0 = t & 3;

    auto issue_unit = [&](int s) {
        int ti = s >> 2, idx = s & 3;
        int kh = idx >> 1, isB = idx & 1;
        const bf16* g = isB ? Bb : Ab;
        int ld = isB ? ldb : lda;
        bf16* lp = (isB ? Bs : As) + ((ti & 1) * 2 + kh) * 8192;
        int k0 = ti * 64 + kh * 32;
        #pragma unroll
        for (int j = 0; j < 2; ++j) {
            int row = j * 128 + srow;
            int cg = scg0 ^ ((row >> 1) & 3);
            gload_lds16(g + (long)row * ld + k0 + cg * 8, lp + (j * 512 + t) * 8);
        }
    };

    #pragma unroll
    for (int s = 0; s < 6; ++s) issue_unit(s);
    asm volatile("s_waitcnt vmcnt(8)" ::: "memory");
    __builtin_amdgcn_s_barrier();
    asm volatile("" ::: "memory");

    bf16x8 bfr[4], af[4];

    for (int ti = 0; ti < NT - 2; ++ti) {
        const bf16* AsT = As + (ti & 1) * 16384;
        const bf16* BsT = Bs + (ti & 1) * 16384;
        const int sb = 4 * ti + 6;
        PH(0, 0, sb + 0, -1)
        PH(1, 0, sb + 1, 8)
        PH(0, 1, sb + 2, -1)
        PH(1, 1, sb + 3, 8)
    }
    {
        const bf16* AsT = As + ((NT - 2) & 1) * 16384;
        const bf16* BsT = Bs + ((NT - 2) & 1) * 16384;
        PH(0, 0, NT4 - 2, -1)
        PH(1, 0, NT4 - 1, 8)
        PH(0, 1, -1, -1)
        PH(1, 1, -1, 4)
    }
    {
        const bf16* AsT = As + ((NT - 1) & 1) * 16384;
        const bf16* BsT = Bs + ((NT - 1) & 1) * 16384;
        PH(0, 0, -1, -1)
        PH(1, 0, -1, 0)
        PH(0, 1, -1, -1)
        PH(1, 1, -1, -1)
    }

    const int row0 = bx * 256 + wm * 128;
    const int col0 = by * 256 + wn * 64;
    const int rq = lg * 4;

    if (EPI == 1) {
        bf16* Cz = C + z * cZ;
        #pragma unroll
        for (int i = 0; i < 8; ++i)
            #pragma unroll
            for (int n = 0; n < 4; ++n) {
                const int col = col0 + n * 16 + lr;
                #pragma unroll
                for (int r = 0; r < 4; ++r)
                    Cz[(long)(row0 + i * 16 + rq + r) * ldc + col] = (bf16)exp2f(acc[i][n][r]);
            }
    } else {
        if (by < 4) {
            #pragma unroll
            for (int i = 0; i < 8; ++i) {
                const int row = row0 + i * 16 + rq;
                #pragma unroll
                for (int n = 0; n < 4; ++n) {
                    const int col = col0 + n * 16 + lr;
                    #pragma unroll
                    for (int r = 0; r < 4; ++r)
                        C[(long)(row + r) * 1024 + col] = (bf16)acc[i][n][r];
                }
            }
        } else {
            // v-transpose into Vt: 4 chunks of 64 d via LDS As.
            const int d0 = by * 256 - 1024;          // 0 or 256
            const int rb0 = bx * 256;
            const int nb = rb0 >> 12;
            const int sp0 = rb0 & 4095;
            bf16* Lt = As;                            // [64][264] bf16 = 33 KB
            #pragma unroll 1
            for (int q = 0; q < 4; ++q) {
                if (wn == q) {
                    #pragma unroll
                    for (int n = 0; n < 4; ++n) {
                        const int dl = n * 16 + lr;          // 0..63 chunk-local d
                        const int a = dl & 7;
                        #pragma unroll
                        for (int i = 0; i < 8; ++i) {
                            const int sp = wm * 128 + i * 16 + rq;   // 0..255
                            const int g = sp >> 3;
                            bf16x4 v;
                            v[0] = (bf16)acc[i][n][0]; v[1] = (bf16)acc[i][n][1];
                            v[2] = (bf16)acc[i][n][2]; v[3] = (bf16)acc[i][n][3];
                            *(bf16x4*)(Lt + dl * 264 + ((g ^ a) * 8) + (sp & 7)) = v;
                        }
                    }
                }
                __syncthreads();
                {
                    const int dl = t >> 3, c8 = t & 7, a2 = dl & 7;
                    bf16* vd = Vt + ((long)nb * 512 + d0 + q * 64 + dl) * 4096 + sp0;
                    #pragma unroll
                    for (int j = 0; j < 4; ++j) {
                        const int gr = c8 + j * 8;
                        bf16x8 vv = *(const bf16x8*)(Lt + dl * 264 + ((gr ^ a2) * 8));
                        *(bf16x8*)(vd + gr * 8) = vv;
                    }
                }
                __syncthreads();
            }
        }
    }
}

// =====================================================================
// PV GEMM v3 -- split-D for 2 blocks/CU (independent barrier groups):
// O[64 x 256] per block = P[64 x 4096] * V-half / rowsum. 256 threads,
// 4 waves, BK=64, 2-tile-deep counted vmcnt(10) (2 P units + 8 V units
// per tile, uniform across threads). LDS exactly 80KB (Bs 2x32K +
// As 2x8K; linv aliases dead As[0] after the loop). Grid (64,2,4) =
// 512 blocks = 2/CU. Rowsum own-slot on 2 rows/thread (duplicated
// across D-halves -- deterministic, cheap). O -> dead q-half of qk.
// =====================================================================
__global__ __launch_bounds__(256, 2) void k_pv(
    const bf16* __restrict__ P, const bf16* __restrict__ Vt,
    bf16* __restrict__ O, int ldo) {
    __shared__ bf16 Bs[2][256 * 64];   // 2 x 32 KB
    __shared__ bf16 As[2][64 * 64];    // 2 x 8 KB
    const int t = threadIdx.x;
    const int w = t >> 6, l = t & 63, lr = l & 15, lg = l >> 4;
    const int lr7 = lr & 7;
    const int r8 = t >> 3, c8 = t & 7, s7 = r8 & 7;   // r8: 0..31
    const long zz = blockIdx.z;
    const int dh = blockIdx.y;
    const int bx = blockIdx.x;

    // P unit j covers row j*32 + r8 (j*32 % 8 == 0 -> same swizzle term s7)
    const bf16* Pg = P + zz * ((long)4096 * 4096)
                       + (long)(bx * 64 + r8) * 4096 + (c8 ^ s7) * 8;
    // V unit u covers d = dh*256 + u*32 + r8
    const bf16* Vg = Vt + zz * ((long)512 * 4096)
                        + (long)(dh * 256 + r8) * 4096 + (c8 ^ s7) * 8;

    auto issue = [&](int tile, int buf) {
        #pragma unroll
        for (int j = 0; j < 2; ++j)
            gload_lds16(Pg + (long)j * 32 * 4096 + tile * 64,
                        As[buf] + (j * 256 + t) * 8);
        #pragma unroll
        for (int u = 0; u < 8; ++u)
            gload_lds16(Vg + (long)u * 32 * 4096 + tile * 64,
                        Bs[buf] + (u * 256 + t) * 8);
    };

    f32x4 acc[4][4];
    #pragma unroll
    for (int i = 0; i < 4; ++i)
        #pragma unroll
        for (int n = 0; n < 4; ++n) acc[i][n] = f32x4{0.f, 0.f, 0.f, 0.f};

    float lsum0 = 0.f, lsum1 = 0.f;

    issue(0, 0);
    issue(1, 1);

    for (int ti = 0; ti < 64; ++ti) {
        if (ti < 63) { asm volatile("s_waitcnt vmcnt(10)" ::: "memory"); }
        else         { asm volatile("s_waitcnt vmcnt(0)" ::: "memory"); }
        __builtin_amdgcn_s_barrier();
        asm volatile("" ::: "memory");

        const bf16* Asb = As[ti & 1];
        const bf16* Bsb = Bs[ti & 1];

        // own-slot row-partial sums: rows r8 and 32+r8
        {
            bf16x8 s0 = *(const bf16x8*)(Asb + t * 8);
            bf16x8 s1 = *(const bf16x8*)(Asb + (256 + t) * 8);
            #pragma unroll
            for (int j = 0; j < 8; ++j) { lsum0 += (float)s0[j]; lsum1 += (float)s1[j]; }
        }

        __builtin_amdgcn_s_setprio(1);
        #pragma unroll
        for (int kk = 0; kk < 2; ++kk) {
            bf16x8 af[4], bfv[4];
            #pragma unroll
            for (int mi = 0; mi < 4; ++mi)
                af[mi] = *(const bf16x8*)(Asb + (mi * 16 + lr) * 64 + (((kk * 4 + lg) ^ lr7) * 8));
            #pragma unroll
            for (int n = 0; n < 4; ++n)
                bfv[n] = *(const bf16x8*)(Bsb + (w * 64 + n * 16 + lr) * 64 + (((kk * 4 + lg) ^ lr7) * 8));
            #pragma unroll
            for (int mi = 0; mi < 4; ++mi)
                #pragma unroll
                for (int n = 0; n < 4; ++n)
                    acc[mi][n] = __builtin_amdgcn_mfma_f32_16x16x32_bf16(af[mi], bfv[n], acc[mi][n], 0, 0, 0);
        }
        __builtin_amdgcn_s_setprio(0);

        __builtin_amdgcn_s_barrier();
        asm volatile("" ::: "memory");
        if (ti < 62) issue(ti + 2, ti & 1);
    }

    // reduce over the 8 threads (c8) sharing each row; linv aliases As[0]
    lsum0 += __shfl_xor(lsum0, 1);
    lsum0 += __shfl_xor(lsum0, 2);
    lsum0 += __shfl_xor(lsum0, 4);
    lsum1 += __shfl_xor(lsum1, 1);
    lsum1 += __shfl_xor(lsum1, 2);
    lsum1 += __shfl_xor(lsum1, 4);
    float* linv = (float*)&As[0][0];
    __builtin_amdgcn_s_barrier();           // all MFMA LDS reads done
    asm volatile("" ::: "memory");
    if (c8 == 0) { linv[r8] = 1.f / lsum0; linv[32 + r8] = 1.f / lsum1; }
    asm volatile("s_waitcnt lgkmcnt(0)" ::: "memory");
    __builtin_amdgcn_s_barrier();
    asm volatile("" ::: "memory");

    bf16* Oz = O + zz * ((long)4096 * ldo);
    #pragma unroll
    for (int mi = 0; mi < 4; ++mi) {
        float4 lv = *(const float4*)&linv[mi * 16 + lg * 4];
        #pragma unroll
        for (int n = 0; n < 4; ++n) {
            const long base = (long)(bx * 64 + mi * 16 + lg * 4) * ldo
                              + dh * 256 + w * 64 + n * 16 + lr;
            Oz[base]           = (bf16)(acc[mi][n][0] * lv.x);
            Oz[base + ldo]     = (bf16)(acc[mi][n][1] * lv.y);
            Oz[base + 2 * ldo] = (bf16)(acc[mi][n][2] * lv.z);
            Oz[base + 3 * ldo] = (bf16)(acc[mi][n][3] * lv.w);
        }
    }
}

// =====================================================================
// 256x128 tile, BK=64, 8-wave (4M x 2N), 8-phase, counted vmcnt.
// FUSED epilogue: transpose -> NCHW + bias + residual, straight to out.
// =====================================================================
#define PH128(nh, kk, S_, WN)                                                      \
  {                                                                                \
    if ((nh) == 0) {                                                               \
      _Pragma("unroll")                                                            \
      for (int i = 0; i < 4; ++i) {                                                \
        int row = wm * 64 + i * 16 + lr;                                           \
        int cg = lg ^ ((row >> 1) & 3);                                            \
        af[i] = *(const bf16x8*)(AsT + (kk) * 8192 + row * 32 + cg * 8);           \
      }                                                                            \
    }                                                                              \
    _Pragma("unroll")                                                              \
    for (int j = 0; j < 2; ++j) {                                                  \
      int row = wn * 64 + ((nh) * 2 + j) * 16 + lr;                                \
      int cg = lg ^ ((row >> 1) & 3);                                              \
      bfr[j] = *(const bf16x8*)(BsT + (kk) * 4096 + row * 32 + cg * 8);            \
    }                                                                              \
    if ((S_) >= 0) issue_unit(S_);                                                 \
    __builtin_amdgcn_s_barrier();                                                  \
    asm volatile("" ::: "memory");                                                 \
    __builtin_amdgcn_s_setprio(1);                                                 \
    _Pragma("unroll")                                                              \
    for (int i = 0; i < 4; ++i)                                                    \
      _Pragma("unroll")                                                            \
      for (int j = 0; j < 2; ++j)                                                  \
        acc[i][(nh) * 2 + j] =                                                     \
            __builtin_amdgcn_mfma_f32_16x16x32_bf16(af[i], bfr[j],                 \
                                                    acc[i][(nh) * 2 + j], 0, 0, 0);\
    __builtin_amdgcn_s_setprio(0);                                                 \
    if constexpr ((WN) >= 0)                                                       \
      asm volatile("s_waitcnt vmcnt(%0)" ::"i"(WN) : "memory");                    \
    __builtin_amdgcn_s_barrier();                                                  \
    asm volatile("" ::: "memory");                                                 \
  }

__global__ __launch_bounds__(512, 2) void gemm_proj(
    const bf16* __restrict__ A, int lda,
    const bf16* __restrict__ B, int ldb,
    const float* __restrict__ bias,
    const float* __restrict__ xres,
    float* __restrict__ outp) {
    __shared__ bf16 As[2 * 2 * 256 * 32];   // 64 KB (reused for transpose)
    __shared__ bf16 Bs[2 * 2 * 128 * 32];   // 32 KB
    const int t = threadIdx.x;
    const int wid = t >> 6, l = t & 63;
    const int wm = wid >> 1, wn = wid & 1;   // 4M x 2N waves, wave tile 64x64
    const int lr = l & 15;
    const int lg = l >> 4;

    const int gx = gridDim.x;
    int nwg = gx * gridDim.y;
    int flat = blockIdx.y * gx + blockIdx.x;
    if ((nwg & 7) == 0) { int qq = nwg >> 3; flat = (flat & 7) * qq + (flat >> 3); }
    const int bx = flat % gx, by = flat / gx;

    const bf16* Ab = A + (long)bx * 256 * lda;
    const bf16* Bb = B + (long)by * 128 * ldb;

    const int NT = 8;            // K = 512
    const int NT4 = 32;

    f32x4 acc[4][4];
    #pragma unroll
    for (int i = 0; i < 4; ++i)
        #pragma unroll
        for (int n = 0; n < 4; ++n) acc[i][n] = f32x4{0.f, 0.f, 0.f, 0.f};

    const int srow = t >> 2;       // 0..127
    const int scg0 = t & 3;

    auto issue_unit = [&](int s) {
        int ti = s >> 2, idx = s & 3;
        int kh = idx >> 1, isB = idx & 1;
        int k0 = ti * 64 + kh * 32;
        if (isB) {
            bf16* lp = Bs + ((ti & 1) * 2 + kh) * 4096;
            int cg = scg0 ^ ((srow >> 1) & 3);
            gload_lds16(Bb + (long)srow * ldb + k0 + cg * 8, lp + t * 8);
        } else {
            bf16* lp = As + ((ti & 1) * 2 + kh) * 8192;
            #pragma unroll
            for (int j = 0; j < 2; ++j) {
                int row = j * 128 + srow;
                int cg = scg0 ^ ((row >> 1) & 3);
                gload_lds16(Ab + (long)row * lda + k0 + cg * 8, lp + (j * 512 + t) * 8);
            }
        }
    };

    #pragma unroll
    for (int s = 0; s < 6; ++s) issue_unit(s);
    asm volatile("s_waitcnt vmcnt(6)" ::: "memory");
    __builtin_amdgcn_s_barrier();
    asm volatile("" ::: "memory");

    bf16x8 bfr[2], af[4];

    for (int ti = 0; ti < NT - 2; ++ti) {
        const bf16* AsT = As + (ti & 1) * 16384;
        const bf16* BsT = Bs + (ti & 1) * 8192;
        const int sb = 4 * ti + 6;
        PH128(0, 0, sb + 0, -1)
        PH128(1, 0, sb + 1, 6)
        PH128(0, 1, sb + 2, -1)
        PH128(1, 1, sb + 3, 6)
    }
    {
        const bf16* AsT = As + ((NT - 2) & 1) * 16384;
        const bf16* BsT = Bs + ((NT - 2) & 1) * 8192;
        PH128(0, 0, NT4 - 2, -1)
        PH128(1, 0, NT4 - 1, 6)
        PH128(0, 1, -1, -1)
        PH128(1, 1, -1, 3)
    }
    {
        const bf16* AsT = As + ((NT - 1) & 1) * 16384;
        const bf16* BsT = Bs + ((NT - 1) & 1) * 8192;
        PH128(0, 0, -1, -1)
        PH128(1, 0, -1, 0)
        PH128(0, 1, -1, -1)
        PH128(1, 1, -1, -1)
    }

    // ---- fused epilogue: transpose -> NCHW + bias + residual ----
    const int r0 = bx * 256;
    const int c0b = by * 128;
    const int nb = r0 >> 12;
    const int sp0 = r0 & 4095;
    const int rq = lg * 4;
    float* Lt = (float*)As;                  // 32*260*4 = 33.3 KB < 64 KB
    #pragma unroll
    for (int q = 0; q < 4; ++q) {
        if (wn == (q >> 1)) {
            #pragma unroll
            for (int nn = 0; nn < 2; ++nn) {
                const int n = (q & 1) * 2 + nn;
                const int cl = nn * 16 + lr;             // 0..31
                #pragma unroll
                for (int i = 0; i < 4; ++i) {
                    const int sp = wm * 64 + i * 16 + rq;   // 0..255, mult of 4
                    float4 v;
                    v.x = acc[i][n][0]; v.y = acc[i][n][1];
                    v.z = acc[i][n][2]; v.w = acc[i][n][3];
                    *(float4*)(Lt + cl * 260 + sp) = v;
                }
            }
        }
        __syncthreads();
        {
            const int cl2 = t >> 4;                  // 0..31
            const int spc = (t & 15) * 16;           // 0..240
            const int col = c0b + q * 32 + cl2;
            const float bb = bias[col];
            const long ob = ((long)nb * 512 + col) * 4096 + sp0 + spc;
            #pragma unroll
            for (int j = 0; j < 4; ++j) {
                float4 lv = *(const float4*)(Lt + cl2 * 260 + spc + j * 4);
                float4 xv = *(const float4*)(xres + ob + j * 4);
                float4 ov;
                ov.x = lv.x + bb + xv.x; ov.y = lv.y + bb + xv.y;
                ov.z = lv.z + bb + xv.z; ov.w = lv.w + bb + xv.w;
                *(float4*)(outp + ob + j * 4) = ov;
            }
        }
        __syncthreads();
    }
}

extern "C" void kernel_launch(void* const* d_in, const int* in_sizes, int n_in,
                              void* d_out, int out_size, void* d_ws, size_t ws_size,
                              hipStream_t stream) {
    const float* x     = (const float*)d_in[0];
    const float* gnw   = (const float*)d_in[1];
    const float* gnb   = (const float*)d_in[2];
    const float* qkvw  = (const float*)d_in[3];
    const float* projw = (const float*)d_in[4];
    const float* projb = (const float*)d_in[5];

    char* ws = (char*)d_ws;
    size_t off = 0;
    auto alloc = [&](size_t bytes) {
        void* p = ws + off;
        off += (bytes + 255) & ~(size_t)255;
        return p;
    };
    // fixed: weights 2.1 MB + qk 33.55 MB + Vt 16.78 MB
    bf16*   qwb   = (bf16*)alloc((size_t)1536 * 512 * 2);
    bf16*   pwb   = (bf16*)alloc((size_t)512 * 512 * 2);
    float2* part  = (float2*)alloc((size_t)1024 * 8);
    bf16*   qk    = (bf16*)alloc((size_t)16384 * 1024 * 2);  // q|k; q-half becomes O
    bf16*   Vt    = (bf16*)alloc((size_t)4 * 512 * 4096 * 2);
    // aliased region R (134.2 MB): tbuf early -> Sbuf(4z)
    char*   R     = (char*)alloc((size_t)4 * 4096 * 4096 * 2);
    bf16*   tbuf  = (bf16*)R;                                  // tokens [16384][512]
    bf16*   Sbuf  = (bf16*)R;                                  // P, all 4 z

    // fused prologue: partial GN stats (1024 blocks) + weight conv (4096)
    k_pre<<<5120, 256, 0, stream>>>(x, qkvw, projw, part, qwb, pwb);
    k_norm_t<<<2048, 256, 0, stream>>>(x, gnw, gnb, part, tbuf);

    // qkv: q,k -> qk [16384][1024]; v transposed in-epilogue -> Vt
    gemm256<2><<<dim3(64, 6, 1), 512, 0, stream>>>(
        tbuf, 512, 0, qwb, 512, 0, qk, 1024, 0, 512, Vt);

    const long QZ = (long)4096 * 1024;   // z-stride in qk
    const long SZ = (long)4096 * 4096;   // z-stride in Sbuf
    // P = exp2(q k^T) for ALL 4 batches in one dispatch (1024 blocks)
    gemm256<1><<<dim3(16, 16, 4), 512, 0, stream>>>(
        qk, 1024, QZ,
        qk + 512, 1024, QZ,
        Sbuf, 4096, SZ, 512, nullptr);
    // O = (P * V) / rowsum, split-D: 512 blocks = 2/CU
    k_pv<<<dim3(64, 2, 4), 256, 0, stream>>>(Sbuf, Vt, qk, 1024);

    // proj + bias + residual + NCHW transpose, straight to d_out
    gemm_proj<<<dim3(64, 4), 512, 0, stream>>>(
        qk, 1024, pwb, 512, projb, x, (float*)d_out);
}